// Round 2
// baseline (1041.498 us; speedup 1.0000x reference)
//
#include <hip/hip_runtime.h>
#include <math.h>

// ---------------------------------------------------------------------------
// GCN pipeline: conv1(relu) -> conv2(relu) -> quantize(+reg) -> add -> conv3
// All fp32 (argmax in quantize is tie-sensitive; bf16 upstream would flip it).
// ---------------------------------------------------------------------------

// ---------------- CSR build ----------------

__global__ void k_init(int* cnt, int* cursor, int* counter, float* balance, int n) {
    int i = blockIdx.x * blockDim.x + threadIdx.x;
    if (i < n) { cnt[i] = 0; cursor[i] = 0; }
    if (i < 480) balance[i] = 0.f;
    if (i == 0) *counter = 0;
}

__global__ void k_count(const int* __restrict__ dst, int* __restrict__ cnt, int e) {
    int i = blockIdx.x * blockDim.x + threadIdx.x;
    if (i < e) atomicAdd(&cnt[dst[i]], 1);
}

__global__ void k_dinv(const int* __restrict__ cnt, float* __restrict__ dinv, int n) {
    int i = blockIdx.x * blockDim.x + threadIdx.x;
    if (i < n) dinv[i] = rsqrtf((float)cnt[i] + 1.0f);   // +1 self loop
}

__global__ void k_alloc(const int* __restrict__ cnt, int* __restrict__ row_start,
                        int* __restrict__ counter, int n) {
    int i = blockIdx.x * blockDim.x + threadIdx.x;
    if (i < n) row_start[i] = atomicAdd(counter, cnt[i]);
}

__global__ void k_fill(const int* __restrict__ src, const int* __restrict__ dst,
                       const float* __restrict__ dinv, const int* __restrict__ row_start,
                       int* __restrict__ cursor, int* __restrict__ csr_src,
                       float* __restrict__ csr_norm, int e) {
    int i = blockIdx.x * blockDim.x + threadIdx.x;
    if (i >= e) return;
    int s = src[i], d = dst[i];
    int slot = atomicAdd(&cursor[d], 1);
    int idx = row_start[d] + slot;
    csr_src[idx] = s;
    csr_norm[idx] = dinv[s] * dinv[d];
}

// ---------------- fp32 GEMM: C[M,N] = A[M,K] @ B[K,N] ----------------
// 128x128 tile, BK=32, 256 threads, 8x8 per thread (split 4+4 rows/cols).

__global__ __launch_bounds__(256, 2) void k_gemm(const float* __restrict__ A,
                                                 const float* __restrict__ B,
                                                 float* __restrict__ C,
                                                 int M, int N, int K) {
    __shared__ float As[32][132];   // transposed A tile: As[k][m]
    __shared__ float Bs[32][132];   // Bs[k][n]
    const int tid = threadIdx.x;
    const int bm = blockIdx.x * 128;
    const int bn = blockIdx.y * 128;
    const int tx = tid & 15, ty = tid >> 4;
    float acc[2][2][4][4] = {};

    for (int k0 = 0; k0 < K; k0 += 32) {
#pragma unroll
        for (int v = 0; v < 4; ++v) {
            int row = (tid >> 3) + v * 32;
            int col = (tid & 7) * 4;
            float4 a = make_float4(0.f, 0.f, 0.f, 0.f);
            if (bm + row < M) a = *(const float4*)(A + (size_t)(bm + row) * K + k0 + col);
            As[col + 0][row] = a.x;
            As[col + 1][row] = a.y;
            As[col + 2][row] = a.z;
            As[col + 3][row] = a.w;
        }
#pragma unroll
        for (int v = 0; v < 4; ++v) {
            int kr = (tid >> 5) + v * 8;
            int col = (tid & 31) * 4;
            *(float4*)&Bs[kr][col] = *(const float4*)(B + (size_t)(k0 + kr) * N + bn + col);
        }
        __syncthreads();
#pragma unroll
        for (int kk = 0; kk < 32; ++kk) {
            float4 a0 = *(float4*)&As[kk][ty * 4];
            float4 a1 = *(float4*)&As[kk][64 + ty * 4];
            float4 b0 = *(float4*)&Bs[kk][tx * 4];
            float4 b1 = *(float4*)&Bs[kk][64 + tx * 4];
            float av[2][4] = {{a0.x, a0.y, a0.z, a0.w}, {a1.x, a1.y, a1.z, a1.w}};
            float bv[2][4] = {{b0.x, b0.y, b0.z, b0.w}, {b1.x, b1.y, b1.z, b1.w}};
#pragma unroll
            for (int ri = 0; ri < 2; ++ri)
#pragma unroll
                for (int i = 0; i < 4; ++i)
#pragma unroll
                    for (int ci = 0; ci < 2; ++ci)
#pragma unroll
                        for (int j = 0; j < 4; ++j)
                            acc[ri][ci][i][j] += av[ri][i] * bv[ci][j];
        }
        __syncthreads();
    }
#pragma unroll
    for (int ri = 0; ri < 2; ++ri)
#pragma unroll
        for (int i = 0; i < 4; ++i) {
            int row = bm + ri * 64 + ty * 4 + i;
            if (row < M) {
#pragma unroll
                for (int ci = 0; ci < 2; ++ci) {
                    float4 o = make_float4(acc[ri][ci][i][0], acc[ri][ci][i][1],
                                           acc[ri][ci][i][2], acc[ri][ci][i][3]);
                    *(float4*)(C + (size_t)row * N + bn + ci * 64 + tx * 4) = o;
                }
            }
        }
}

// ---------------- Aggregation (gather over CSR), one wave per node ----------------

template <bool RELU>
__global__ __launch_bounds__(256) void k_agg4(const float* __restrict__ xw,
                                              const float* __restrict__ dinv,
                                              const int* __restrict__ csr_src,
                                              const float* __restrict__ csr_norm,
                                              const int* __restrict__ row_start,
                                              const int* __restrict__ cnt,
                                              const float* __restrict__ bias,
                                              float* __restrict__ out, int n) {
    int node = blockIdx.x * 4 + (threadIdx.x >> 6);
    if (node >= n) return;
    int lane = threadIdx.x & 63;
    int c = lane * 4;
    float di = dinv[node];
    float4 self = *(const float4*)(xw + (size_t)node * 256 + c);
    float4 bv = *(const float4*)(bias + c);
    float sw = di * di;
    float ax = self.x * sw + bv.x;
    float ay = self.y * sw + bv.y;
    float az = self.z * sw + bv.z;
    float aw = self.w * sw + bv.w;
    int st = row_start[node];
    int m = cnt[node];
#pragma unroll 4
    for (int t = 0; t < m; ++t) {
        int s = csr_src[st + t];
        float w = csr_norm[st + t];
        float4 v = *(const float4*)(xw + (size_t)s * 256 + c);
        ax += v.x * w; ay += v.y * w; az += v.z * w; aw += v.w * w;
    }
    if (RELU) {
        ax = ax > 0.f ? ax : 0.5f * ax;
        ay = ay > 0.f ? ay : 0.5f * ay;
        az = az > 0.f ? az : 0.5f * az;
        aw = aw > 0.f ? aw : 0.5f * aw;
    }
    *(float4*)(out + (size_t)node * 256 + c) = make_float4(ax, ay, az, aw);
}

__global__ __launch_bounds__(256) void k_agg2(const float* __restrict__ xw,
                                              const float* __restrict__ dinv,
                                              const int* __restrict__ csr_src,
                                              const float* __restrict__ csr_norm,
                                              const int* __restrict__ row_start,
                                              const int* __restrict__ cnt,
                                              const float* __restrict__ bias,
                                              float* __restrict__ out, int n) {
    int node = blockIdx.x * 4 + (threadIdx.x >> 6);
    if (node >= n) return;
    int lane = threadIdx.x & 63;
    int c = lane * 2;
    float di = dinv[node];
    float2 self = *(const float2*)(xw + (size_t)node * 128 + c);
    float2 bv = *(const float2*)(bias + c);
    float sw = di * di;
    float ax = self.x * sw + bv.x;
    float ay = self.y * sw + bv.y;
    int st = row_start[node];
    int m = cnt[node];
#pragma unroll 4
    for (int t = 0; t < m; ++t) {
        int s = csr_src[st + t];
        float w = csr_norm[st + t];
        float2 v = *(const float2*)(xw + (size_t)s * 128 + c);
        ax += v.x * w; ay += v.y * w;
    }
    *(float2*)(out + (size_t)node * 128 + c) = make_float2(ax, ay);
}

// ---------------- Quantize (fused, GEMM-structured) ----------------
// grid (ceil(n/64), 4=d). Block 256 threads, 64 nodes, one d-slice.
// Forward value of q is HARD (stop_gradient(hard-soft)+soft == hard), so we
// need only: prods -> argmax (hard select) and softmax probs -> balance.
// P1: prods = hT[64k x 64n] x centT[64k x 128c] register GEMM (8n x 4c /thread)
//     hT reads are wave-broadcast (2 addrs/wave) -> VALU-bound, not DS-bound.
// P2: acc -> LDS prods (XOR-swizzled float4 granules, reuses centT buffer)
// P3: per (node, group): argmax + softmax; balance via 64-lane butterfly + atomic
// P4: h3 = h + max_j C[km_j] epilogue (centroid table is L1/L2-hot, 122 KB)

template <int M_, int OFF>
__device__ __forceinline__ int soft_group(const float* __restrict__ u,
                                          float* __restrict__ balance_g,
                                          int node, int d, bool act) {
    float pv[M_];
#pragma unroll
    for (int q4 = 0; q4 < M_ / 4; ++q4) {
        int cq = (OFF >> 2) + q4;
        float4 v = *(const float4*)&u[node * 128 + ((cq ^ (node & 31)) << 2)];
        pv[q4 * 4 + 0] = v.x; pv[q4 * 4 + 1] = v.y;
        pv[q4 * 4 + 2] = v.z; pv[q4 * 4 + 3] = v.w;
    }
    float mx = pv[0];
    int am = 0;
#pragma unroll
    for (int t = 1; t < M_; ++t)
        if (pv[t] > mx) { mx = pv[t]; am = t; }   // first-max == jnp.argmax
    float Z = 0.f;
#pragma unroll
    for (int t = 0; t < M_; ++t) {
        pv[t] = expf(pv[t] - mx);
        Z += pv[t];
    }
    float invZ = act ? 1.0f / Z : 0.f;   // inactive nodes contribute 0 to balance
#pragma unroll
    for (int t = 0; t < M_; ++t) {
        float p = pv[t] * invZ;
        p += __shfl_xor(p, 1);
        p += __shfl_xor(p, 2);
        p += __shfl_xor(p, 4);
        p += __shfl_xor(p, 8);
        p += __shfl_xor(p, 16);
        p += __shfl_xor(p, 32);
        if (node == 0) atomicAdd(&balance_g[(OFF + t) * 4 + d], p);
    }
    return OFF + am;
}

__global__ __launch_bounds__(256) void k_quant2(const float* __restrict__ h2,
                                                const float* __restrict__ cent,
                                                float* __restrict__ h3,
                                                float* __restrict__ balance_g, int n) {
    __shared__ float hT[64 * 68];    // hT[k][node], pad 68
    __shared__ float u[64 * 132];    // P0/P1: centT[k][kc] pad 132; P2+: prods[node][128] swz
    __shared__ int km_ls[64 * 4];
    const int tid = threadIdx.x;
    const int n0 = blockIdx.x * 64;
    const int d = blockIdx.y;

    // P0: stage hT (zeros for tail nodes) and centT (zeros for pad kc 120..127)
#pragma unroll
    for (int it = 0; it < 16; ++it) {
        int idx = it * 256 + tid;
        int nd = idx >> 6, k = idx & 63;
        hT[k * 68 + nd] = (n0 + nd < n) ? h2[(size_t)(n0 + nd) * 256 + d * 64 + k] : 0.f;
    }
#pragma unroll
    for (int it = 0; it < 32; ++it) {
        int idx = it * 256 + tid;
        int kc = idx >> 6, k = idx & 63;
        u[k * 132 + kc] = (kc < 120) ? cent[(size_t)kc * 256 + d * 64 + k] : 0.f;
    }
    __syncthreads();

    // P1: register GEMM, thread tile = 8 nodes x 4 cents
    const int nr = tid >> 5;     // 0..7  (node group of 8) — wave-halves broadcast hT
    const int cg = tid & 31;     // 0..31 (cent group of 4)
    float acc[8][4] = {};
#pragma unroll 4
    for (int k = 0; k < 64; ++k) {
        float4 c4 = *(const float4*)&u[k * 132 + cg * 4];
        float4 h0 = *(const float4*)&hT[k * 68 + nr * 8];
        float4 h1 = *(const float4*)&hT[k * 68 + nr * 8 + 4];
        float hv[8] = {h0.x, h0.y, h0.z, h0.w, h1.x, h1.y, h1.z, h1.w};
        float cv[4] = {c4.x, c4.y, c4.z, c4.w};
#pragma unroll
        for (int i = 0; i < 8; ++i)
#pragma unroll
            for (int j = 0; j < 4; ++j)
                acc[i][j] += hv[i] * cv[j];
    }
    __syncthreads();   // all reads of centT done before overwrite

    // P2: acc -> prods in LDS, XOR-swizzled float4 granules (stride 128, no pad)
#pragma unroll
    for (int i = 0; i < 8; ++i) {
        int node = nr * 8 + i;
        float4 v = make_float4(acc[i][0], acc[i][1], acc[i][2], acc[i][3]);
        *(float4*)&u[node * 128 + ((cg ^ (node & 31)) << 2)] = v;
    }
    __syncthreads();

    // P3: wave w handles group j=w for its lane's node
    {
        const int part = tid >> 6;       // == wave index == group j
        const int node = tid & 63;       // == lane
        const bool act = (n0 + node) < n;
        int km;
        if (part == 0)      km = soft_group<8, 0>(u, balance_g, node, d, act);
        else if (part == 1) km = soft_group<16, 8>(u, balance_g, node, d, act);
        else if (part == 2) km = soft_group<32, 24>(u, balance_g, node, d, act);
        else                km = soft_group<64, 56>(u, balance_g, node, d, act);
        km_ls[node * 4 + part] = km;
    }
    __syncthreads();

    // P4: h3[node][d*64+s] = h2 + max_j cent[km_j][d*64+s]
    {
        const int node = tid >> 2;
        const int ql = tid & 3;
        const bool act = (n0 + node) < n;
        if (act) {
            int k0 = km_ls[node * 4 + 0], k1 = km_ls[node * 4 + 1];
            int k2 = km_ls[node * 4 + 2], k3 = km_ls[node * 4 + 3];
            const float* hp = h2 + (size_t)(n0 + node) * 256 + d * 64;
            const float* c0 = cent + (size_t)k0 * 256 + d * 64;
            const float* c1 = cent + (size_t)k1 * 256 + d * 64;
            const float* c2 = cent + (size_t)k2 * 256 + d * 64;
            const float* c3 = cent + (size_t)k3 * 256 + d * 64;
            float* op = h3 + (size_t)(n0 + node) * 256 + d * 64;
#pragma unroll
            for (int u4 = 0; u4 < 4; ++u4) {
                int g = (ql + u4 * 4) * 4;    // float offset, lanes cover 64B runs
                float4 hv = *(const float4*)(hp + g);
                float4 v0 = *(const float4*)(c0 + g);
                float4 v1 = *(const float4*)(c1 + g);
                float4 v2 = *(const float4*)(c2 + g);
                float4 v3 = *(const float4*)(c3 + g);
                float4 r;
                r.x = hv.x + fmaxf(fmaxf(v0.x, v1.x), fmaxf(v2.x, v3.x));
                r.y = hv.y + fmaxf(fmaxf(v0.y, v1.y), fmaxf(v2.y, v3.y));
                r.z = hv.z + fmaxf(fmaxf(v0.z, v1.z), fmaxf(v2.z, v3.z));
                r.w = hv.w + fmaxf(fmaxf(v0.w, v1.w), fmaxf(v2.w, v3.w));
                *(float4*)(op + g) = r;
            }
        }
    }
}

__global__ void k_reg(const float* __restrict__ balance_g, float* __restrict__ out_reg,
                      float inv_n) {
    __shared__ float red[512];
    int tid = threadIdx.x;
    float v = 0.f;
    if (tid < 480) {
        int k = tid >> 2;
        float target = (k < 8) ? 0.125f : (k < 24) ? 0.0625f : (k < 56) ? 0.03125f : 0.015625f;
        float b = balance_g[tid] * inv_n;
        float df = b - target;
        v = df * df;
    }
    red[tid] = v;
    __syncthreads();
    for (int s = 256; s > 0; s >>= 1) {
        if (tid < s) red[tid] += red[tid + s];
        __syncthreads();
    }
    if (tid == 0) *out_reg = sqrtf(red[0]);
}

// ---------------- host launch ----------------

extern "C" void kernel_launch(void* const* d_in, const int* in_sizes, int n_in,
                              void* d_out, int out_size, void* d_ws, size_t ws_size,
                              hipStream_t stream) {
    const float* x    = (const float*)d_in[0];
    const int*   ei   = (const int*)d_in[1];
    const float* W0   = (const float*)d_in[2];
    const float* b0   = (const float*)d_in[3];
    const float* W1   = (const float*)d_in[4];
    const float* b1   = (const float*)d_in[5];
    const float* W2   = (const float*)d_in[6];
    const float* b2   = (const float*)d_in[7];
    const float* cent = (const float*)d_in[8];
    const int n = in_sizes[0] / 256;
    const int e = in_sizes[1] / 2;
    const int* src = ei;
    const int* dst = ei + e;
    float* out = (float*)d_out;

    char* w = (char*)d_ws;
    float* bufA = (float*)w;      w += (size_t)n * 256 * 4;
    float* bufB = (float*)w;      w += (size_t)n * 256 * 4;
    float* dinv = (float*)w;      w += (size_t)n * 4;
    int* cnt = (int*)w;           w += (size_t)n * 4;
    int* row_start = (int*)w;     w += (size_t)n * 4;
    int* cursor = (int*)w;        w += (size_t)n * 4;
    int* csr_src = (int*)w;       w += (size_t)e * 4;
    float* csr_norm = (float*)w;  w += (size_t)e * 4;
    int* counter = (int*)w;       w += 256;
    float* balance = (float*)w;   w += 480 * 4;

    const int tb = 256;
    k_init<<<(n + tb - 1) / tb, tb, 0, stream>>>(cnt, cursor, counter, balance, n);
    k_count<<<(e + tb - 1) / tb, tb, 0, stream>>>(dst, cnt, e);
    k_dinv<<<(n + tb - 1) / tb, tb, 0, stream>>>(cnt, dinv, n);
    k_alloc<<<(n + tb - 1) / tb, tb, 0, stream>>>(cnt, row_start, counter, n);
    k_fill<<<(e + tb - 1) / tb, tb, 0, stream>>>(src, dst, dinv, row_start, cursor,
                                                 csr_src, csr_norm, e);

    dim3 g1((n + 127) / 128, 2);
    k_gemm<<<g1, 256, 0, stream>>>(x, W0, bufA, n, 256, 256);
    k_agg4<true><<<(n + 3) / 4, 256, 0, stream>>>(bufA, dinv, csr_src, csr_norm,
                                                  row_start, cnt, b0, bufB, n);
    k_gemm<<<g1, 256, 0, stream>>>(bufB, W1, bufA, n, 256, 256);
    k_agg4<true><<<(n + 3) / 4, 256, 0, stream>>>(bufA, dinv, csr_src, csr_norm,
                                                  row_start, cnt, b1, bufB, n);

    dim3 gq((n + 63) / 64, 4);
    k_quant2<<<gq, 256, 0, stream>>>(bufB, cent, bufA, balance, n);

    dim3 g3((n + 127) / 128, 1);
    k_gemm<<<g3, 256, 0, stream>>>(bufA, W2, bufB, n, 128, 256);
    k_agg2<<<(n + 3) / 4, 256, 0, stream>>>(bufB, dinv, csr_src, csr_norm,
                                            row_start, cnt, b2, out, n);
    k_reg<<<1, 512, 0, stream>>>(balance, out + (size_t)n * 128, 1.0f / (float)n);
}

// Round 3
// 822.108 us; speedup vs baseline: 1.2669x; 1.2669x over previous
//
#include <hip/hip_runtime.h>
#include <math.h>

// ---------------------------------------------------------------------------
// GCN pipeline: conv1(relu) -> conv2(relu) -> quantize(+reg) -> add -> conv3
// All fp32 (argmax in quantize is tie-sensitive; bf16 upstream would flip it).
// ---------------------------------------------------------------------------

// ---------------- CSR build ----------------

__global__ void k_init(int* cnt, int* cursor, int* counter, float* balance, int n) {
    int i = blockIdx.x * blockDim.x + threadIdx.x;
    if (i < n) { cnt[i] = 0; cursor[i] = 0; }
    if (i < 480) balance[i] = 0.f;
    if (i == 0) *counter = 0;
}

__global__ void k_count(const int* __restrict__ dst, int* __restrict__ cnt, int e) {
    int i = blockIdx.x * blockDim.x + threadIdx.x;
    if (i < e) atomicAdd(&cnt[dst[i]], 1);
}

__global__ void k_dinv(const int* __restrict__ cnt, float* __restrict__ dinv, int n) {
    int i = blockIdx.x * blockDim.x + threadIdx.x;
    if (i < n) dinv[i] = rsqrtf((float)cnt[i] + 1.0f);   // +1 self loop
}

__global__ void k_alloc(const int* __restrict__ cnt, int* __restrict__ row_start,
                        int* __restrict__ counter, int n) {
    int i = blockIdx.x * blockDim.x + threadIdx.x;
    if (i < n) row_start[i] = atomicAdd(counter, cnt[i]);
}

__global__ void k_fill(const int* __restrict__ src, const int* __restrict__ dst,
                       const float* __restrict__ dinv, const int* __restrict__ row_start,
                       int* __restrict__ cursor, int* __restrict__ csr_src,
                       float* __restrict__ csr_norm, int e) {
    int i = blockIdx.x * blockDim.x + threadIdx.x;
    if (i >= e) return;
    int s = src[i], d = dst[i];
    int slot = atomicAdd(&cursor[d], 1);
    int idx = row_start[d] + slot;
    csr_src[idx] = s;
    csr_norm[idx] = dinv[s] * dinv[d];
}

// ---------------- fp32 GEMM: C[M,N] = A[M,K] @ B[K,N] ----------------
// 128x128 tile, BK=32, 256 threads, 8x8 per thread (split 4+4 rows/cols).

__global__ __launch_bounds__(256, 2) void k_gemm(const float* __restrict__ A,
                                                 const float* __restrict__ B,
                                                 float* __restrict__ C,
                                                 int M, int N, int K) {
    __shared__ float As[32][132];   // transposed A tile: As[k][m]
    __shared__ float Bs[32][132];   // Bs[k][n]
    const int tid = threadIdx.x;
    const int bm = blockIdx.x * 128;
    const int bn = blockIdx.y * 128;
    const int tx = tid & 15, ty = tid >> 4;
    float acc[2][2][4][4] = {};

    for (int k0 = 0; k0 < K; k0 += 32) {
#pragma unroll
        for (int v = 0; v < 4; ++v) {
            int row = (tid >> 3) + v * 32;
            int col = (tid & 7) * 4;
            float4 a = make_float4(0.f, 0.f, 0.f, 0.f);
            if (bm + row < M) a = *(const float4*)(A + (size_t)(bm + row) * K + k0 + col);
            As[col + 0][row] = a.x;
            As[col + 1][row] = a.y;
            As[col + 2][row] = a.z;
            As[col + 3][row] = a.w;
        }
#pragma unroll
        for (int v = 0; v < 4; ++v) {
            int kr = (tid >> 5) + v * 8;
            int col = (tid & 31) * 4;
            *(float4*)&Bs[kr][col] = *(const float4*)(B + (size_t)(k0 + kr) * N + bn + col);
        }
        __syncthreads();
#pragma unroll
        for (int kk = 0; kk < 32; ++kk) {
            float4 a0 = *(float4*)&As[kk][ty * 4];
            float4 a1 = *(float4*)&As[kk][64 + ty * 4];
            float4 b0 = *(float4*)&Bs[kk][tx * 4];
            float4 b1 = *(float4*)&Bs[kk][64 + tx * 4];
            float av[2][4] = {{a0.x, a0.y, a0.z, a0.w}, {a1.x, a1.y, a1.z, a1.w}};
            float bv[2][4] = {{b0.x, b0.y, b0.z, b0.w}, {b1.x, b1.y, b1.z, b1.w}};
#pragma unroll
            for (int ri = 0; ri < 2; ++ri)
#pragma unroll
                for (int i = 0; i < 4; ++i)
#pragma unroll
                    for (int ci = 0; ci < 2; ++ci)
#pragma unroll
                        for (int j = 0; j < 4; ++j)
                            acc[ri][ci][i][j] += av[ri][i] * bv[ci][j];
        }
        __syncthreads();
    }
#pragma unroll
    for (int ri = 0; ri < 2; ++ri)
#pragma unroll
        for (int i = 0; i < 4; ++i) {
            int row = bm + ri * 64 + ty * 4 + i;
            if (row < M) {
#pragma unroll
                for (int ci = 0; ci < 2; ++ci) {
                    float4 o = make_float4(acc[ri][ci][i][0], acc[ri][ci][i][1],
                                           acc[ri][ci][i][2], acc[ri][ci][i][3]);
                    *(float4*)(C + (size_t)row * N + bn + ci * 64 + tx * 4) = o;
                }
            }
        }
}

// ---------------- Aggregation (gather over CSR), one wave per node ----------------

template <bool RELU>
__global__ __launch_bounds__(256) void k_agg4(const float* __restrict__ xw,
                                              const float* __restrict__ dinv,
                                              const int* __restrict__ csr_src,
                                              const float* __restrict__ csr_norm,
                                              const int* __restrict__ row_start,
                                              const int* __restrict__ cnt,
                                              const float* __restrict__ bias,
                                              float* __restrict__ out, int n) {
    int node = blockIdx.x * 4 + (threadIdx.x >> 6);
    if (node >= n) return;
    int lane = threadIdx.x & 63;
    int c = lane * 4;
    float di = dinv[node];
    float4 self = *(const float4*)(xw + (size_t)node * 256 + c);
    float4 bv = *(const float4*)(bias + c);
    float sw = di * di;
    float ax = self.x * sw + bv.x;
    float ay = self.y * sw + bv.y;
    float az = self.z * sw + bv.z;
    float aw = self.w * sw + bv.w;
    int st = row_start[node];
    int m = cnt[node];
#pragma unroll 4
    for (int t = 0; t < m; ++t) {
        int s = csr_src[st + t];
        float w = csr_norm[st + t];
        float4 v = *(const float4*)(xw + (size_t)s * 256 + c);
        ax += v.x * w; ay += v.y * w; az += v.z * w; aw += v.w * w;
    }
    if (RELU) {
        ax = ax > 0.f ? ax : 0.5f * ax;
        ay = ay > 0.f ? ay : 0.5f * ay;
        az = az > 0.f ? az : 0.5f * az;
        aw = aw > 0.f ? aw : 0.5f * aw;
    }
    *(float4*)(out + (size_t)node * 256 + c) = make_float4(ax, ay, az, aw);
}

__global__ __launch_bounds__(256) void k_agg2(const float* __restrict__ xw,
                                              const float* __restrict__ dinv,
                                              const int* __restrict__ csr_src,
                                              const float* __restrict__ csr_norm,
                                              const int* __restrict__ row_start,
                                              const int* __restrict__ cnt,
                                              const float* __restrict__ bias,
                                              float* __restrict__ out, int n) {
    int node = blockIdx.x * 4 + (threadIdx.x >> 6);
    if (node >= n) return;
    int lane = threadIdx.x & 63;
    int c = lane * 2;
    float di = dinv[node];
    float2 self = *(const float2*)(xw + (size_t)node * 128 + c);
    float2 bv = *(const float2*)(bias + c);
    float sw = di * di;
    float ax = self.x * sw + bv.x;
    float ay = self.y * sw + bv.y;
    int st = row_start[node];
    int m = cnt[node];
#pragma unroll 4
    for (int t = 0; t < m; ++t) {
        int s = csr_src[st + t];
        float w = csr_norm[st + t];
        float2 v = *(const float2*)(xw + (size_t)s * 128 + c);
        ax += v.x * w; ay += v.y * w;
    }
    *(float2*)(out + (size_t)node * 128 + c) = make_float2(ax, ay);
}

// ---------------- Quantize v3 ----------------
// grid (ceil(n/128), 4=d), 256 threads. Per block: 128 nodes x 120 cents, K=64.
// Forward value of q is HARD (stop_gradient(hard-soft)+soft == hard): we need
// only argmax (hard select) + softmax probs (balance).
//  P0: stage As=h^T[64k x 128n], Bs=cent^T[64k x 128c(pad)] (once per block)
//  P1: register GEMM acc[8][8] per thread (proven k_gemm shape)
//  P2: acc -> P[node][132] in LDS (reuses As+Bs space)
//  P3: 3 streaming float4 passes per group (max/argmax, exp+sum, p*invZ+reduce)
//      -- NO large per-thread arrays (round-2 lesson: pv[64] spilled to scratch)
//      wave 0/1: group3 (64c) for nodes 0-63/64-127; wave 2/3: groups 0,1,2
//      balance: 6-step butterfly -> 1 LDS atomic/elem/wave -> 120 global atomics
//  P4: h3 = h2 + max_j cent[km_j] epilogue (cent is L2-hot)

template <int M_, int OFF>
__device__ __forceinline__ int sgroup(float* __restrict__ Pn, float* __restrict__ bal,
                                      bool act, int lane) {
    // pass 1: max + first-argmax (matches jnp.argmax)
    float mx = -3.4e38f;
    int am = OFF;
#pragma unroll
    for (int q = 0; q < M_ / 4; ++q) {
        float4 v = *(const float4*)&Pn[OFF + q * 4];
        float e[4] = {v.x, v.y, v.z, v.w};
#pragma unroll
        for (int t = 0; t < 4; ++t)
            if (e[t] > mx) { mx = e[t]; am = OFF + q * 4 + t; }
    }
    // pass 2: exp (stored back to LDS) + sum
    float Z = 0.f;
#pragma unroll
    for (int q = 0; q < M_ / 4; ++q) {
        float4 v = *(const float4*)&Pn[OFF + q * 4];
        v.x = expf(v.x - mx); v.y = expf(v.y - mx);
        v.z = expf(v.z - mx); v.w = expf(v.w - mx);
        *(float4*)&Pn[OFF + q * 4] = v;
        Z += v.x + v.y + v.z + v.w;
    }
    float invZ = act ? (1.0f / Z) : 0.f;   // inactive nodes contribute 0
    // pass 3: p = exp * invZ, butterfly-sum across 64 nodes, 1 LDS atomic
#pragma unroll
    for (int q = 0; q < M_ / 4; ++q) {
        float4 v = *(const float4*)&Pn[OFF + q * 4];
        float e[4] = {v.x, v.y, v.z, v.w};
#pragma unroll
        for (int t = 0; t < 4; ++t) {
            float p = e[t] * invZ;
            p += __shfl_xor(p, 1);
            p += __shfl_xor(p, 2);
            p += __shfl_xor(p, 4);
            p += __shfl_xor(p, 8);
            p += __shfl_xor(p, 16);
            p += __shfl_xor(p, 32);
            if (lane == 0) atomicAdd(&bal[OFF + q * 4 + t], p);
        }
    }
    return am;
}

__global__ __launch_bounds__(256) void k_quant3(const float* __restrict__ h2,
                                                const float* __restrict__ cent,
                                                float* __restrict__ h3,
                                                float* __restrict__ balance_g, int n) {
    __shared__ float smem[16896];    // As[64][132] | Bs[64][132]; later P[128][132]
    __shared__ float bal[128];
    __shared__ int km_ls[128 * 4];
    float* As = smem;                // As[k*132 + m]
    float* Bs = smem + 64 * 132;     // Bs[k*132 + c]
    float* P = smem;                 // P[node*132 + c]
    const int tid = threadIdx.x;
    const int n0 = blockIdx.x * 128;
    const int d = blockIdx.y;

    if (tid < 128) bal[tid] = 0.f;

    // P0: stage As (h2 tile transposed; zeros for tail rows)
#pragma unroll
    for (int it = 0; it < 8; ++it) {
        int q = it * 256 + tid;          // 2048 quads = 128 rows x 16
        int row = q >> 4, k4 = q & 15;
        float4 v = make_float4(0.f, 0.f, 0.f, 0.f);
        if (n0 + row < n) v = *(const float4*)(h2 + (size_t)(n0 + row) * 256 + d * 64 + k4 * 4);
        As[(k4 * 4 + 0) * 132 + row] = v.x;
        As[(k4 * 4 + 1) * 132 + row] = v.y;
        As[(k4 * 4 + 2) * 132 + row] = v.z;
        As[(k4 * 4 + 3) * 132 + row] = v.w;
    }
    // P0: stage Bs (cent^T for this d; cols 120..127 zero)
#pragma unroll
    for (int it = 0; it < 8; ++it) {
        int q = it * 256 + tid;          // 1920 quads = 120 rows x 16
        if (q < 1920) {
            int c = q >> 4, k4 = q & 15;
            float4 v = *(const float4*)(cent + (size_t)c * 256 + d * 64 + k4 * 4);
            Bs[(k4 * 4 + 0) * 132 + c] = v.x;
            Bs[(k4 * 4 + 1) * 132 + c] = v.y;
            Bs[(k4 * 4 + 2) * 132 + c] = v.z;
            Bs[(k4 * 4 + 3) * 132 + c] = v.w;
        }
    }
    for (int idx = tid; idx < 512; idx += 256) {
        int k = idx >> 3, c = 120 + (idx & 7);
        Bs[k * 132 + c] = 0.f;
    }
    __syncthreads();

    // P1: register GEMM, thread tile 8 nodes x 8 cents
    const int ty = tid >> 4, tx = tid & 15;
    float acc[8][8] = {};
#pragma unroll 4
    for (int k = 0; k < 64; ++k) {
        float4 a0 = *(const float4*)&As[k * 132 + ty * 8];
        float4 a1 = *(const float4*)&As[k * 132 + ty * 8 + 4];
        float4 b0 = *(const float4*)&Bs[k * 132 + tx * 8];
        float4 b1 = *(const float4*)&Bs[k * 132 + tx * 8 + 4];
        float av[8] = {a0.x, a0.y, a0.z, a0.w, a1.x, a1.y, a1.z, a1.w};
        float bv[8] = {b0.x, b0.y, b0.z, b0.w, b1.x, b1.y, b1.z, b1.w};
#pragma unroll
        for (int i = 0; i < 8; ++i)
#pragma unroll
            for (int j = 0; j < 8; ++j)
                acc[i][j] += av[i] * bv[j];
    }
    __syncthreads();   // all As/Bs reads done before P overwrites

    // P2: acc -> P[node][c]
#pragma unroll
    for (int i = 0; i < 8; ++i) {
        int node = ty * 8 + i;
        *(float4*)&P[node * 132 + tx * 8] =
            make_float4(acc[i][0], acc[i][1], acc[i][2], acc[i][3]);
        *(float4*)&P[node * 132 + tx * 8 + 4] =
            make_float4(acc[i][4], acc[i][5], acc[i][6], acc[i][7]);
    }
    __syncthreads();

    // P3: softmax/argmax/balance. wave0/1 -> group3; wave2/3 -> groups 0,1,2
    {
        const int wv = tid >> 6;
        const int node = (tid & 63) + (wv & 1) * 64;
        const bool act = (n0 + node) < n;
        const int lane = tid & 63;
        float* Pn = &P[node * 132];
        if (wv < 2) {
            km_ls[node * 4 + 3] = sgroup<64, 56>(Pn, bal, act, lane);
        } else {
            km_ls[node * 4 + 0] = sgroup<8, 0>(Pn, bal, act, lane);
            km_ls[node * 4 + 1] = sgroup<16, 8>(Pn, bal, act, lane);
            km_ls[node * 4 + 2] = sgroup<32, 24>(Pn, bal, act, lane);
        }
    }
    __syncthreads();

    // flush balance (120 entries for this d)
    if (tid < 120) atomicAdd(&balance_g[tid * 4 + d], bal[tid]);

    // P4: h3 = h2 + max_j cent[km_j], 2 threads per node (32 floats each)
    {
        const int node = tid >> 1;
        const int half = tid & 1;
        if (n0 + node < n) {
            int k0 = km_ls[node * 4 + 0], k1 = km_ls[node * 4 + 1];
            int k2 = km_ls[node * 4 + 2], k3 = km_ls[node * 4 + 3];
            const float* hp = h2 + (size_t)(n0 + node) * 256 + d * 64 + half * 32;
            const float* c0 = cent + (size_t)k0 * 256 + d * 64 + half * 32;
            const float* c1 = cent + (size_t)k1 * 256 + d * 64 + half * 32;
            const float* c2 = cent + (size_t)k2 * 256 + d * 64 + half * 32;
            const float* c3 = cent + (size_t)k3 * 256 + d * 64 + half * 32;
            float* op = h3 + (size_t)(n0 + node) * 256 + d * 64 + half * 32;
#pragma unroll
            for (int q = 0; q < 8; ++q) {
                int g = q * 4;
                float4 hv = *(const float4*)(hp + g);
                float4 v0 = *(const float4*)(c0 + g);
                float4 v1 = *(const float4*)(c1 + g);
                float4 v2 = *(const float4*)(c2 + g);
                float4 v3 = *(const float4*)(c3 + g);
                float4 r;
                r.x = hv.x + fmaxf(fmaxf(v0.x, v1.x), fmaxf(v2.x, v3.x));
                r.y = hv.y + fmaxf(fmaxf(v0.y, v1.y), fmaxf(v2.y, v3.y));
                r.z = hv.z + fmaxf(fmaxf(v0.z, v1.z), fmaxf(v2.z, v3.z));
                r.w = hv.w + fmaxf(fmaxf(v0.w, v1.w), fmaxf(v2.w, v3.w));
                *(float4*)(op + g) = r;
            }
        }
    }
}

__global__ void k_reg(const float* __restrict__ balance_g, float* __restrict__ out_reg,
                      float inv_n) {
    __shared__ float red[512];
    int tid = threadIdx.x;
    float v = 0.f;
    if (tid < 480) {
        int k = tid >> 2;
        float target = (k < 8) ? 0.125f : (k < 24) ? 0.0625f : (k < 56) ? 0.03125f : 0.015625f;
        float b = balance_g[tid] * inv_n;
        float df = b - target;
        v = df * df;
    }
    red[tid] = v;
    __syncthreads();
    for (int s = 256; s > 0; s >>= 1) {
        if (tid < s) red[tid] += red[tid + s];
        __syncthreads();
    }
    if (tid == 0) *out_reg = sqrtf(red[0]);
}

// ---------------- host launch ----------------

extern "C" void kernel_launch(void* const* d_in, const int* in_sizes, int n_in,
                              void* d_out, int out_size, void* d_ws, size_t ws_size,
                              hipStream_t stream) {
    const float* x    = (const float*)d_in[0];
    const int*   ei   = (const int*)d_in[1];
    const float* W0   = (const float*)d_in[2];
    const float* b0   = (const float*)d_in[3];
    const float* W1   = (const float*)d_in[4];
    const float* b1   = (const float*)d_in[5];
    const float* W2   = (const float*)d_in[6];
    const float* b2   = (const float*)d_in[7];
    const float* cent = (const float*)d_in[8];
    const int n = in_sizes[0] / 256;
    const int e = in_sizes[1] / 2;
    const int* src = ei;
    const int* dst = ei + e;
    float* out = (float*)d_out;

    char* w = (char*)d_ws;
    float* bufA = (float*)w;      w += (size_t)n * 256 * 4;
    float* bufB = (float*)w;      w += (size_t)n * 256 * 4;
    float* dinv = (float*)w;      w += (size_t)n * 4;
    int* cnt = (int*)w;           w += (size_t)n * 4;
    int* row_start = (int*)w;     w += (size_t)n * 4;
    int* cursor = (int*)w;        w += (size_t)n * 4;
    int* csr_src = (int*)w;       w += (size_t)e * 4;
    float* csr_norm = (float*)w;  w += (size_t)e * 4;
    int* counter = (int*)w;       w += 256;
    float* balance = (float*)w;   w += 480 * 4;

    const int tb = 256;
    k_init<<<(n + tb - 1) / tb, tb, 0, stream>>>(cnt, cursor, counter, balance, n);
    k_count<<<(e + tb - 1) / tb, tb, 0, stream>>>(dst, cnt, e);
    k_dinv<<<(n + tb - 1) / tb, tb, 0, stream>>>(cnt, dinv, n);
    k_alloc<<<(n + tb - 1) / tb, tb, 0, stream>>>(cnt, row_start, counter, n);
    k_fill<<<(e + tb - 1) / tb, tb, 0, stream>>>(src, dst, dinv, row_start, cursor,
                                                 csr_src, csr_norm, e);

    dim3 g1((n + 127) / 128, 2);
    k_gemm<<<g1, 256, 0, stream>>>(x, W0, bufA, n, 256, 256);
    k_agg4<true><<<(n + 3) / 4, 256, 0, stream>>>(bufA, dinv, csr_src, csr_norm,
                                                  row_start, cnt, b0, bufB, n);
    k_gemm<<<g1, 256, 0, stream>>>(bufB, W1, bufA, n, 256, 256);
    k_agg4<true><<<(n + 3) / 4, 256, 0, stream>>>(bufA, dinv, csr_src, csr_norm,
                                                  row_start, cnt, b1, bufB, n);

    dim3 gq((n + 127) / 128, 4);
    k_quant3<<<gq, 256, 0, stream>>>(bufB, cent, bufA, balance, n);

    dim3 g3((n + 127) / 128, 1);
    k_gemm<<<g3, 256, 0, stream>>>(bufA, W2, bufB, n, 128, 256);
    k_agg2<<<(n + 3) / 4, 256, 0, stream>>>(bufB, dinv, csr_src, csr_norm,
                                            row_start, cnt, b2, out, n);
    k_reg<<<1, 512, 0, stream>>>(balance, out + (size_t)n * 128, 1.0f / (float)n);
}

// Round 4
// 755.682 us; speedup vs baseline: 1.3782x; 1.0879x over previous
//
#include <hip/hip_runtime.h>
#include <math.h>

// ---------------------------------------------------------------------------
// GCN pipeline: conv1(relu) -> conv2(relu) -> quantize(+reg) -> add -> conv3
// All fp32 (argmax in quantize is tie-sensitive; bf16 upstream would flip it).
// ---------------------------------------------------------------------------

// ---------------- CSR build ----------------

__global__ void k_init(int* cnt, int* cursor, int* counter, float* balance, int n) {
    int i = blockIdx.x * blockDim.x + threadIdx.x;
    if (i < n) { cnt[i] = 0; cursor[i] = 0; }
    if (i < 480) balance[i] = 0.f;
    if (i == 0) *counter = 0;
}

__global__ void k_count(const int* __restrict__ dst, int* __restrict__ cnt, int e) {
    int i = blockIdx.x * blockDim.x + threadIdx.x;
    if (i < e) atomicAdd(&cnt[dst[i]], 1);
}

__global__ void k_dinv(const int* __restrict__ cnt, float* __restrict__ dinv, int n) {
    int i = blockIdx.x * blockDim.x + threadIdx.x;
    if (i < n) dinv[i] = rsqrtf((float)cnt[i] + 1.0f);   // +1 self loop
}

__global__ void k_alloc(const int* __restrict__ cnt, int* __restrict__ row_start,
                        int* __restrict__ counter, int n) {
    int i = blockIdx.x * blockDim.x + threadIdx.x;
    if (i < n) row_start[i] = atomicAdd(counter, cnt[i]);
}

__global__ void k_fill(const int* __restrict__ src, const int* __restrict__ dst,
                       const float* __restrict__ dinv, const int* __restrict__ row_start,
                       int* __restrict__ cursor, int* __restrict__ csr_src,
                       float* __restrict__ csr_norm, int e) {
    int i = blockIdx.x * blockDim.x + threadIdx.x;
    if (i >= e) return;
    int s = src[i], d = dst[i];
    int slot = atomicAdd(&cursor[d], 1);
    int idx = row_start[d] + slot;
    csr_src[idx] = s;
    csr_norm[idx] = dinv[s] * dinv[d];
}

// ---------------- fp32 GEMM: C[M,N] = A[M,K] @ B[K,N] ----------------
// 128x128 tile, BK=32, 256 threads, 8x8 per thread (split 4+4 rows/cols).

__global__ __launch_bounds__(256, 2) void k_gemm(const float* __restrict__ A,
                                                 const float* __restrict__ B,
                                                 float* __restrict__ C,
                                                 int M, int N, int K) {
    __shared__ float As[32][132];   // transposed A tile: As[k][m]
    __shared__ float Bs[32][132];   // Bs[k][n]
    const int tid = threadIdx.x;
    const int bm = blockIdx.x * 128;
    const int bn = blockIdx.y * 128;
    const int tx = tid & 15, ty = tid >> 4;
    float acc[2][2][4][4] = {};

    for (int k0 = 0; k0 < K; k0 += 32) {
#pragma unroll
        for (int v = 0; v < 4; ++v) {
            int row = (tid >> 3) + v * 32;
            int col = (tid & 7) * 4;
            float4 a = make_float4(0.f, 0.f, 0.f, 0.f);
            if (bm + row < M) a = *(const float4*)(A + (size_t)(bm + row) * K + k0 + col);
            As[col + 0][row] = a.x;
            As[col + 1][row] = a.y;
            As[col + 2][row] = a.z;
            As[col + 3][row] = a.w;
        }
#pragma unroll
        for (int v = 0; v < 4; ++v) {
            int kr = (tid >> 5) + v * 8;
            int col = (tid & 31) * 4;
            *(float4*)&Bs[kr][col] = *(const float4*)(B + (size_t)(k0 + kr) * N + bn + col);
        }
        __syncthreads();
#pragma unroll
        for (int kk = 0; kk < 32; ++kk) {
            float4 a0 = *(float4*)&As[kk][ty * 4];
            float4 a1 = *(float4*)&As[kk][64 + ty * 4];
            float4 b0 = *(float4*)&Bs[kk][tx * 4];
            float4 b1 = *(float4*)&Bs[kk][64 + tx * 4];
            float av[2][4] = {{a0.x, a0.y, a0.z, a0.w}, {a1.x, a1.y, a1.z, a1.w}};
            float bv[2][4] = {{b0.x, b0.y, b0.z, b0.w}, {b1.x, b1.y, b1.z, b1.w}};
#pragma unroll
            for (int ri = 0; ri < 2; ++ri)
#pragma unroll
                for (int i = 0; i < 4; ++i)
#pragma unroll
                    for (int ci = 0; ci < 2; ++ci)
#pragma unroll
                        for (int j = 0; j < 4; ++j)
                            acc[ri][ci][i][j] += av[ri][i] * bv[ci][j];
        }
        __syncthreads();
    }
#pragma unroll
    for (int ri = 0; ri < 2; ++ri)
#pragma unroll
        for (int i = 0; i < 4; ++i) {
            int row = bm + ri * 64 + ty * 4 + i;
            if (row < M) {
#pragma unroll
                for (int ci = 0; ci < 2; ++ci) {
                    float4 o = make_float4(acc[ri][ci][i][0], acc[ri][ci][i][1],
                                           acc[ri][ci][i][2], acc[ri][ci][i][3]);
                    *(float4*)(C + (size_t)row * N + bn + ci * 64 + tx * 4) = o;
                }
            }
        }
}

// ---------------- Aggregation (gather over CSR), one wave per node ----------------

template <bool RELU>
__global__ __launch_bounds__(256) void k_agg4(const float* __restrict__ xw,
                                              const float* __restrict__ dinv,
                                              const int* __restrict__ csr_src,
                                              const float* __restrict__ csr_norm,
                                              const int* __restrict__ row_start,
                                              const int* __restrict__ cnt,
                                              const float* __restrict__ bias,
                                              float* __restrict__ out, int n) {
    int node = blockIdx.x * 4 + (threadIdx.x >> 6);
    if (node >= n) return;
    int lane = threadIdx.x & 63;
    int c = lane * 4;
    float di = dinv[node];
    float4 self = *(const float4*)(xw + (size_t)node * 256 + c);
    float4 bv = *(const float4*)(bias + c);
    float sw = di * di;
    float ax = self.x * sw + bv.x;
    float ay = self.y * sw + bv.y;
    float az = self.z * sw + bv.z;
    float aw = self.w * sw + bv.w;
    int st = row_start[node];
    int m = cnt[node];
#pragma unroll 4
    for (int t = 0; t < m; ++t) {
        int s = csr_src[st + t];
        float w = csr_norm[st + t];
        float4 v = *(const float4*)(xw + (size_t)s * 256 + c);
        ax += v.x * w; ay += v.y * w; az += v.z * w; aw += v.w * w;
    }
    if (RELU) {
        ax = ax > 0.f ? ax : 0.5f * ax;
        ay = ay > 0.f ? ay : 0.5f * ay;
        az = az > 0.f ? az : 0.5f * az;
        aw = aw > 0.f ? aw : 0.5f * aw;
    }
    *(float4*)(out + (size_t)node * 256 + c) = make_float4(ax, ay, az, aw);
}

__global__ __launch_bounds__(256) void k_agg2(const float* __restrict__ xw,
                                              const float* __restrict__ dinv,
                                              const int* __restrict__ csr_src,
                                              const float* __restrict__ csr_norm,
                                              const int* __restrict__ row_start,
                                              const int* __restrict__ cnt,
                                              const float* __restrict__ bias,
                                              float* __restrict__ out, int n) {
    int node = blockIdx.x * 4 + (threadIdx.x >> 6);
    if (node >= n) return;
    int lane = threadIdx.x & 63;
    int c = lane * 2;
    float di = dinv[node];
    float2 self = *(const float2*)(xw + (size_t)node * 128 + c);
    float2 bv = *(const float2*)(bias + c);
    float sw = di * di;
    float ax = self.x * sw + bv.x;
    float ay = self.y * sw + bv.y;
    int st = row_start[node];
    int m = cnt[node];
#pragma unroll 4
    for (int t = 0; t < m; ++t) {
        int s = csr_src[st + t];
        float w = csr_norm[st + t];
        float2 v = *(const float2*)(xw + (size_t)s * 128 + c);
        ax += v.x * w; ay += v.y * w;
    }
    *(float2*)(out + (size_t)node * 128 + c) = make_float2(ax, ay);
}

// ---------------- Quantize v4 (softmax fully in registers) ----------------
// grid (ceil(n/128), 4=d), 256 threads. 128 nodes x 120 cents, K=64 in 2 chunks.
// Thread (ty=tid>>4, tx=tid&15) owns acc[8 nodes][8 cents = tx*8..tx*8+7].
// Group boundaries (8,24,56,120) are multiples of 8 -> each tx lane belongs to
// exactly one group: g0={tx0} g1={tx1,2} g2={tx3..6} g3={tx7..14} tx15=pad.
// Softmax/argmax/balance per group via masked __shfl butterflies -> NO prods
// in LDS (kills round-3's P3 conflicts + 70KB LDS). LDS = As+Bs only (38KB)
// -> 4 blocks/CU (50% occ). Bs stored granule-swizzled (g=2t+h -> t+16h) so
// P1 cent reads are two contiguous-256B b128 sweeps (2-way = free).

__global__ __launch_bounds__(256, 4) void k_quant4(const float* __restrict__ h2,
                                                   const float* __restrict__ cent,
                                                   float* __restrict__ h3,
                                                   float* __restrict__ balance_g, int n) {
    __shared__ float As[32 * 132];     // As[k][node]
    __shared__ float Bs[32 * 132];     // Bs[k][swizzled cent col]
    __shared__ float bal4[4 * 128];    // per-wave balance slices
    __shared__ int km_ls[128 * 4];
    const int tid = threadIdx.x;
    const int n0 = blockIdx.x * 128;
    const int d = blockIdx.y;
    const int ty = tid >> 4, tx = tid & 15;
    const int wave = tid >> 6, lane = tid & 63;

    // group params from tx
    int gid, base, sz;
    if (tx == 0)       { gid = 0; base = 0;  sz = 1; }
    else if (tx <= 2)  { gid = 1; base = 1;  sz = 2; }
    else if (tx <= 6)  { gid = 2; base = 3;  sz = 4; }
    else if (tx <= 14) { gid = 3; base = 7;  sz = 8; }
    else               { gid = 0; base = 15; sz = 0; }   // pad lane
    const int l = tx - base;
    const int segbase = lane & 48;     // 16-lane segment start within wave

    // zero swizzled pad columns (cents 120..127 -> cols 60..63 and 124..127)
    {
        int k = tid >> 3, r = tid & 7;
        int col = (r < 4) ? (60 + r) : (120 + r);
        Bs[k * 132 + col] = 0.f;
    }

    float acc[8][8] = {};
    for (int c0 = 0; c0 < 64; c0 += 32) {
        // stage As: h2 tile transposed (zeros for tail rows)
#pragma unroll
        for (int it = 0; it < 4; ++it) {
            int q = it * 256 + tid;            // 1024 quads = 128 rows x 8
            int row = q >> 3, k4 = q & 7;
            float4 v = make_float4(0.f, 0.f, 0.f, 0.f);
            if (n0 + row < n)
                v = *(const float4*)(h2 + (size_t)(n0 + row) * 256 + d * 64 + c0 + k4 * 4);
            As[(k4 * 4 + 0) * 132 + row] = v.x;
            As[(k4 * 4 + 1) * 132 + row] = v.y;
            As[(k4 * 4 + 2) * 132 + row] = v.z;
            As[(k4 * 4 + 3) * 132 + row] = v.w;
        }
        // stage Bs: cent^T, granule-swizzled columns
#pragma unroll
        for (int it = 0; it < 4; ++it) {
            int q = it * 256 + tid;            // 960 quads = 120 cents x 8
            if (q < 960) {
                int c = q >> 3, k4 = q & 7;
                float4 v = *(const float4*)(cent + (size_t)c * 256 + d * 64 + c0 + k4 * 4);
                int col = ((c >> 3) << 2) + (((c >> 2) & 1) << 6) + (c & 3);
                Bs[(k4 * 4 + 0) * 132 + col] = v.x;
                Bs[(k4 * 4 + 1) * 132 + col] = v.y;
                Bs[(k4 * 4 + 2) * 132 + col] = v.z;
                Bs[(k4 * 4 + 3) * 132 + col] = v.w;
            }
        }
        __syncthreads();
        // P1: register GEMM, 8 nodes x 8 cents per thread
#pragma unroll 4
        for (int k = 0; k < 32; ++k) {
            float4 a0 = *(const float4*)&As[k * 132 + ty * 8];
            float4 a1 = *(const float4*)&As[k * 132 + ty * 8 + 4];
            float4 b0 = *(const float4*)&Bs[k * 132 + tx * 4];        // cents tx*8..+3
            float4 b1 = *(const float4*)&Bs[k * 132 + 64 + tx * 4];   // cents tx*8+4..+7
            float av[8] = {a0.x, a0.y, a0.z, a0.w, a1.x, a1.y, a1.z, a1.w};
            float bv[8] = {b0.x, b0.y, b0.z, b0.w, b1.x, b1.y, b1.z, b1.w};
#pragma unroll
            for (int i = 0; i < 8; ++i)
#pragma unroll
                for (int j = 0; j < 8; ++j)
                    acc[i][j] += av[i] * bv[j];
        }
        __syncthreads();   // before restaging
    }

    // P2: per-group softmax/argmax/balance, all in registers
    float balp[8] = {};
#pragma unroll
    for (int i = 0; i < 8; ++i) {
        const int node = ty * 8 + i;
        const bool act = (n0 + node) < n;
        // in-lane first-max
        float m = acc[i][0];
        int am = tx * 8;
#pragma unroll
        for (int j = 1; j < 8; ++j)
            if (acc[i][j] > m) { m = acc[i][j]; am = tx * 8 + j; }
        // cross-lane butterfly (exact first-max tie-break)
#pragma unroll
        for (int s = 1; s <= 4; s <<= 1) {
            int pl = l ^ s;
            int srcl = segbase + base + pl;
            float mo = __shfl(m, srcl, 64);
            int amo = __shfl(am, srcl, 64);
            if (pl < sz && (mo > m || (mo == m && amo < am))) { m = mo; am = amo; }
        }
        // exp + group-sum
        float Z = 0.f;
#pragma unroll
        for (int j = 0; j < 8; ++j) {
            float e2 = expf(acc[i][j] - m);
            acc[i][j] = e2;
            Z += e2;
        }
#pragma unroll
        for (int s = 1; s <= 4; s <<= 1) {
            int pl = l ^ s;
            int srcl = segbase + base + pl;
            float Zo = __shfl(Z, srcl, 64);
            if (pl < sz) Z += Zo;
        }
        float invZ = (act && sz > 0) ? (1.0f / Z) : 0.f;
#pragma unroll
        for (int j = 0; j < 8; ++j) balp[j] += acc[i][j] * invZ;
        if (l == 0 && sz > 0) km_ls[node * 4 + gid] = am;
    }

    // balance: sum the 4 ty-segments within each wave, store per-wave slice
#pragma unroll
    for (int j = 0; j < 8; ++j) {
        float v = balp[j];
        v += __shfl_xor(v, 16, 64);
        v += __shfl_xor(v, 32, 64);
        balp[j] = v;
    }
    if (lane < 16) {
#pragma unroll
        for (int j = 0; j < 8; ++j)
            bal4[wave * 128 + tx * 8 + j] = balp[j];
    }
    __syncthreads();
    if (tid < 120) {
        float s = bal4[tid] + bal4[128 + tid] + bal4[256 + tid] + bal4[384 + tid];
        atomicAdd(&balance_g[tid * 4 + d], s);
    }

    // P4: h3 = h2 + max_j cent[km_j], 2 threads per node (32 floats each)
    {
        const int node = tid >> 1;
        const int half = tid & 1;
        if (n0 + node < n) {
            int k0 = km_ls[node * 4 + 0], k1 = km_ls[node * 4 + 1];
            int k2 = km_ls[node * 4 + 2], k3 = km_ls[node * 4 + 3];
            const float* hp = h2 + (size_t)(n0 + node) * 256 + d * 64 + half * 32;
            const float* c0 = cent + (size_t)k0 * 256 + d * 64 + half * 32;
            const float* c1 = cent + (size_t)k1 * 256 + d * 64 + half * 32;
            const float* c2 = cent + (size_t)k2 * 256 + d * 64 + half * 32;
            const float* c3 = cent + (size_t)k3 * 256 + d * 64 + half * 32;
            float* op = h3 + (size_t)(n0 + node) * 256 + d * 64 + half * 32;
#pragma unroll
            for (int q = 0; q < 8; ++q) {
                int g = q * 4;
                float4 hv = *(const float4*)(hp + g);
                float4 v0 = *(const float4*)(c0 + g);
                float4 v1 = *(const float4*)(c1 + g);
                float4 v2 = *(const float4*)(c2 + g);
                float4 v3 = *(const float4*)(c3 + g);
                float4 r;
                r.x = hv.x + fmaxf(fmaxf(v0.x, v1.x), fmaxf(v2.x, v3.x));
                r.y = hv.y + fmaxf(fmaxf(v0.y, v1.y), fmaxf(v2.y, v3.y));
                r.z = hv.z + fmaxf(fmaxf(v0.z, v1.z), fmaxf(v2.z, v3.z));
                r.w = hv.w + fmaxf(fmaxf(v0.w, v1.w), fmaxf(v2.w, v3.w));
                *(float4*)(op + g) = r;
            }
        }
    }
}

__global__ void k_reg(const float* __restrict__ balance_g, float* __restrict__ out_reg,
                      float inv_n) {
    __shared__ float red[512];
    int tid = threadIdx.x;
    float v = 0.f;
    if (tid < 480) {
        int k = tid >> 2;
        float target = (k < 8) ? 0.125f : (k < 24) ? 0.0625f : (k < 56) ? 0.03125f : 0.015625f;
        float b = balance_g[tid] * inv_n;
        float df = b - target;
        v = df * df;
    }
    red[tid] = v;
    __syncthreads();
    for (int s = 256; s > 0; s >>= 1) {
        if (tid < s) red[tid] += red[tid + s];
        __syncthreads();
    }
    if (tid == 0) *out_reg = sqrtf(red[0]);
}

// ---------------- host launch ----------------

extern "C" void kernel_launch(void* const* d_in, const int* in_sizes, int n_in,
                              void* d_out, int out_size, void* d_ws, size_t ws_size,
                              hipStream_t stream) {
    const float* x    = (const float*)d_in[0];
    const int*   ei   = (const int*)d_in[1];
    const float* W0   = (const float*)d_in[2];
    const float* b0   = (const float*)d_in[3];
    const float* W1   = (const float*)d_in[4];
    const float* b1   = (const float*)d_in[5];
    const float* W2   = (const float*)d_in[6];
    const float* b2   = (const float*)d_in[7];
    const float* cent = (const float*)d_in[8];
    const int n = in_sizes[0] / 256;
    const int e = in_sizes[1] / 2;
    const int* src = ei;
    const int* dst = ei + e;
    float* out = (float*)d_out;

    char* w = (char*)d_ws;
    float* bufA = (float*)w;      w += (size_t)n * 256 * 4;
    float* bufB = (float*)w;      w += (size_t)n * 256 * 4;
    float* dinv = (float*)w;      w += (size_t)n * 4;
    int* cnt = (int*)w;           w += (size_t)n * 4;
    int* row_start = (int*)w;     w += (size_t)n * 4;
    int* cursor = (int*)w;        w += (size_t)n * 4;
    int* csr_src = (int*)w;       w += (size_t)e * 4;
    float* csr_norm = (float*)w;  w += (size_t)e * 4;
    int* counter = (int*)w;       w += 256;
    float* balance = (float*)w;   w += 480 * 4;

    const int tb = 256;
    k_init<<<(n + tb - 1) / tb, tb, 0, stream>>>(cnt, cursor, counter, balance, n);
    k_count<<<(e + tb - 1) / tb, tb, 0, stream>>>(dst, cnt, e);
    k_dinv<<<(n + tb - 1) / tb, tb, 0, stream>>>(cnt, dinv, n);
    k_alloc<<<(n + tb - 1) / tb, tb, 0, stream>>>(cnt, row_start, counter, n);
    k_fill<<<(e + tb - 1) / tb, tb, 0, stream>>>(src, dst, dinv, row_start, cursor,
                                                 csr_src, csr_norm, e);

    dim3 g1((n + 127) / 128, 2);
    k_gemm<<<g1, 256, 0, stream>>>(x, W0, bufA, n, 256, 256);
    k_agg4<true><<<(n + 3) / 4, 256, 0, stream>>>(bufA, dinv, csr_src, csr_norm,
                                                  row_start, cnt, b0, bufB, n);
    k_gemm<<<g1, 256, 0, stream>>>(bufB, W1, bufA, n, 256, 256);
    k_agg4<true><<<(n + 3) / 4, 256, 0, stream>>>(bufA, dinv, csr_src, csr_norm,
                                                  row_start, cnt, b1, bufB, n);

    dim3 gq((n + 127) / 128, 4);
    k_quant4<<<gq, 256, 0, stream>>>(bufB, cent, bufA, balance, n);

    dim3 g3((n + 127) / 128, 1);
    k_gemm<<<g3, 256, 0, stream>>>(bufA, W2, bufB, n, 128, 256);
    k_agg2<<<(n + 3) / 4, 256, 0, stream>>>(bufB, dinv, csr_src, csr_norm,
                                            row_start, cnt, b2, out, n);
    k_reg<<<1, 512, 0, stream>>>(balance, out + (size_t)n * 128, 1.0f / (float)n);
}

// Round 5
// 750.735 us; speedup vs baseline: 1.3873x; 1.0066x over previous
//
#include <hip/hip_runtime.h>
#include <math.h>

// ---------------------------------------------------------------------------
// GCN pipeline: conv1(relu) -> conv2(relu) -> quantize(+reg) -> add -> conv3
// All fp32 (argmax in quantize is tie-sensitive; bf16 upstream would flip it).
// ---------------------------------------------------------------------------

// ---------------- CSR build ----------------

__global__ void k_init(int* cnt, int* cursor, int* counter, float* balance, int n) {
    int i = blockIdx.x * blockDim.x + threadIdx.x;
    if (i < n) { cnt[i] = 0; cursor[i] = 0; }
    if (i < 480) balance[i] = 0.f;
    if (i == 0) *counter = 0;
}

__global__ void k_count(const int* __restrict__ dst, int* __restrict__ cnt, int e) {
    int i = blockIdx.x * blockDim.x + threadIdx.x;
    if (i < e) atomicAdd(&cnt[dst[i]], 1);
}

__global__ void k_dinv(const int* __restrict__ cnt, float* __restrict__ dinv, int n) {
    int i = blockIdx.x * blockDim.x + threadIdx.x;
    if (i < n) dinv[i] = rsqrtf((float)cnt[i] + 1.0f);   // +1 self loop
}

__global__ void k_alloc(const int* __restrict__ cnt, int* __restrict__ row_start,
                        int* __restrict__ counter, int n) {
    int i = blockIdx.x * blockDim.x + threadIdx.x;
    if (i < n) row_start[i] = atomicAdd(counter, cnt[i]);
}

__global__ void k_fill(const int* __restrict__ src, const int* __restrict__ dst,
                       const float* __restrict__ dinv, const int* __restrict__ row_start,
                       int* __restrict__ cursor, int* __restrict__ csr_src,
                       float* __restrict__ csr_norm, int e) {
    int i = blockIdx.x * blockDim.x + threadIdx.x;
    if (i >= e) return;
    int s = src[i], d = dst[i];
    int slot = atomicAdd(&cursor[d], 1);
    int idx = row_start[d] + slot;
    csr_src[idx] = s;
    csr_norm[idx] = dinv[s] * dinv[d];
}

// ---------------- fp32 GEMM: C[M,N] = A[M,K] @ B[K,N] ----------------
// 128x128 tile, BK=32, 256 threads, 8x8 per thread (split 4+4 rows/cols).

__global__ __launch_bounds__(256, 2) void k_gemm(const float* __restrict__ A,
                                                 const float* __restrict__ B,
                                                 float* __restrict__ C,
                                                 int M, int N, int K) {
    __shared__ float As[32][132];   // transposed A tile: As[k][m]
    __shared__ float Bs[32][132];   // Bs[k][n]
    const int tid = threadIdx.x;
    const int bm = blockIdx.x * 128;
    const int bn = blockIdx.y * 128;
    const int tx = tid & 15, ty = tid >> 4;
    float acc[2][2][4][4] = {};

    for (int k0 = 0; k0 < K; k0 += 32) {
#pragma unroll
        for (int v = 0; v < 4; ++v) {
            int row = (tid >> 3) + v * 32;
            int col = (tid & 7) * 4;
            float4 a = make_float4(0.f, 0.f, 0.f, 0.f);
            if (bm + row < M) a = *(const float4*)(A + (size_t)(bm + row) * K + k0 + col);
            As[col + 0][row] = a.x;
            As[col + 1][row] = a.y;
            As[col + 2][row] = a.z;
            As[col + 3][row] = a.w;
        }
#pragma unroll
        for (int v = 0; v < 4; ++v) {
            int kr = (tid >> 5) + v * 8;
            int col = (tid & 31) * 4;
            *(float4*)&Bs[kr][col] = *(const float4*)(B + (size_t)(k0 + kr) * N + bn + col);
        }
        __syncthreads();
#pragma unroll
        for (int kk = 0; kk < 32; ++kk) {
            float4 a0 = *(float4*)&As[kk][ty * 4];
            float4 a1 = *(float4*)&As[kk][64 + ty * 4];
            float4 b0 = *(float4*)&Bs[kk][tx * 4];
            float4 b1 = *(float4*)&Bs[kk][64 + tx * 4];
            float av[2][4] = {{a0.x, a0.y, a0.z, a0.w}, {a1.x, a1.y, a1.z, a1.w}};
            float bv[2][4] = {{b0.x, b0.y, b0.z, b0.w}, {b1.x, b1.y, b1.z, b1.w}};
#pragma unroll
            for (int ri = 0; ri < 2; ++ri)
#pragma unroll
                for (int i = 0; i < 4; ++i)
#pragma unroll
                    for (int ci = 0; ci < 2; ++ci)
#pragma unroll
                        for (int j = 0; j < 4; ++j)
                            acc[ri][ci][i][j] += av[ri][i] * bv[ci][j];
        }
        __syncthreads();
    }
#pragma unroll
    for (int ri = 0; ri < 2; ++ri)
#pragma unroll
        for (int i = 0; i < 4; ++i) {
            int row = bm + ri * 64 + ty * 4 + i;
            if (row < M) {
#pragma unroll
                for (int ci = 0; ci < 2; ++ci) {
                    float4 o = make_float4(acc[ri][ci][i][0], acc[ri][ci][i][1],
                                           acc[ri][ci][i][2], acc[ri][ci][i][3]);
                    *(float4*)(C + (size_t)row * N + bn + ci * 64 + tx * 4) = o;
                }
            }
        }
}

// ---------------- Aggregation (gather over CSR), one wave per node ----------------
// v2: wave cooperatively loads 64 (src,norm) pairs in 2 coalesced loads, then
// broadcasts via __shfl -> row gathers have NO index-load on the critical path
// (round-4 lesson: dependent idx loads capped MLP; VALUBusy was 9.7%).

template <bool RELU>
__global__ __launch_bounds__(256) void k_agg4(const float* __restrict__ xw,
                                              const float* __restrict__ dinv,
                                              const int* __restrict__ csr_src,
                                              const float* __restrict__ csr_norm,
                                              const int* __restrict__ row_start,
                                              const int* __restrict__ cnt,
                                              const float* __restrict__ bias,
                                              float* __restrict__ out, int n) {
    int node = blockIdx.x * 4 + (threadIdx.x >> 6);
    if (node >= n) return;
    int lane = threadIdx.x & 63;
    int c = lane * 4;
    float di = dinv[node];
    float4 self = *(const float4*)(xw + (size_t)node * 256 + c);
    float4 bv = *(const float4*)(bias + c);
    float sw = di * di;
    float ax = self.x * sw + bv.x;
    float ay = self.y * sw + bv.y;
    float az = self.z * sw + bv.z;
    float aw = self.w * sw + bv.w;
    int st = row_start[node];
    int m = cnt[node];
    for (int t0 = 0; t0 < m; t0 += 64) {
        int rem = m - t0;
        int cnt_i = rem < 64 ? rem : 64;
        int idx_l = 0;
        float nrm_l = 0.f;
        if (lane < cnt_i) {
            idx_l = csr_src[st + t0 + lane];
            nrm_l = csr_norm[st + t0 + lane];
        }
#pragma unroll 8
        for (int t = 0; t < cnt_i; ++t) {
            int s = __shfl(idx_l, t, 64);
            float w = __shfl(nrm_l, t, 64);
            float4 v = *(const float4*)(xw + (size_t)s * 256 + c);
            ax += v.x * w; ay += v.y * w; az += v.z * w; aw += v.w * w;
        }
    }
    if (RELU) {
        ax = ax > 0.f ? ax : 0.5f * ax;
        ay = ay > 0.f ? ay : 0.5f * ay;
        az = az > 0.f ? az : 0.5f * az;
        aw = aw > 0.f ? aw : 0.5f * aw;
    }
    *(float4*)(out + (size_t)node * 256 + c) = make_float4(ax, ay, az, aw);
}

__global__ __launch_bounds__(256) void k_agg2(const float* __restrict__ xw,
                                              const float* __restrict__ dinv,
                                              const int* __restrict__ csr_src,
                                              const float* __restrict__ csr_norm,
                                              const int* __restrict__ row_start,
                                              const int* __restrict__ cnt,
                                              const float* __restrict__ bias,
                                              float* __restrict__ out, int n) {
    int node = blockIdx.x * 4 + (threadIdx.x >> 6);
    if (node >= n) return;
    int lane = threadIdx.x & 63;
    int c = lane * 2;
    float di = dinv[node];
    float2 self = *(const float2*)(xw + (size_t)node * 128 + c);
    float2 bv = *(const float2*)(bias + c);
    float sw = di * di;
    float ax = self.x * sw + bv.x;
    float ay = self.y * sw + bv.y;
    int st = row_start[node];
    int m = cnt[node];
    for (int t0 = 0; t0 < m; t0 += 64) {
        int rem = m - t0;
        int cnt_i = rem < 64 ? rem : 64;
        int idx_l = 0;
        float nrm_l = 0.f;
        if (lane < cnt_i) {
            idx_l = csr_src[st + t0 + lane];
            nrm_l = csr_norm[st + t0 + lane];
        }
#pragma unroll 8
        for (int t = 0; t < cnt_i; ++t) {
            int s = __shfl(idx_l, t, 64);
            float w = __shfl(nrm_l, t, 64);
            float2 v = *(const float2*)(xw + (size_t)s * 128 + c);
            ax += v.x * w; ay += v.y * w;
        }
    }
    *(float2*)(out + (size_t)node * 128 + c) = make_float2(ax, ay);
}

// ---------------- Quantize v4 (softmax fully in registers) ----------------
// grid (ceil(n/128), 4=d), 256 threads. 128 nodes x 120 cents, K=64 in 2 chunks.
// Thread (ty=tid>>4, tx=tid&15) owns acc[8 nodes][8 cents = tx*8..tx*8+7].
// Group boundaries (8,24,56,120) are multiples of 8 -> each tx lane belongs to
// exactly one group: g0={tx0} g1={tx1,2} g2={tx3..6} g3={tx7..14} tx15=pad.
// Softmax/argmax/balance per group via masked __shfl butterflies -> NO prods
// in LDS. LDS = As+Bs only (38KB) -> 4 blocks/CU. Bs granule-swizzled.

__global__ __launch_bounds__(256, 4) void k_quant4(const float* __restrict__ h2,
                                                   const float* __restrict__ cent,
                                                   float* __restrict__ h3,
                                                   float* __restrict__ balance_g, int n) {
    __shared__ float As[32 * 132];     // As[k][node]
    __shared__ float Bs[32 * 132];     // Bs[k][swizzled cent col]
    __shared__ float bal4[4 * 128];    // per-wave balance slices
    __shared__ int km_ls[128 * 4];
    const int tid = threadIdx.x;
    const int n0 = blockIdx.x * 128;
    const int d = blockIdx.y;
    const int ty = tid >> 4, tx = tid & 15;
    const int wave = tid >> 6, lane = tid & 63;

    // group params from tx
    int gid, base, sz;
    if (tx == 0)       { gid = 0; base = 0;  sz = 1; }
    else if (tx <= 2)  { gid = 1; base = 1;  sz = 2; }
    else if (tx <= 6)  { gid = 2; base = 3;  sz = 4; }
    else if (tx <= 14) { gid = 3; base = 7;  sz = 8; }
    else               { gid = 0; base = 15; sz = 0; }   // pad lane
    const int l = tx - base;
    const int segbase = lane & 48;     // 16-lane segment start within wave

    // zero swizzled pad columns (cents 120..127 -> cols 60..63 and 124..127)
    {
        int k = tid >> 3, r = tid & 7;
        int col = (r < 4) ? (60 + r) : (120 + r);
        Bs[k * 132 + col] = 0.f;
    }

    float acc[8][8] = {};
    for (int c0 = 0; c0 < 64; c0 += 32) {
        // stage As: h2 tile transposed (zeros for tail rows)
#pragma unroll
        for (int it = 0; it < 4; ++it) {
            int q = it * 256 + tid;            // 1024 quads = 128 rows x 8
            int row = q >> 3, k4 = q & 7;
            float4 v = make_float4(0.f, 0.f, 0.f, 0.f);
            if (n0 + row < n)
                v = *(const float4*)(h2 + (size_t)(n0 + row) * 256 + d * 64 + c0 + k4 * 4);
            As[(k4 * 4 + 0) * 132 + row] = v.x;
            As[(k4 * 4 + 1) * 132 + row] = v.y;
            As[(k4 * 4 + 2) * 132 + row] = v.z;
            As[(k4 * 4 + 3) * 132 + row] = v.w;
        }
        // stage Bs: cent^T, granule-swizzled columns
#pragma unroll
        for (int it = 0; it < 4; ++it) {
            int q = it * 256 + tid;            // 960 quads = 120 cents x 8
            if (q < 960) {
                int c = q >> 3, k4 = q & 7;
                float4 v = *(const float4*)(cent + (size_t)c * 256 + d * 64 + c0 + k4 * 4);
                int col = ((c >> 3) << 2) + (((c >> 2) & 1) << 6) + (c & 3);
                Bs[(k4 * 4 + 0) * 132 + col] = v.x;
                Bs[(k4 * 4 + 1) * 132 + col] = v.y;
                Bs[(k4 * 4 + 2) * 132 + col] = v.z;
                Bs[(k4 * 4 + 3) * 132 + col] = v.w;
            }
        }
        __syncthreads();
        // P1: register GEMM, 8 nodes x 8 cents per thread
#pragma unroll 4
        for (int k = 0; k < 32; ++k) {
            float4 a0 = *(const float4*)&As[k * 132 + ty * 8];
            float4 a1 = *(const float4*)&As[k * 132 + ty * 8 + 4];
            float4 b0 = *(const float4*)&Bs[k * 132 + tx * 4];        // cents tx*8..+3
            float4 b1 = *(const float4*)&Bs[k * 132 + 64 + tx * 4];   // cents tx*8+4..+7
            float av[8] = {a0.x, a0.y, a0.z, a0.w, a1.x, a1.y, a1.z, a1.w};
            float bv[8] = {b0.x, b0.y, b0.z, b0.w, b1.x, b1.y, b1.z, b1.w};
#pragma unroll
            for (int i = 0; i < 8; ++i)
#pragma unroll
                for (int j = 0; j < 8; ++j)
                    acc[i][j] += av[i] * bv[j];
        }
        __syncthreads();   // before restaging
    }

    // P2: per-group softmax/argmax/balance, all in registers
    float balp[8] = {};
#pragma unroll
    for (int i = 0; i < 8; ++i) {
        const int node = ty * 8 + i;
        const bool act = (n0 + node) < n;
        // in-lane first-max
        float m = acc[i][0];
        int am = tx * 8;
#pragma unroll
        for (int j = 1; j < 8; ++j)
            if (acc[i][j] > m) { m = acc[i][j]; am = tx * 8 + j; }
        // cross-lane butterfly (exact first-max tie-break)
#pragma unroll
        for (int s = 1; s <= 4; s <<= 1) {
            int pl = l ^ s;
            int srcl = segbase + base + pl;
            float mo = __shfl(m, srcl, 64);
            int amo = __shfl(am, srcl, 64);
            if (pl < sz && (mo > m || (mo == m && amo < am))) { m = mo; am = amo; }
        }
        // exp + group-sum
        float Z = 0.f;
#pragma unroll
        for (int j = 0; j < 8; ++j) {
            float e2 = expf(acc[i][j] - m);
            acc[i][j] = e2;
            Z += e2;
        }
#pragma unroll
        for (int s = 1; s <= 4; s <<= 1) {
            int pl = l ^ s;
            int srcl = segbase + base + pl;
            float Zo = __shfl(Z, srcl, 64);
            if (pl < sz) Z += Zo;
        }
        float invZ = (act && sz > 0) ? (1.0f / Z) : 0.f;
#pragma unroll
        for (int j = 0; j < 8; ++j) balp[j] += acc[i][j] * invZ;
        if (l == 0 && sz > 0) km_ls[node * 4 + gid] = am;
    }

    // balance: sum the 4 ty-segments within each wave, store per-wave slice
#pragma unroll
    for (int j = 0; j < 8; ++j) {
        float v = balp[j];
        v += __shfl_xor(v, 16, 64);
        v += __shfl_xor(v, 32, 64);
        balp[j] = v;
    }
    if (lane < 16) {
#pragma unroll
        for (int j = 0; j < 8; ++j)
            bal4[wave * 128 + tx * 8 + j] = balp[j];
    }
    __syncthreads();
    if (tid < 120) {
        float s = bal4[tid] + bal4[128 + tid] + bal4[256 + tid] + bal4[384 + tid];
        atomicAdd(&balance_g[tid * 4 + d], s);
    }

    // P4: h3 = h2 + max_j cent[km_j], 2 threads per node (32 floats each)
    {
        const int node = tid >> 1;
        const int half = tid & 1;
        if (n0 + node < n) {
            int k0 = km_ls[node * 4 + 0], k1 = km_ls[node * 4 + 1];
            int k2 = km_ls[node * 4 + 2], k3 = km_ls[node * 4 + 3];
            const float* hp = h2 + (size_t)(n0 + node) * 256 + d * 64 + half * 32;
            const float* c0 = cent + (size_t)k0 * 256 + d * 64 + half * 32;
            const float* c1 = cent + (size_t)k1 * 256 + d * 64 + half * 32;
            const float* c2 = cent + (size_t)k2 * 256 + d * 64 + half * 32;
            const float* c3 = cent + (size_t)k3 * 256 + d * 64 + half * 32;
            float* op = h3 + (size_t)(n0 + node) * 256 + d * 64 + half * 32;
#pragma unroll
            for (int q = 0; q < 8; ++q) {
                int g = q * 4;
                float4 hv = *(const float4*)(hp + g);
                float4 v0 = *(const float4*)(c0 + g);
                float4 v1 = *(const float4*)(c1 + g);
                float4 v2 = *(const float4*)(c2 + g);
                float4 v3 = *(const float4*)(c3 + g);
                float4 r;
                r.x = hv.x + fmaxf(fmaxf(v0.x, v1.x), fmaxf(v2.x, v3.x));
                r.y = hv.y + fmaxf(fmaxf(v0.y, v1.y), fmaxf(v2.y, v3.y));
                r.z = hv.z + fmaxf(fmaxf(v0.z, v1.z), fmaxf(v2.z, v3.z));
                r.w = hv.w + fmaxf(fmaxf(v0.w, v1.w), fmaxf(v2.w, v3.w));
                *(float4*)(op + g) = r;
            }
        }
    }
}

__global__ void k_reg(const float* __restrict__ balance_g, float* __restrict__ out_reg,
                      float inv_n) {
    __shared__ float red[512];
    int tid = threadIdx.x;
    float v = 0.f;
    if (tid < 480) {
        int k = tid >> 2;
        float target = (k < 8) ? 0.125f : (k < 24) ? 0.0625f : (k < 56) ? 0.03125f : 0.015625f;
        float b = balance_g[tid] * inv_n;
        float df = b - target;
        v = df * df;
    }
    red[tid] = v;
    __syncthreads();
    for (int s = 256; s > 0; s >>= 1) {
        if (tid < s) red[tid] += red[tid + s];
        __syncthreads();
    }
    if (tid == 0) *out_reg = sqrtf(red[0]);
}

// ---------------- host launch ----------------

extern "C" void kernel_launch(void* const* d_in, const int* in_sizes, int n_in,
                              void* d_out, int out_size, void* d_ws, size_t ws_size,
                              hipStream_t stream) {
    const float* x    = (const float*)d_in[0];
    const int*   ei   = (const int*)d_in[1];
    const float* W0   = (const float*)d_in[2];
    const float* b0   = (const float*)d_in[3];
    const float* W1   = (const float*)d_in[4];
    const float* b1   = (const float*)d_in[5];
    const float* W2   = (const float*)d_in[6];
    const float* b2   = (const float*)d_in[7];
    const float* cent = (const float*)d_in[8];
    const int n = in_sizes[0] / 256;
    const int e = in_sizes[1] / 2;
    const int* src = ei;
    const int* dst = ei + e;
    float* out = (float*)d_out;

    char* w = (char*)d_ws;
    float* bufA = (float*)w;      w += (size_t)n * 256 * 4;
    float* bufB = (float*)w;      w += (size_t)n * 256 * 4;
    float* dinv = (float*)w;      w += (size_t)n * 4;
    int* cnt = (int*)w;           w += (size_t)n * 4;
    int* row_start = (int*)w;     w += (size_t)n * 4;
    int* cursor = (int*)w;        w += (size_t)n * 4;
    int* csr_src = (int*)w;       w += (size_t)e * 4;
    float* csr_norm = (float*)w;  w += (size_t)e * 4;
    int* counter = (int*)w;       w += 256;
    float* balance = (float*)w;   w += 480 * 4;

    const int tb = 256;
    k_init<<<(n + tb - 1) / tb, tb, 0, stream>>>(cnt, cursor, counter, balance, n);
    k_count<<<(e + tb - 1) / tb, tb, 0, stream>>>(dst, cnt, e);
    k_dinv<<<(n + tb - 1) / tb, tb, 0, stream>>>(cnt, dinv, n);
    k_alloc<<<(n + tb - 1) / tb, tb, 0, stream>>>(cnt, row_start, counter, n);
    k_fill<<<(e + tb - 1) / tb, tb, 0, stream>>>(src, dst, dinv, row_start, cursor,
                                                 csr_src, csr_norm, e);

    dim3 g1((n + 127) / 128, 2);
    k_gemm<<<g1, 256, 0, stream>>>(x, W0, bufA, n, 256, 256);
    k_agg4<true><<<(n + 3) / 4, 256, 0, stream>>>(bufA, dinv, csr_src, csr_norm,
                                                  row_start, cnt, b0, bufB, n);
    k_gemm<<<g1, 256, 0, stream>>>(bufB, W1, bufA, n, 256, 256);
    k_agg4<true><<<(n + 3) / 4, 256, 0, stream>>>(bufA, dinv, csr_src, csr_norm,
                                                  row_start, cnt, b1, bufB, n);

    dim3 gq((n + 127) / 128, 4);
    k_quant4<<<gq, 256, 0, stream>>>(bufB, cent, bufA, balance, n);

    dim3 g3((n + 127) / 128, 1);
    k_gemm<<<g3, 256, 0, stream>>>(bufA, W2, bufB, n, 128, 256);
    k_agg2<<<(n + 3) / 4, 256, 0, stream>>>(bufB, dinv, csr_src, csr_norm,
                                            row_start, cnt, b2, out, n);
    k_reg<<<1, 512, 0, stream>>>(balance, out + (size_t)n * 128, 1.0f / (float)n);
}

// Round 6
// 747.049 us; speedup vs baseline: 1.3941x; 1.0049x over previous
//
#include <hip/hip_runtime.h>
#include <math.h>

// ---------------------------------------------------------------------------
// GCN pipeline: conv1(relu) -> conv2(relu) -> quantize(+reg) -> add -> conv3
// All fp32 (argmax in quantize is tie-sensitive; bf16 upstream would flip it).
// ---------------------------------------------------------------------------

// ---------------- CSR build ----------------

__global__ void k_init(int* cnt, int* cursor, int* counter, float* balance, int n) {
    int i = blockIdx.x * blockDim.x + threadIdx.x;
    if (i < n) { cnt[i] = 0; cursor[i] = 0; }
    if (i < 480) balance[i] = 0.f;
    if (i == 0) *counter = 0;
}

__global__ void k_count(const int* __restrict__ dst, int* __restrict__ cnt, int e) {
    int i = blockIdx.x * blockDim.x + threadIdx.x;
    if (i < e) atomicAdd(&cnt[dst[i]], 1);
}

__global__ void k_dinv(const int* __restrict__ cnt, float* __restrict__ dinv, int n) {
    int i = blockIdx.x * blockDim.x + threadIdx.x;
    if (i < n) dinv[i] = rsqrtf((float)cnt[i] + 1.0f);   // +1 self loop
}

__global__ void k_alloc(const int* __restrict__ cnt, int* __restrict__ row_start,
                        int* __restrict__ counter, int n) {
    int i = blockIdx.x * blockDim.x + threadIdx.x;
    if (i < n) row_start[i] = atomicAdd(counter, cnt[i]);
}

__global__ void k_fill(const int* __restrict__ src, const int* __restrict__ dst,
                       const float* __restrict__ dinv, const int* __restrict__ row_start,
                       int* __restrict__ cursor, int* __restrict__ csr_src,
                       float* __restrict__ csr_norm, int e) {
    int i = blockIdx.x * blockDim.x + threadIdx.x;
    if (i >= e) return;
    int s = src[i], d = dst[i];
    int slot = atomicAdd(&cursor[d], 1);
    int idx = row_start[d] + slot;
    csr_src[idx] = s;
    csr_norm[idx] = dinv[s] * dinv[d];
}

// ---------------- fp32 GEMM: C[M,N] = A[M,K] @ B[K,N] ----------------
// 128x128 tile, BK=32, 256 threads, 8x8 per thread (split 4+4 rows/cols).

__global__ __launch_bounds__(256, 2) void k_gemm(const float* __restrict__ A,
                                                 const float* __restrict__ B,
                                                 float* __restrict__ C,
                                                 int M, int N, int K) {
    __shared__ float As[32][132];   // transposed A tile: As[k][m]
    __shared__ float Bs[32][132];   // Bs[k][n]
    const int tid = threadIdx.x;
    const int bm = blockIdx.x * 128;
    const int bn = blockIdx.y * 128;
    const int tx = tid & 15, ty = tid >> 4;
    float acc[2][2][4][4] = {};

    for (int k0 = 0; k0 < K; k0 += 32) {
#pragma unroll
        for (int v = 0; v < 4; ++v) {
            int row = (tid >> 3) + v * 32;
            int col = (tid & 7) * 4;
            float4 a = make_float4(0.f, 0.f, 0.f, 0.f);
            if (bm + row < M) a = *(const float4*)(A + (size_t)(bm + row) * K + k0 + col);
            As[col + 0][row] = a.x;
            As[col + 1][row] = a.y;
            As[col + 2][row] = a.z;
            As[col + 3][row] = a.w;
        }
#pragma unroll
        for (int v = 0; v < 4; ++v) {
            int kr = (tid >> 5) + v * 8;
            int col = (tid & 31) * 4;
            *(float4*)&Bs[kr][col] = *(const float4*)(B + (size_t)(k0 + kr) * N + bn + col);
        }
        __syncthreads();
#pragma unroll
        for (int kk = 0; kk < 32; ++kk) {
            float4 a0 = *(float4*)&As[kk][ty * 4];
            float4 a1 = *(float4*)&As[kk][64 + ty * 4];
            float4 b0 = *(float4*)&Bs[kk][tx * 4];
            float4 b1 = *(float4*)&Bs[kk][64 + tx * 4];
            float av[2][4] = {{a0.x, a0.y, a0.z, a0.w}, {a1.x, a1.y, a1.z, a1.w}};
            float bv[2][4] = {{b0.x, b0.y, b0.z, b0.w}, {b1.x, b1.y, b1.z, b1.w}};
#pragma unroll
            for (int ri = 0; ri < 2; ++ri)
#pragma unroll
                for (int i = 0; i < 4; ++i)
#pragma unroll
                    for (int ci = 0; ci < 2; ++ci)
#pragma unroll
                        for (int j = 0; j < 4; ++j)
                            acc[ri][ci][i][j] += av[ri][i] * bv[ci][j];
        }
        __syncthreads();
    }
#pragma unroll
    for (int ri = 0; ri < 2; ++ri)
#pragma unroll
        for (int i = 0; i < 4; ++i) {
            int row = bm + ri * 64 + ty * 4 + i;
            if (row < M) {
#pragma unroll
                for (int ci = 0; ci < 2; ++ci) {
                    float4 o = make_float4(acc[ri][ci][i][0], acc[ri][ci][i][1],
                                           acc[ri][ci][i][2], acc[ri][ci][i][3]);
                    *(float4*)(C + (size_t)row * N + bn + ci * 64 + tx * 4) = o;
                }
            }
        }
}

// ---------------- Aggregation (gather over CSR), one wave per node ----------------
// v3: wave loads 64 (src,norm) pairs coalesced, broadcasts via __shfl, and the
// inner loop issues 8 NAMED float4 row loads before any FMA. launch_bounds
// (256,4) permits 64 VGPR so the 8 loads stay in flight (round-5 lesson: the
// compiler minimized to 12 VGPR and serialized the gather -> no MLP).

template <bool RELU>
__global__ __launch_bounds__(256, 4) void k_agg4(const float* __restrict__ xw,
                                                 const float* __restrict__ dinv,
                                                 const int* __restrict__ csr_src,
                                                 const float* __restrict__ csr_norm,
                                                 const int* __restrict__ row_start,
                                                 const int* __restrict__ cnt,
                                                 const float* __restrict__ bias,
                                                 float* __restrict__ out, int n) {
    int node = blockIdx.x * 4 + (threadIdx.x >> 6);
    if (node >= n) return;
    int lane = threadIdx.x & 63;
    int c = lane * 4;
    float di = dinv[node];
    float4 self = *(const float4*)(xw + (size_t)node * 256 + c);
    float4 bv = *(const float4*)(bias + c);
    float sw = di * di;
    float ax = self.x * sw + bv.x;
    float ay = self.y * sw + bv.y;
    float az = self.z * sw + bv.z;
    float aw = self.w * sw + bv.w;
    int st = row_start[node];
    int m = cnt[node];
    for (int t0 = 0; t0 < m; t0 += 64) {
        int rem = m - t0;
        int cnt_i = rem < 64 ? rem : 64;
        int idx_l = 0;
        float nrm_l = 0.f;
        if (lane < cnt_i) {
            idx_l = csr_src[st + t0 + lane];
            nrm_l = csr_norm[st + t0 + lane];
        }
        int t = 0;
        for (; t + 8 <= cnt_i; t += 8) {
            const float* p0 = xw + (size_t)__shfl(idx_l, t + 0, 64) * 256 + c;
            const float* p1 = xw + (size_t)__shfl(idx_l, t + 1, 64) * 256 + c;
            const float* p2 = xw + (size_t)__shfl(idx_l, t + 2, 64) * 256 + c;
            const float* p3 = xw + (size_t)__shfl(idx_l, t + 3, 64) * 256 + c;
            const float* p4 = xw + (size_t)__shfl(idx_l, t + 4, 64) * 256 + c;
            const float* p5 = xw + (size_t)__shfl(idx_l, t + 5, 64) * 256 + c;
            const float* p6 = xw + (size_t)__shfl(idx_l, t + 6, 64) * 256 + c;
            const float* p7 = xw + (size_t)__shfl(idx_l, t + 7, 64) * 256 + c;
            float4 v0 = *(const float4*)p0;
            float4 v1 = *(const float4*)p1;
            float4 v2 = *(const float4*)p2;
            float4 v3 = *(const float4*)p3;
            float4 v4 = *(const float4*)p4;
            float4 v5 = *(const float4*)p5;
            float4 v6 = *(const float4*)p6;
            float4 v7 = *(const float4*)p7;
            float w0 = __shfl(nrm_l, t + 0, 64);
            float w1 = __shfl(nrm_l, t + 1, 64);
            float w2 = __shfl(nrm_l, t + 2, 64);
            float w3 = __shfl(nrm_l, t + 3, 64);
            float w4 = __shfl(nrm_l, t + 4, 64);
            float w5 = __shfl(nrm_l, t + 5, 64);
            float w6 = __shfl(nrm_l, t + 6, 64);
            float w7 = __shfl(nrm_l, t + 7, 64);
            ax += v0.x * w0; ay += v0.y * w0; az += v0.z * w0; aw += v0.w * w0;
            ax += v1.x * w1; ay += v1.y * w1; az += v1.z * w1; aw += v1.w * w1;
            ax += v2.x * w2; ay += v2.y * w2; az += v2.z * w2; aw += v2.w * w2;
            ax += v3.x * w3; ay += v3.y * w3; az += v3.z * w3; aw += v3.w * w3;
            ax += v4.x * w4; ay += v4.y * w4; az += v4.z * w4; aw += v4.w * w4;
            ax += v5.x * w5; ay += v5.y * w5; az += v5.z * w5; aw += v5.w * w5;
            ax += v6.x * w6; ay += v6.y * w6; az += v6.z * w6; aw += v6.w * w6;
            ax += v7.x * w7; ay += v7.y * w7; az += v7.z * w7; aw += v7.w * w7;
        }
        for (; t < cnt_i; ++t) {
            int s = __shfl(idx_l, t, 64);
            float w = __shfl(nrm_l, t, 64);
            float4 v = *(const float4*)(xw + (size_t)s * 256 + c);
            ax += v.x * w; ay += v.y * w; az += v.z * w; aw += v.w * w;
        }
    }
    if (RELU) {
        ax = ax > 0.f ? ax : 0.5f * ax;
        ay = ay > 0.f ? ay : 0.5f * ay;
        az = az > 0.f ? az : 0.5f * az;
        aw = aw > 0.f ? aw : 0.5f * aw;
    }
    *(float4*)(out + (size_t)node * 256 + c) = make_float4(ax, ay, az, aw);
}

__global__ __launch_bounds__(256, 4) void k_agg2(const float* __restrict__ xw,
                                                 const float* __restrict__ dinv,
                                                 const int* __restrict__ csr_src,
                                                 const float* __restrict__ csr_norm,
                                                 const int* __restrict__ row_start,
                                                 const int* __restrict__ cnt,
                                                 const float* __restrict__ bias,
                                                 float* __restrict__ out, int n) {
    int node = blockIdx.x * 4 + (threadIdx.x >> 6);
    if (node >= n) return;
    int lane = threadIdx.x & 63;
    int c = lane * 2;
    float di = dinv[node];
    float2 self = *(const float2*)(xw + (size_t)node * 128 + c);
    float2 bv = *(const float2*)(bias + c);
    float sw = di * di;
    float ax = self.x * sw + bv.x;
    float ay = self.y * sw + bv.y;
    int st = row_start[node];
    int m = cnt[node];
    for (int t0 = 0; t0 < m; t0 += 64) {
        int rem = m - t0;
        int cnt_i = rem < 64 ? rem : 64;
        int idx_l = 0;
        float nrm_l = 0.f;
        if (lane < cnt_i) {
            idx_l = csr_src[st + t0 + lane];
            nrm_l = csr_norm[st + t0 + lane];
        }
        int t = 0;
        for (; t + 8 <= cnt_i; t += 8) {
            const float* p0 = xw + (size_t)__shfl(idx_l, t + 0, 64) * 128 + c;
            const float* p1 = xw + (size_t)__shfl(idx_l, t + 1, 64) * 128 + c;
            const float* p2 = xw + (size_t)__shfl(idx_l, t + 2, 64) * 128 + c;
            const float* p3 = xw + (size_t)__shfl(idx_l, t + 3, 64) * 128 + c;
            const float* p4 = xw + (size_t)__shfl(idx_l, t + 4, 64) * 128 + c;
            const float* p5 = xw + (size_t)__shfl(idx_l, t + 5, 64) * 128 + c;
            const float* p6 = xw + (size_t)__shfl(idx_l, t + 6, 64) * 128 + c;
            const float* p7 = xw + (size_t)__shfl(idx_l, t + 7, 64) * 128 + c;
            float2 v0 = *(const float2*)p0;
            float2 v1 = *(const float2*)p1;
            float2 v2 = *(const float2*)p2;
            float2 v3 = *(const float2*)p3;
            float2 v4 = *(const float2*)p4;
            float2 v5 = *(const float2*)p5;
            float2 v6 = *(const float2*)p6;
            float2 v7 = *(const float2*)p7;
            float w0 = __shfl(nrm_l, t + 0, 64);
            float w1 = __shfl(nrm_l, t + 1, 64);
            float w2 = __shfl(nrm_l, t + 2, 64);
            float w3 = __shfl(nrm_l, t + 3, 64);
            float w4 = __shfl(nrm_l, t + 4, 64);
            float w5 = __shfl(nrm_l, t + 5, 64);
            float w6 = __shfl(nrm_l, t + 6, 64);
            float w7 = __shfl(nrm_l, t + 7, 64);
            ax += v0.x * w0; ay += v0.y * w0;
            ax += v1.x * w1; ay += v1.y * w1;
            ax += v2.x * w2; ay += v2.y * w2;
            ax += v3.x * w3; ay += v3.y * w3;
            ax += v4.x * w4; ay += v4.y * w4;
            ax += v5.x * w5; ay += v5.y * w5;
            ax += v6.x * w6; ay += v6.y * w6;
            ax += v7.x * w7; ay += v7.y * w7;
        }
        for (; t < cnt_i; ++t) {
            int s = __shfl(idx_l, t, 64);
            float w = __shfl(nrm_l, t, 64);
            float2 v = *(const float2*)(xw + (size_t)s * 128 + c);
            ax += v.x * w; ay += v.y * w;
        }
    }
    *(float2*)(out + (size_t)node * 128 + c) = make_float2(ax, ay);
}

// ---------------- Quantize v4 (softmax fully in registers) ----------------
// grid (ceil(n/128), 4=d), 256 threads. 128 nodes x 120 cents, K=64 in 2 chunks.
// Thread (ty=tid>>4, tx=tid&15) owns acc[8 nodes][8 cents = tx*8..tx*8+7].
// Group boundaries (8,24,56,120) are multiples of 8 -> each tx lane belongs to
// exactly one group: g0={tx0} g1={tx1,2} g2={tx3..6} g3={tx7..14} tx15=pad.
// Softmax/argmax/balance per group via masked __shfl butterflies -> NO prods
// in LDS. LDS = As+Bs only (38KB) -> 4 blocks/CU. Bs granule-swizzled.

__global__ __launch_bounds__(256, 4) void k_quant4(const float* __restrict__ h2,
                                                   const float* __restrict__ cent,
                                                   float* __restrict__ h3,
                                                   float* __restrict__ balance_g, int n) {
    __shared__ float As[32 * 132];     // As[k][node]
    __shared__ float Bs[32 * 132];     // Bs[k][swizzled cent col]
    __shared__ float bal4[4 * 128];    // per-wave balance slices
    __shared__ int km_ls[128 * 4];
    const int tid = threadIdx.x;
    const int n0 = blockIdx.x * 128;
    const int d = blockIdx.y;
    const int ty = tid >> 4, tx = tid & 15;
    const int wave = tid >> 6, lane = tid & 63;

    // group params from tx
    int gid, base, sz;
    if (tx == 0)       { gid = 0; base = 0;  sz = 1; }
    else if (tx <= 2)  { gid = 1; base = 1;  sz = 2; }
    else if (tx <= 6)  { gid = 2; base = 3;  sz = 4; }
    else if (tx <= 14) { gid = 3; base = 7;  sz = 8; }
    else               { gid = 0; base = 15; sz = 0; }   // pad lane
    const int l = tx - base;
    const int segbase = lane & 48;     // 16-lane segment start within wave

    // zero swizzled pad columns (cents 120..127 -> cols 60..63 and 124..127)
    {
        int k = tid >> 3, r = tid & 7;
        int col = (r < 4) ? (60 + r) : (120 + r);
        Bs[k * 132 + col] = 0.f;
    }

    float acc[8][8] = {};
    for (int c0 = 0; c0 < 64; c0 += 32) {
        // stage As: h2 tile transposed (zeros for tail rows)
#pragma unroll
        for (int it = 0; it < 4; ++it) {
            int q = it * 256 + tid;            // 1024 quads = 128 rows x 8
            int row = q >> 3, k4 = q & 7;
            float4 v = make_float4(0.f, 0.f, 0.f, 0.f);
            if (n0 + row < n)
                v = *(const float4*)(h2 + (size_t)(n0 + row) * 256 + d * 64 + c0 + k4 * 4);
            As[(k4 * 4 + 0) * 132 + row] = v.x;
            As[(k4 * 4 + 1) * 132 + row] = v.y;
            As[(k4 * 4 + 2) * 132 + row] = v.z;
            As[(k4 * 4 + 3) * 132 + row] = v.w;
        }
        // stage Bs: cent^T, granule-swizzled columns
#pragma unroll
        for (int it = 0; it < 4; ++it) {
            int q = it * 256 + tid;            // 960 quads = 120 cents x 8
            if (q < 960) {
                int c = q >> 3, k4 = q & 7;
                float4 v = *(const float4*)(cent + (size_t)c * 256 + d * 64 + c0 + k4 * 4);
                int col = ((c >> 3) << 2) + (((c >> 2) & 1) << 6) + (c & 3);
                Bs[(k4 * 4 + 0) * 132 + col] = v.x;
                Bs[(k4 * 4 + 1) * 132 + col] = v.y;
                Bs[(k4 * 4 + 2) * 132 + col] = v.z;
                Bs[(k4 * 4 + 3) * 132 + col] = v.w;
            }
        }
        __syncthreads();
        // P1: register GEMM, 8 nodes x 8 cents per thread
#pragma unroll 4
        for (int k = 0; k < 32; ++k) {
            float4 a0 = *(const float4*)&As[k * 132 + ty * 8];
            float4 a1 = *(const float4*)&As[k * 132 + ty * 8 + 4];
            float4 b0 = *(const float4*)&Bs[k * 132 + tx * 4];        // cents tx*8..+3
            float4 b1 = *(const float4*)&Bs[k * 132 + 64 + tx * 4];   // cents tx*8+4..+7
            float av[8] = {a0.x, a0.y, a0.z, a0.w, a1.x, a1.y, a1.z, a1.w};
            float bv[8] = {b0.x, b0.y, b0.z, b0.w, b1.x, b1.y, b1.z, b1.w};
#pragma unroll
            for (int i = 0; i < 8; ++i)
#pragma unroll
                for (int j = 0; j < 8; ++j)
                    acc[i][j] += av[i] * bv[j];
        }
        __syncthreads();   // before restaging
    }

    // P2: per-group softmax/argmax/balance, all in registers
    float balp[8] = {};
#pragma unroll
    for (int i = 0; i < 8; ++i) {
        const int node = ty * 8 + i;
        const bool act = (n0 + node) < n;
        // in-lane first-max
        float m = acc[i][0];
        int am = tx * 8;
#pragma unroll
        for (int j = 1; j < 8; ++j)
            if (acc[i][j] > m) { m = acc[i][j]; am = tx * 8 + j; }
        // cross-lane butterfly (exact first-max tie-break)
#pragma unroll
        for (int s = 1; s <= 4; s <<= 1) {
            int pl = l ^ s;
            int srcl = segbase + base + pl;
            float mo = __shfl(m, srcl, 64);
            int amo = __shfl(am, srcl, 64);
            if (pl < sz && (mo > m || (mo == m && amo < am))) { m = mo; am = amo; }
        }
        // exp + group-sum
        float Z = 0.f;
#pragma unroll
        for (int j = 0; j < 8; ++j) {
            float e2 = expf(acc[i][j] - m);
            acc[i][j] = e2;
            Z += e2;
        }
#pragma unroll
        for (int s = 1; s <= 4; s <<= 1) {
            int pl = l ^ s;
            int srcl = segbase + base + pl;
            float Zo = __shfl(Z, srcl, 64);
            if (pl < sz) Z += Zo;
        }
        float invZ = (act && sz > 0) ? (1.0f / Z) : 0.f;
#pragma unroll
        for (int j = 0; j < 8; ++j) balp[j] += acc[i][j] * invZ;
        if (l == 0 && sz > 0) km_ls[node * 4 + gid] = am;
    }

    // balance: sum the 4 ty-segments within each wave, store per-wave slice
#pragma unroll
    for (int j = 0; j < 8; ++j) {
        float v = balp[j];
        v += __shfl_xor(v, 16, 64);
        v += __shfl_xor(v, 32, 64);
        balp[j] = v;
    }
    if (lane < 16) {
#pragma unroll
        for (int j = 0; j < 8; ++j)
            bal4[wave * 128 + tx * 8 + j] = balp[j];
    }
    __syncthreads();
    if (tid < 120) {
        float s = bal4[tid] + bal4[128 + tid] + bal4[256 + tid] + bal4[384 + tid];
        atomicAdd(&balance_g[tid * 4 + d], s);
    }

    // P4: h3 = h2 + max_j cent[km_j], 2 threads per node (32 floats each)
    {
        const int node = tid >> 1;
        const int half = tid & 1;
        if (n0 + node < n) {
            int k0 = km_ls[node * 4 + 0], k1 = km_ls[node * 4 + 1];
            int k2 = km_ls[node * 4 + 2], k3 = km_ls[node * 4 + 3];
            const float* hp = h2 + (size_t)(n0 + node) * 256 + d * 64 + half * 32;
            const float* c0 = cent + (size_t)k0 * 256 + d * 64 + half * 32;
            const float* c1 = cent + (size_t)k1 * 256 + d * 64 + half * 32;
            const float* c2 = cent + (size_t)k2 * 256 + d * 64 + half * 32;
            const float* c3 = cent + (size_t)k3 * 256 + d * 64 + half * 32;
            float* op = h3 + (size_t)(n0 + node) * 256 + d * 64 + half * 32;
#pragma unroll
            for (int q = 0; q < 8; ++q) {
                int g = q * 4;
                float4 hv = *(const float4*)(hp + g);
                float4 v0 = *(const float4*)(c0 + g);
                float4 v1 = *(const float4*)(c1 + g);
                float4 v2 = *(const float4*)(c2 + g);
                float4 v3 = *(const float4*)(c3 + g);
                float4 r;
                r.x = hv.x + fmaxf(fmaxf(v0.x, v1.x), fmaxf(v2.x, v3.x));
                r.y = hv.y + fmaxf(fmaxf(v0.y, v1.y), fmaxf(v2.y, v3.y));
                r.z = hv.z + fmaxf(fmaxf(v0.z, v1.z), fmaxf(v2.z, v3.z));
                r.w = hv.w + fmaxf(fmaxf(v0.w, v1.w), fmaxf(v2.w, v3.w));
                *(float4*)(op + g) = r;
            }
        }
    }
}

__global__ void k_reg(const float* __restrict__ balance_g, float* __restrict__ out_reg,
                      float inv_n) {
    __shared__ float red[512];
    int tid = threadIdx.x;
    float v = 0.f;
    if (tid < 480) {
        int k = tid >> 2;
        float target = (k < 8) ? 0.125f : (k < 24) ? 0.0625f : (k < 56) ? 0.03125f : 0.015625f;
        float b = balance_g[tid] * inv_n;
        float df = b - target;
        v = df * df;
    }
    red[tid] = v;
    __syncthreads();
    for (int s = 256; s > 0; s >>= 1) {
        if (tid < s) red[tid] += red[tid + s];
        __syncthreads();
    }
    if (tid == 0) *out_reg = sqrtf(red[0]);
}

// ---------------- host launch ----------------

extern "C" void kernel_launch(void* const* d_in, const int* in_sizes, int n_in,
                              void* d_out, int out_size, void* d_ws, size_t ws_size,
                              hipStream_t stream) {
    const float* x    = (const float*)d_in[0];
    const int*   ei   = (const int*)d_in[1];
    const float* W0   = (const float*)d_in[2];
    const float* b0   = (const float*)d_in[3];
    const float* W1   = (const float*)d_in[4];
    const float* b1   = (const float*)d_in[5];
    const float* W2   = (const float*)d_in[6];
    const float* b2   = (const float*)d_in[7];
    const float* cent = (const float*)d_in[8];
    const int n = in_sizes[0] / 256;
    const int e = in_sizes[1] / 2;
    const int* src = ei;
    const int* dst = ei + e;
    float* out = (float*)d_out;

    char* w = (char*)d_ws;
    float* bufA = (float*)w;      w += (size_t)n * 256 * 4;
    float* bufB = (float*)w;      w += (size_t)n * 256 * 4;
    float* dinv = (float*)w;      w += (size_t)n * 4;
    int* cnt = (int*)w;           w += (size_t)n * 4;
    int* row_start = (int*)w;     w += (size_t)n * 4;
    int* cursor = (int*)w;        w += (size_t)n * 4;
    int* csr_src = (int*)w;       w += (size_t)e * 4;
    float* csr_norm = (float*)w;  w += (size_t)e * 4;
    int* counter = (int*)w;       w += 256;
    float* balance = (float*)w;   w += 480 * 4;

    const int tb = 256;
    k_init<<<(n + tb - 1) / tb, tb, 0, stream>>>(cnt, cursor, counter, balance, n);
    k_count<<<(e + tb - 1) / tb, tb, 0, stream>>>(dst, cnt, e);
    k_dinv<<<(n + tb - 1) / tb, tb, 0, stream>>>(cnt, dinv, n);
    k_alloc<<<(n + tb - 1) / tb, tb, 0, stream>>>(cnt, row_start, counter, n);
    k_fill<<<(e + tb - 1) / tb, tb, 0, stream>>>(src, dst, dinv, row_start, cursor,
                                                 csr_src, csr_norm, e);

    dim3 g1((n + 127) / 128, 2);
    k_gemm<<<g1, 256, 0, stream>>>(x, W0, bufA, n, 256, 256);
    k_agg4<true><<<(n + 3) / 4, 256, 0, stream>>>(bufA, dinv, csr_src, csr_norm,
                                                  row_start, cnt, b0, bufB, n);
    k_gemm<<<g1, 256, 0, stream>>>(bufB, W1, bufA, n, 256, 256);
    k_agg4<true><<<(n + 3) / 4, 256, 0, stream>>>(bufA, dinv, csr_src, csr_norm,
                                                  row_start, cnt, b1, bufB, n);

    dim3 gq((n + 127) / 128, 4);
    k_quant4<<<gq, 256, 0, stream>>>(bufB, cent, bufA, balance, n);

    dim3 g3((n + 127) / 128, 1);
    k_gemm<<<g3, 256, 0, stream>>>(bufA, W2, bufB, n, 128, 256);
    k_agg2<<<(n + 3) / 4, 256, 0, stream>>>(bufB, dinv, csr_src, csr_norm,
                                            row_start, cnt, b2, out, n);
    k_reg<<<1, 512, 0, stream>>>(balance, out + (size_t)n * 128, 1.0f / (float)n);
}

// Round 7
// 723.718 us; speedup vs baseline: 1.4391x; 1.0322x over previous
//
#include <hip/hip_runtime.h>
#include <math.h>

// ---------------------------------------------------------------------------
// GCN pipeline: conv1(relu) -> conv2(relu) -> quantize(+reg) -> add -> conv3
// Numerics: fp32 everywhere visible to quantize's argmax; GEMMs use
// split-bf16 MFMA (Ootomo 3-term, residual ~1e-5 rel == fp32-reorder noise).
// ---------------------------------------------------------------------------

// ---------------- CSR build ----------------

__global__ void k_init(int* cnt, int* cursor, int* counter, float* balance, int n) {
    int i = blockIdx.x * blockDim.x + threadIdx.x;
    if (i < n) { cnt[i] = 0; cursor[i] = 0; }
    if (i < 480) balance[i] = 0.f;
    if (i == 0) *counter = 0;
}

__global__ void k_count(const int* __restrict__ dst, int* __restrict__ cnt, int e) {
    int i = blockIdx.x * blockDim.x + threadIdx.x;
    if (i < e) atomicAdd(&cnt[dst[i]], 1);
}

__global__ void k_dinv(const int* __restrict__ cnt, float* __restrict__ dinv, int n) {
    int i = blockIdx.x * blockDim.x + threadIdx.x;
    if (i < n) dinv[i] = rsqrtf((float)cnt[i] + 1.0f);   // +1 self loop
}

__global__ void k_alloc(const int* __restrict__ cnt, int* __restrict__ row_start,
                        int* __restrict__ counter, int n) {
    int i = blockIdx.x * blockDim.x + threadIdx.x;
    if (i < n) row_start[i] = atomicAdd(counter, cnt[i]);
}

__global__ void k_fill(const int* __restrict__ src, const int* __restrict__ dst,
                       const float* __restrict__ dinv, const int* __restrict__ row_start,
                       int* __restrict__ cursor, int* __restrict__ csr_src,
                       float* __restrict__ csr_norm, int e) {
    int i = blockIdx.x * blockDim.x + threadIdx.x;
    if (i >= e) return;
    int s = src[i], d = dst[i];
    int slot = atomicAdd(&cursor[d], 1);
    int idx = row_start[d] + slot;
    csr_src[idx] = s;
    csr_norm[idx] = dinv[s] * dinv[d];
}

// ---------------- split-bf16 MFMA GEMM: C[M,N] = A[M,K=256] @ B[K,N] -------
// 128x128 tile, BK=32, 4 waves in 2x2, 64x64 per wave (4x4 x 16x16 MFMA).
// fp32 tiles are split in-flight into (hi, lo) bf16 during LDS staging
// (same global bytes as fp32 GEMM). 3 MFMA per tile: AlBh + AhBl + AhBh.
// k-map consistency: A and B frags both use k = (lane>>4)*8 + j, so any HW
// k-permutation cancels; load-bearing facts are non-K idx = lane&15 and
// C/D {col=lane&15, row=(lane>>4)*4+reg} [verified m89].

typedef short bf16x8 __attribute__((ext_vector_type(8)));
typedef float f32x4 __attribute__((ext_vector_type(4)));

__device__ __forceinline__ unsigned short bf16_rne(float a) {
    unsigned u = __builtin_bit_cast(unsigned, a);
    return (unsigned short)((u + 0x7FFFu + ((u >> 16) & 1u)) >> 16);
}
__device__ __forceinline__ float bf16_to_f(unsigned short h) {
    return __builtin_bit_cast(float, (unsigned)h << 16);
}

__global__ __launch_bounds__(256, 3) void k_gemm_mfma(const float* __restrict__ A,
                                                      const float* __restrict__ B,
                                                      float* __restrict__ C,
                                                      int M, int N) {
    constexpr int K = 256;
    __shared__ unsigned short Ash[128 * 40];   // [m][k] bf16-hi, row stride 40
    __shared__ unsigned short Asl[128 * 40];   // bf16-lo
    __shared__ unsigned short Bsh[128 * 40];   // [n][k] (transposed), bf16-hi
    __shared__ unsigned short Bsl[128 * 40];
    const int tid = threadIdx.x;
    const int bm = blockIdx.x * 128;
    const int bn = blockIdx.y * 128;
    const int wave = tid >> 6, lane = tid & 63;
    const int wr = wave >> 1, wc = wave & 1;
    const int lr = lane & 15, lk = lane >> 4;

    f32x4 acc[4][4] = {};

    for (int k0 = 0; k0 < K; k0 += 32) {
        // stage A: 128 rows x 32 k (fp32 -> hi/lo bf16)
#pragma unroll
        for (int it = 0; it < 4; ++it) {
            int q = it * 256 + tid;        // 1024 float4 = 128 x 8
            int row = q >> 3, kq = q & 7;
            float4 v = make_float4(0.f, 0.f, 0.f, 0.f);
            if (bm + row < M) v = *(const float4*)(A + (size_t)(bm + row) * K + k0 + kq * 4);
            float e[4] = {v.x, v.y, v.z, v.w};
            unsigned hh[4], ll[4];
#pragma unroll
            for (int t = 0; t < 4; ++t) {
                unsigned short h = bf16_rne(e[t]);
                unsigned short l = bf16_rne(e[t] - bf16_to_f(h));
                hh[t] = h; ll[t] = l;
            }
            unsigned off = row * 40 + kq * 4;
            *(uint2*)&Ash[off] = make_uint2(hh[0] | (hh[1] << 16), hh[2] | (hh[3] << 16));
            *(uint2*)&Asl[off] = make_uint2(ll[0] | (ll[1] << 16), ll[2] | (ll[3] << 16));
        }
        // stage B: 32 k x 128 n, transposed into [n][k]
#pragma unroll
        for (int it = 0; it < 4; ++it) {
            int q = it * 256 + tid;        // 1024 float4 = 32 x 32
            int k = q >> 5, nq = q & 31;
            float4 v = *(const float4*)(B + (size_t)(k0 + k) * N + bn + nq * 4);
            float e[4] = {v.x, v.y, v.z, v.w};
#pragma unroll
            for (int t = 0; t < 4; ++t) {
                unsigned short h = bf16_rne(e[t]);
                unsigned short l = bf16_rne(e[t] - bf16_to_f(h));
                Bsh[(nq * 4 + t) * 40 + k] = h;
                Bsl[(nq * 4 + t) * 40 + k] = l;
            }
        }
        __syncthreads();

        bf16x8 ah[4], al[4], bh[4], bl[4];
#pragma unroll
        for (int i = 0; i < 4; ++i) {
            unsigned off = (wr * 64 + i * 16 + lr) * 40 + lk * 8;
            ah[i] = *(bf16x8*)&Ash[off];
            al[i] = *(bf16x8*)&Asl[off];
        }
#pragma unroll
        for (int j = 0; j < 4; ++j) {
            unsigned off = (wc * 64 + j * 16 + lr) * 40 + lk * 8;
            bh[j] = *(bf16x8*)&Bsh[off];
            bl[j] = *(bf16x8*)&Bsl[off];
        }
#pragma unroll
        for (int i = 0; i < 4; ++i)
#pragma unroll
            for (int j = 0; j < 4; ++j) {
                acc[i][j] = __builtin_amdgcn_mfma_f32_16x16x32_bf16(al[i], bh[j], acc[i][j], 0, 0, 0);
                acc[i][j] = __builtin_amdgcn_mfma_f32_16x16x32_bf16(ah[i], bl[j], acc[i][j], 0, 0, 0);
                acc[i][j] = __builtin_amdgcn_mfma_f32_16x16x32_bf16(ah[i], bh[j], acc[i][j], 0, 0, 0);
            }
        __syncthreads();
    }

    // epilogue: C/D layout col=lane&15, row=(lane>>4)*4+reg
#pragma unroll
    for (int i = 0; i < 4; ++i) {
        int rbase = bm + wr * 64 + i * 16 + lk * 4;
#pragma unroll
        for (int r = 0; r < 4; ++r) {
            int row = rbase + r;
            if (row < M) {
#pragma unroll
                for (int j = 0; j < 4; ++j)
                    C[(size_t)row * N + bn + wc * 64 + j * 16 + lr] = acc[i][j][r];
            }
        }
    }
}

// ---------------- Aggregation (gather over CSR), one wave per node ----------------
// Structurally L3-BW-bound (rounds 4-6: 3.7 TB/s, FETCH = 8 XCD x 51 MB table,
// invariant under 3 different MLP structures). ~125 us is the floor.

template <bool RELU>
__global__ __launch_bounds__(256, 4) void k_agg4(const float* __restrict__ xw,
                                                 const float* __restrict__ dinv,
                                                 const int* __restrict__ csr_src,
                                                 const float* __restrict__ csr_norm,
                                                 const int* __restrict__ row_start,
                                                 const int* __restrict__ cnt,
                                                 const float* __restrict__ bias,
                                                 float* __restrict__ out, int n) {
    int node = blockIdx.x * 4 + (threadIdx.x >> 6);
    if (node >= n) return;
    int lane = threadIdx.x & 63;
    int c = lane * 4;
    float di = dinv[node];
    float4 self = *(const float4*)(xw + (size_t)node * 256 + c);
    float4 bv = *(const float4*)(bias + c);
    float sw = di * di;
    float ax = self.x * sw + bv.x;
    float ay = self.y * sw + bv.y;
    float az = self.z * sw + bv.z;
    float aw = self.w * sw + bv.w;
    int st = row_start[node];
    int m = cnt[node];
    for (int t0 = 0; t0 < m; t0 += 64) {
        int rem = m - t0;
        int cnt_i = rem < 64 ? rem : 64;
        int idx_l = 0;
        float nrm_l = 0.f;
        if (lane < cnt_i) {
            idx_l = csr_src[st + t0 + lane];
            nrm_l = csr_norm[st + t0 + lane];
        }
        int t = 0;
        for (; t + 8 <= cnt_i; t += 8) {
            const float* p0 = xw + (size_t)__shfl(idx_l, t + 0, 64) * 256 + c;
            const float* p1 = xw + (size_t)__shfl(idx_l, t + 1, 64) * 256 + c;
            const float* p2 = xw + (size_t)__shfl(idx_l, t + 2, 64) * 256 + c;
            const float* p3 = xw + (size_t)__shfl(idx_l, t + 3, 64) * 256 + c;
            const float* p4 = xw + (size_t)__shfl(idx_l, t + 4, 64) * 256 + c;
            const float* p5 = xw + (size_t)__shfl(idx_l, t + 5, 64) * 256 + c;
            const float* p6 = xw + (size_t)__shfl(idx_l, t + 6, 64) * 256 + c;
            const float* p7 = xw + (size_t)__shfl(idx_l, t + 7, 64) * 256 + c;
            float4 v0 = *(const float4*)p0;
            float4 v1 = *(const float4*)p1;
            float4 v2 = *(const float4*)p2;
            float4 v3 = *(const float4*)p3;
            float4 v4 = *(const float4*)p4;
            float4 v5 = *(const float4*)p5;
            float4 v6 = *(const float4*)p6;
            float4 v7 = *(const float4*)p7;
            float w0 = __shfl(nrm_l, t + 0, 64);
            float w1 = __shfl(nrm_l, t + 1, 64);
            float w2 = __shfl(nrm_l, t + 2, 64);
            float w3 = __shfl(nrm_l, t + 3, 64);
            float w4 = __shfl(nrm_l, t + 4, 64);
            float w5 = __shfl(nrm_l, t + 5, 64);
            float w6 = __shfl(nrm_l, t + 6, 64);
            float w7 = __shfl(nrm_l, t + 7, 64);
            ax += v0.x * w0; ay += v0.y * w0; az += v0.z * w0; aw += v0.w * w0;
            ax += v1.x * w1; ay += v1.y * w1; az += v1.z * w1; aw += v1.w * w1;
            ax += v2.x * w2; ay += v2.y * w2; az += v2.z * w2; aw += v2.w * w2;
            ax += v3.x * w3; ay += v3.y * w3; az += v3.z * w3; aw += v3.w * w3;
            ax += v4.x * w4; ay += v4.y * w4; az += v4.z * w4; aw += v4.w * w4;
            ax += v5.x * w5; ay += v5.y * w5; az += v5.z * w5; aw += v5.w * w5;
            ax += v6.x * w6; ay += v6.y * w6; az += v6.z * w6; aw += v6.w * w6;
            ax += v7.x * w7; ay += v7.y * w7; az += v7.z * w7; aw += v7.w * w7;
        }
        for (; t < cnt_i; ++t) {
            int s = __shfl(idx_l, t, 64);
            float w = __shfl(nrm_l, t, 64);
            float4 v = *(const float4*)(xw + (size_t)s * 256 + c);
            ax += v.x * w; ay += v.y * w; az += v.z * w; aw += v.w * w;
        }
    }
    if (RELU) {
        ax = ax > 0.f ? ax : 0.5f * ax;
        ay = ay > 0.f ? ay : 0.5f * ay;
        az = az > 0.f ? az : 0.5f * az;
        aw = aw > 0.f ? aw : 0.5f * aw;
    }
    *(float4*)(out + (size_t)node * 256 + c) = make_float4(ax, ay, az, aw);
}

__global__ __launch_bounds__(256, 4) void k_agg2(const float* __restrict__ xw,
                                                 const float* __restrict__ dinv,
                                                 const int* __restrict__ csr_src,
                                                 const float* __restrict__ csr_norm,
                                                 const int* __restrict__ row_start,
                                                 const int* __restrict__ cnt,
                                                 const float* __restrict__ bias,
                                                 float* __restrict__ out, int n) {
    int node = blockIdx.x * 4 + (threadIdx.x >> 6);
    if (node >= n) return;
    int lane = threadIdx.x & 63;
    int c = lane * 2;
    float di = dinv[node];
    float2 self = *(const float2*)(xw + (size_t)node * 128 + c);
    float2 bv = *(const float2*)(bias + c);
    float sw = di * di;
    float ax = self.x * sw + bv.x;
    float ay = self.y * sw + bv.y;
    int st = row_start[node];
    int m = cnt[node];
    for (int t0 = 0; t0 < m; t0 += 64) {
        int rem = m - t0;
        int cnt_i = rem < 64 ? rem : 64;
        int idx_l = 0;
        float nrm_l = 0.f;
        if (lane < cnt_i) {
            idx_l = csr_src[st + t0 + lane];
            nrm_l = csr_norm[st + t0 + lane];
        }
        int t = 0;
        for (; t + 8 <= cnt_i; t += 8) {
            const float* p0 = xw + (size_t)__shfl(idx_l, t + 0, 64) * 128 + c;
            const float* p1 = xw + (size_t)__shfl(idx_l, t + 1, 64) * 128 + c;
            const float* p2 = xw + (size_t)__shfl(idx_l, t + 2, 64) * 128 + c;
            const float* p3 = xw + (size_t)__shfl(idx_l, t + 3, 64) * 128 + c;
            const float* p4 = xw + (size_t)__shfl(idx_l, t + 4, 64) * 128 + c;
            const float* p5 = xw + (size_t)__shfl(idx_l, t + 5, 64) * 128 + c;
            const float* p6 = xw + (size_t)__shfl(idx_l, t + 6, 64) * 128 + c;
            const float* p7 = xw + (size_t)__shfl(idx_l, t + 7, 64) * 128 + c;
            float2 v0 = *(const float2*)p0;
            float2 v1 = *(const float2*)p1;
            float2 v2 = *(const float2*)p2;
            float2 v3 = *(const float2*)p3;
            float2 v4 = *(const float2*)p4;
            float2 v5 = *(const float2*)p5;
            float2 v6 = *(const float2*)p6;
            float2 v7 = *(const float2*)p7;
            float w0 = __shfl(nrm_l, t + 0, 64);
            float w1 = __shfl(nrm_l, t + 1, 64);
            float w2 = __shfl(nrm_l, t + 2, 64);
            float w3 = __shfl(nrm_l, t + 3, 64);
            float w4 = __shfl(nrm_l, t + 4, 64);
            float w5 = __shfl(nrm_l, t + 5, 64);
            float w6 = __shfl(nrm_l, t + 6, 64);
            float w7 = __shfl(nrm_l, t + 7, 64);
            ax += v0.x * w0; ay += v0.y * w0;
            ax += v1.x * w1; ay += v1.y * w1;
            ax += v2.x * w2; ay += v2.y * w2;
            ax += v3.x * w3; ay += v3.y * w3;
            ax += v4.x * w4; ay += v4.y * w4;
            ax += v5.x * w5; ay += v5.y * w5;
            ax += v6.x * w6; ay += v6.y * w6;
            ax += v7.x * w7; ay += v7.y * w7;
        }
        for (; t < cnt_i; ++t) {
            int s = __shfl(idx_l, t, 64);
            float w = __shfl(nrm_l, t, 64);
            float2 v = *(const float2*)(xw + (size_t)s * 128 + c);
            ax += v.x * w; ay += v.y * w;
        }
    }
    *(float2*)(out + (size_t)node * 128 + c) = make_float2(ax, ay);
}

// ---------------- Quantize v4 (softmax fully in registers) ----------------

__global__ __launch_bounds__(256, 4) void k_quant4(const float* __restrict__ h2,
                                                   const float* __restrict__ cent,
                                                   float* __restrict__ h3,
                                                   float* __restrict__ balance_g, int n) {
    __shared__ float As[32 * 132];     // As[k][node]
    __shared__ float Bs[32 * 132];     // Bs[k][swizzled cent col]
    __shared__ float bal4[4 * 128];    // per-wave balance slices
    __shared__ int km_ls[128 * 4];
    const int tid = threadIdx.x;
    const int n0 = blockIdx.x * 128;
    const int d = blockIdx.y;
    const int ty = tid >> 4, tx = tid & 15;
    const int wave = tid >> 6, lane = tid & 63;

    int gid, base, sz;
    if (tx == 0)       { gid = 0; base = 0;  sz = 1; }
    else if (tx <= 2)  { gid = 1; base = 1;  sz = 2; }
    else if (tx <= 6)  { gid = 2; base = 3;  sz = 4; }
    else if (tx <= 14) { gid = 3; base = 7;  sz = 8; }
    else               { gid = 0; base = 15; sz = 0; }   // pad lane
    const int l = tx - base;
    const int segbase = lane & 48;

    {
        int k = tid >> 3, r = tid & 7;
        int col = (r < 4) ? (60 + r) : (120 + r);
        Bs[k * 132 + col] = 0.f;
    }

    float acc[8][8] = {};
    for (int c0 = 0; c0 < 64; c0 += 32) {
#pragma unroll
        for (int it = 0; it < 4; ++it) {
            int q = it * 256 + tid;
            int row = q >> 3, k4 = q & 7;
            float4 v = make_float4(0.f, 0.f, 0.f, 0.f);
            if (n0 + row < n)
                v = *(const float4*)(h2 + (size_t)(n0 + row) * 256 + d * 64 + c0 + k4 * 4);
            As[(k4 * 4 + 0) * 132 + row] = v.x;
            As[(k4 * 4 + 1) * 132 + row] = v.y;
            As[(k4 * 4 + 2) * 132 + row] = v.z;
            As[(k4 * 4 + 3) * 132 + row] = v.w;
        }
#pragma unroll
        for (int it = 0; it < 4; ++it) {
            int q = it * 256 + tid;
            if (q < 960) {
                int c = q >> 3, k4 = q & 7;
                float4 v = *(const float4*)(cent + (size_t)c * 256 + d * 64 + c0 + k4 * 4);
                int col = ((c >> 3) << 2) + (((c >> 2) & 1) << 6) + (c & 3);
                Bs[(k4 * 4 + 0) * 132 + col] = v.x;
                Bs[(k4 * 4 + 1) * 132 + col] = v.y;
                Bs[(k4 * 4 + 2) * 132 + col] = v.z;
                Bs[(k4 * 4 + 3) * 132 + col] = v.w;
            }
        }
        __syncthreads();
#pragma unroll 4
        for (int k = 0; k < 32; ++k) {
            float4 a0 = *(const float4*)&As[k * 132 + ty * 8];
            float4 a1 = *(const float4*)&As[k * 132 + ty * 8 + 4];
            float4 b0 = *(const float4*)&Bs[k * 132 + tx * 4];
            float4 b1 = *(const float4*)&Bs[k * 132 + 64 + tx * 4];
            float av[8] = {a0.x, a0.y, a0.z, a0.w, a1.x, a1.y, a1.z, a1.w};
            float bv[8] = {b0.x, b0.y, b0.z, b0.w, b1.x, b1.y, b1.z, b1.w};
#pragma unroll
            for (int i = 0; i < 8; ++i)
#pragma unroll
                for (int j = 0; j < 8; ++j)
                    acc[i][j] += av[i] * bv[j];
        }
        __syncthreads();
    }

    float balp[8] = {};
#pragma unroll
    for (int i = 0; i < 8; ++i) {
        const int node = ty * 8 + i;
        const bool act = (n0 + node) < n;
        float m = acc[i][0];
        int am = tx * 8;
#pragma unroll
        for (int j = 1; j < 8; ++j)
            if (acc[i][j] > m) { m = acc[i][j]; am = tx * 8 + j; }
#pragma unroll
        for (int s = 1; s <= 4; s <<= 1) {
            int pl = l ^ s;
            int srcl = segbase + base + pl;
            float mo = __shfl(m, srcl, 64);
            int amo = __shfl(am, srcl, 64);
            if (pl < sz && (mo > m || (mo == m && amo < am))) { m = mo; am = amo; }
        }
        float Z = 0.f;
#pragma unroll
        for (int j = 0; j < 8; ++j) {
            float e2 = expf(acc[i][j] - m);
            acc[i][j] = e2;
            Z += e2;
        }
#pragma unroll
        for (int s = 1; s <= 4; s <<= 1) {
            int pl = l ^ s;
            int srcl = segbase + base + pl;
            float Zo = __shfl(Z, srcl, 64);
            if (pl < sz) Z += Zo;
        }
        float invZ = (act && sz > 0) ? (1.0f / Z) : 0.f;
#pragma unroll
        for (int j = 0; j < 8; ++j) balp[j] += acc[i][j] * invZ;
        if (l == 0 && sz > 0) km_ls[node * 4 + gid] = am;
    }

#pragma unroll
    for (int j = 0; j < 8; ++j) {
        float v = balp[j];
        v += __shfl_xor(v, 16, 64);
        v += __shfl_xor(v, 32, 64);
        balp[j] = v;
    }
    if (lane < 16) {
#pragma unroll
        for (int j = 0; j < 8; ++j)
            bal4[wave * 128 + tx * 8 + j] = balp[j];
    }
    __syncthreads();
    if (tid < 120) {
        float s = bal4[tid] + bal4[128 + tid] + bal4[256 + tid] + bal4[384 + tid];
        atomicAdd(&balance_g[tid * 4 + d], s);
    }

    {
        const int node = tid >> 1;
        const int half = tid & 1;
        if (n0 + node < n) {
            int k0 = km_ls[node * 4 + 0], k1 = km_ls[node * 4 + 1];
            int k2 = km_ls[node * 4 + 2], k3 = km_ls[node * 4 + 3];
            const float* hp = h2 + (size_t)(n0 + node) * 256 + d * 64 + half * 32;
            const float* c0 = cent + (size_t)k0 * 256 + d * 64 + half * 32;
            const float* c1 = cent + (size_t)k1 * 256 + d * 64 + half * 32;
            const float* c2 = cent + (size_t)k2 * 256 + d * 64 + half * 32;
            const float* c3 = cent + (size_t)k3 * 256 + d * 64 + half * 32;
            float* op = h3 + (size_t)(n0 + node) * 256 + d * 64 + half * 32;
#pragma unroll
            for (int q = 0; q < 8; ++q) {
                int g = q * 4;
                float4 hv = *(const float4*)(hp + g);
                float4 v0 = *(const float4*)(c0 + g);
                float4 v1 = *(const float4*)(c1 + g);
                float4 v2 = *(const float4*)(c2 + g);
                float4 v3 = *(const float4*)(c3 + g);
                float4 r;
                r.x = hv.x + fmaxf(fmaxf(v0.x, v1.x), fmaxf(v2.x, v3.x));
                r.y = hv.y + fmaxf(fmaxf(v0.y, v1.y), fmaxf(v2.y, v3.y));
                r.z = hv.z + fmaxf(fmaxf(v0.z, v1.z), fmaxf(v2.z, v3.z));
                r.w = hv.w + fmaxf(fmaxf(v0.w, v1.w), fmaxf(v2.w, v3.w));
                *(float4*)(op + g) = r;
            }
        }
    }
}

__global__ void k_reg(const float* __restrict__ balance_g, float* __restrict__ out_reg,
                      float inv_n) {
    __shared__ float red[512];
    int tid = threadIdx.x;
    float v = 0.f;
    if (tid < 480) {
        int k = tid >> 2;
        float target = (k < 8) ? 0.125f : (k < 24) ? 0.0625f : (k < 56) ? 0.03125f : 0.015625f;
        float b = balance_g[tid] * inv_n;
        float df = b - target;
        v = df * df;
    }
    red[tid] = v;
    __syncthreads();
    for (int s = 256; s > 0; s >>= 1) {
        if (tid < s) red[tid] += red[tid + s];
        __syncthreads();
    }
    if (tid == 0) *out_reg = sqrtf(red[0]);
}

// ---------------- host launch ----------------

extern "C" void kernel_launch(void* const* d_in, const int* in_sizes, int n_in,
                              void* d_out, int out_size, void* d_ws, size_t ws_size,
                              hipStream_t stream) {
    const float* x    = (const float*)d_in[0];
    const int*   ei   = (const int*)d_in[1];
    const float* W0   = (const float*)d_in[2];
    const float* b0   = (const float*)d_in[3];
    const float* W1   = (const float*)d_in[4];
    const float* b1   = (const float*)d_in[5];
    const float* W2   = (const float*)d_in[6];
    const float* b2   = (const float*)d_in[7];
    const float* cent = (const float*)d_in[8];
    const int n = in_sizes[0] / 256;
    const int e = in_sizes[1] / 2;
    const int* src = ei;
    const int* dst = ei + e;
    float* out = (float*)d_out;

    char* w = (char*)d_ws;
    float* bufA = (float*)w;      w += (size_t)n * 256 * 4;
    float* bufB = (float*)w;      w += (size_t)n * 256 * 4;
    float* dinv = (float*)w;      w += (size_t)n * 4;
    int* cnt = (int*)w;           w += (size_t)n * 4;
    int* row_start = (int*)w;     w += (size_t)n * 4;
    int* cursor = (int*)w;        w += (size_t)n * 4;
    int* csr_src = (int*)w;       w += (size_t)e * 4;
    float* csr_norm = (float*)w;  w += (size_t)e * 4;
    int* counter = (int*)w;       w += 256;
    float* balance = (float*)w;   w += 480 * 4;

    const int tb = 256;
    k_init<<<(n + tb - 1) / tb, tb, 0, stream>>>(cnt, cursor, counter, balance, n);
    k_count<<<(e + tb - 1) / tb, tb, 0, stream>>>(dst, cnt, e);
    k_dinv<<<(n + tb - 1) / tb, tb, 0, stream>>>(cnt, dinv, n);
    k_alloc<<<(n + tb - 1) / tb, tb, 0, stream>>>(cnt, row_start, counter, n);
    k_fill<<<(e + tb - 1) / tb, tb, 0, stream>>>(src, dst, dinv, row_start, cursor,
                                                 csr_src, csr_norm, e);

    dim3 g1((n + 127) / 128, 2);
    k_gemm_mfma<<<g1, 256, 0, stream>>>(x, W0, bufA, n, 256);
    k_agg4<true><<<(n + 3) / 4, 256, 0, stream>>>(bufA, dinv, csr_src, csr_norm,
                                                  row_start, cnt, b0, bufB, n);
    k_gemm_mfma<<<g1, 256, 0, stream>>>(bufB, W1, bufA, n, 256);
    k_agg4<true><<<(n + 3) / 4, 256, 0, stream>>>(bufA, dinv, csr_src, csr_norm,
                                                  row_start, cnt, b1, bufB, n);

    dim3 gq((n + 127) / 128, 4);
    k_quant4<<<gq, 256, 0, stream>>>(bufB, cent, bufA, balance, n);

    dim3 g3((n + 127) / 128, 1);
    k_gemm_mfma<<<g3, 256, 0, stream>>>(bufA, W2, bufB, n, 128);
    k_agg2<<<(n + 3) / 4, 256, 0, stream>>>(bufB, dinv, csr_src, csr_norm,
                                            row_start, cnt, b2, out, n);
    k_reg<<<1, 512, 0, stream>>>(balance, out + (size_t)n * 128, 1.0f / (float)n);
}

// Round 8
// 619.619 us; speedup vs baseline: 1.6809x; 1.1680x over previous
//
#include <hip/hip_runtime.h>
#include <math.h>

// ---------------------------------------------------------------------------
// GCN pipeline: conv1(relu) -> conv2(relu) -> quantize(+reg) -> add -> conv3
// GEMMs: split-bf16 MFMA (Ootomo 3-term). All hi/lo tables PRECOMPUTED
// (weights once, transposed; activations fused into producer epilogues).
// fp32 visible to quantize's argmax; split residual ~1e-5 rel (accepted since
// round 7: absmax 6.9e-3 vs threshold 1.1e-2).
// ---------------------------------------------------------------------------

typedef short bf16x8 __attribute__((ext_vector_type(8)));
typedef float f32x4 __attribute__((ext_vector_type(4)));

__device__ __forceinline__ unsigned short bf16_rne(float a) {
    unsigned u = __builtin_bit_cast(unsigned, a);
    return (unsigned short)((u + 0x7FFFu + ((u >> 16) & 1u)) >> 16);
}
__device__ __forceinline__ float bf16_to_f(unsigned short h) {
    return __builtin_bit_cast(float, (unsigned)h << 16);
}
__device__ __forceinline__ void split4(const float* e, unsigned short* h, unsigned short* l) {
#pragma unroll
    for (int t = 0; t < 4; ++t) {
        h[t] = bf16_rne(e[t]);
        l[t] = bf16_rne(e[t] - bf16_to_f(h[t]));
    }
}

// ---------------- CSR build ----------------

__global__ void k_init(int* cnt, int* cursor, int* counter, float* balance, int n) {
    int i = blockIdx.x * blockDim.x + threadIdx.x;
    if (i < n) { cnt[i] = 0; cursor[i] = 0; }
    if (i < 480) balance[i] = 0.f;
    if (i == 0) *counter = 0;
}

__global__ void k_count(const int* __restrict__ dst, int* __restrict__ cnt, int e) {
    int i = blockIdx.x * blockDim.x + threadIdx.x;
    if (i < e) atomicAdd(&cnt[dst[i]], 1);
}

__global__ void k_dinv(const int* __restrict__ cnt, float* __restrict__ dinv, int n) {
    int i = blockIdx.x * blockDim.x + threadIdx.x;
    if (i < n) dinv[i] = rsqrtf((float)cnt[i] + 1.0f);   // +1 self loop
}

__global__ void k_alloc(const int* __restrict__ cnt, int* __restrict__ row_start,
                        int* __restrict__ counter, int n) {
    int i = blockIdx.x * blockDim.x + threadIdx.x;
    if (i < n) row_start[i] = atomicAdd(counter, cnt[i]);
}

__global__ void k_fill(const int* __restrict__ src, const int* __restrict__ dst,
                       const float* __restrict__ dinv, const int* __restrict__ row_start,
                       int* __restrict__ cursor, int* __restrict__ csr_src,
                       float* __restrict__ csr_norm, int e) {
    int i = blockIdx.x * blockDim.x + threadIdx.x;
    if (i >= e) return;
    int s = src[i], d = dst[i];
    int slot = atomicAdd(&cursor[d], 1);
    int idx = row_start[d] + slot;
    csr_src[idx] = s;
    csr_norm[idx] = dinv[s] * dinv[d];
}

// ---------------- split kernels ----------------

// W[K=256][N] fp32 -> Th[N][256], Tl[N][256] bf16 (transposed)
__global__ void k_splitW(const float* __restrict__ W, short* __restrict__ Th,
                         short* __restrict__ Tl, int N) {
    int i = blockIdx.x * blockDim.x + threadIdx.x;
    if (i >= N * 256) return;
    int nn = i >> 8, kk = i & 255;
    float v = W[kk * N + nn];
    unsigned short h = bf16_rne(v);
    unsigned short l = bf16_rne(v - bf16_to_f(h));
    Th[i] = (short)h;
    Tl[i] = (short)l;
}

// X[M][256] fp32 -> Hi/Lo [M][256] bf16 (8 elements per thread)
__global__ void k_splitA(const float* __restrict__ X, short* __restrict__ Hi,
                         short* __restrict__ Lo, int total8) {
    int i = blockIdx.x * blockDim.x + threadIdx.x;
    if (i >= total8) return;
    float4 a = *(const float4*)(X + (size_t)i * 8);
    float4 b = *(const float4*)(X + (size_t)i * 8 + 4);
    float e0[4] = {a.x, a.y, a.z, a.w}, e1[4] = {b.x, b.y, b.z, b.w};
    unsigned short h0[4], l0[4], h1[4], l1[4];
    split4(e0, h0, l0);
    split4(e1, h1, l1);
    *(uint4*)(Hi + (size_t)i * 8) = make_uint4(h0[0] | (h0[1] << 16), h0[2] | (h0[3] << 16),
                                              h1[0] | (h1[1] << 16), h1[2] | (h1[3] << 16));
    *(uint4*)(Lo + (size_t)i * 8) = make_uint4(l0[0] | (l0[1] << 16), l0[2] | (l0[3] << 16),
                                              l1[0] | (l1[1] << 16), l1[2] | (l1[3] << 16));
}

// ---------------- bf16-split MFMA GEMM ----------------
// C[M,N] = A[M,256] @ B[256,N], A/B pre-split hi/lo bf16; B pre-transposed
// [n][k]. 128x128 tile, BK=32, 4 waves 2x2, 64x64/wave (4x4 16x16x32 MFMA),
// 3 MFMA per tile (AlBh + AhBl + AhBh). LDS row stride 56 shorts = 112B
// (16B-aligned b128s, bank stride 28 -> 2-way = free). LDS 56KB -> 2 blk/CU.

__global__ __launch_bounds__(256, 2) void k_gemm_bf16s(const short* __restrict__ Ah,
                                                       const short* __restrict__ Al,
                                                       const short* __restrict__ Bh,
                                                       const short* __restrict__ Bl,
                                                       float* __restrict__ C,
                                                       int M, int N) {
    __shared__ short Ash[128 * 56], Asl[128 * 56], Bsh[128 * 56], Bsl[128 * 56];
    const int tid = threadIdx.x;
    const int bm = blockIdx.x * 128;
    const int bn = blockIdx.y * 128;
    const int wave = tid >> 6, lane = tid & 63;
    const int wr = wave >> 1, wc = wave & 1;
    const int lr = lane & 15, lk = lane >> 4;

    f32x4 acc[4][4] = {};

    for (int k0 = 0; k0 < 256; k0 += 32) {
#pragma unroll
        for (int it = 0; it < 2; ++it) {
            int u = it * 256 + tid;              // 512 units = 128 rows x 4 segs
            int row = u >> 2, sg = (u & 3) << 3; // seg start (shorts)
            int lo_off = row * 56 + sg;
            size_t arow = (size_t)(bm + row) * 256 + k0 + sg;
            bf16x8 va = {0, 0, 0, 0, 0, 0, 0, 0};
            bf16x8 vl = {0, 0, 0, 0, 0, 0, 0, 0};
            if (bm + row < M) {
                va = *(const bf16x8*)(Ah + arow);
                vl = *(const bf16x8*)(Al + arow);
            }
            *(bf16x8*)&Ash[lo_off] = va;
            *(bf16x8*)&Asl[lo_off] = vl;
            size_t brow = (size_t)(bn + row) * 256 + k0 + sg;   // bn+row < N always
            *(bf16x8*)&Bsh[lo_off] = *(const bf16x8*)(Bh + brow);
            *(bf16x8*)&Bsl[lo_off] = *(const bf16x8*)(Bl + brow);
        }
        __syncthreads();

        bf16x8 ah[4], al[4], bh[4], bl[4];
#pragma unroll
        for (int i = 0; i < 4; ++i) {
            int off = (wr * 64 + i * 16 + lr) * 56 + lk * 8;
            ah[i] = *(bf16x8*)&Ash[off];
            al[i] = *(bf16x8*)&Asl[off];
        }
#pragma unroll
        for (int j = 0; j < 4; ++j) {
            int off = (wc * 64 + j * 16 + lr) * 56 + lk * 8;
            bh[j] = *(bf16x8*)&Bsh[off];
            bl[j] = *(bf16x8*)&Bsl[off];
        }
#pragma unroll
        for (int i = 0; i < 4; ++i)
#pragma unroll
            for (int j = 0; j < 4; ++j) {
                acc[i][j] = __builtin_amdgcn_mfma_f32_16x16x32_bf16(al[i], bh[j], acc[i][j], 0, 0, 0);
                acc[i][j] = __builtin_amdgcn_mfma_f32_16x16x32_bf16(ah[i], bl[j], acc[i][j], 0, 0, 0);
                acc[i][j] = __builtin_amdgcn_mfma_f32_16x16x32_bf16(ah[i], bh[j], acc[i][j], 0, 0, 0);
            }
        __syncthreads();
    }

    // epilogue: C/D layout col=lane&15, row=(lane>>4)*4+reg  [verified m89]
#pragma unroll
    for (int i = 0; i < 4; ++i) {
        int rbase = bm + wr * 64 + i * 16 + lk * 4;
#pragma unroll
        for (int r = 0; r < 4; ++r) {
            int row = rbase + r;
            if (row < M) {
#pragma unroll
                for (int j = 0; j < 4; ++j)
                    C[(size_t)row * N + bn + wc * 64 + j * 16 + lr] = acc[i][j][r];
            }
        }
    }
}

// ---------------- Aggregation (gather over CSR), one wave per node ----------------
// L3-BW-bound (rounds 4-6: 3.7 TB/s, FETCH = 8 XCD x 51 MB, invariant across
// 3 MLP structures) -> ~125 us floor. MODE=1 emits bf16 hi/lo split instead of
// fp32 (same byte count; feeds next GEMM's pre-split input for free).

template <bool RELU, int MODE>
__global__ __launch_bounds__(256, 4) void k_agg4(const float* __restrict__ xw,
                                                 const float* __restrict__ dinv,
                                                 const int* __restrict__ csr_src,
                                                 const float* __restrict__ csr_norm,
                                                 const int* __restrict__ row_start,
                                                 const int* __restrict__ cnt,
                                                 const float* __restrict__ bias,
                                                 float* __restrict__ out,
                                                 short* __restrict__ outH,
                                                 short* __restrict__ outL, int n) {
    int node = blockIdx.x * 4 + (threadIdx.x >> 6);
    if (node >= n) return;
    int lane = threadIdx.x & 63;
    int c = lane * 4;
    float di = dinv[node];
    float4 self = *(const float4*)(xw + (size_t)node * 256 + c);
    float4 bv = *(const float4*)(bias + c);
    float sw = di * di;
    float ax = self.x * sw + bv.x;
    float ay = self.y * sw + bv.y;
    float az = self.z * sw + bv.z;
    float aw = self.w * sw + bv.w;
    int st = row_start[node];
    int m = cnt[node];
    for (int t0 = 0; t0 < m; t0 += 64) {
        int rem = m - t0;
        int cnt_i = rem < 64 ? rem : 64;
        int idx_l = 0;
        float nrm_l = 0.f;
        if (lane < cnt_i) {
            idx_l = csr_src[st + t0 + lane];
            nrm_l = csr_norm[st + t0 + lane];
        }
        int t = 0;
        for (; t + 8 <= cnt_i; t += 8) {
            const float* p0 = xw + (size_t)__shfl(idx_l, t + 0, 64) * 256 + c;
            const float* p1 = xw + (size_t)__shfl(idx_l, t + 1, 64) * 256 + c;
            const float* p2 = xw + (size_t)__shfl(idx_l, t + 2, 64) * 256 + c;
            const float* p3 = xw + (size_t)__shfl(idx_l, t + 3, 64) * 256 + c;
            const float* p4 = xw + (size_t)__shfl(idx_l, t + 4, 64) * 256 + c;
            const float* p5 = xw + (size_t)__shfl(idx_l, t + 5, 64) * 256 + c;
            const float* p6 = xw + (size_t)__shfl(idx_l, t + 6, 64) * 256 + c;
            const float* p7 = xw + (size_t)__shfl(idx_l, t + 7, 64) * 256 + c;
            float4 v0 = *(const float4*)p0;
            float4 v1 = *(const float4*)p1;
            float4 v2 = *(const float4*)p2;
            float4 v3 = *(const float4*)p3;
            float4 v4 = *(const float4*)p4;
            float4 v5 = *(const float4*)p5;
            float4 v6 = *(const float4*)p6;
            float4 v7 = *(const float4*)p7;
            float w0 = __shfl(nrm_l, t + 0, 64);
            float w1 = __shfl(nrm_l, t + 1, 64);
            float w2 = __shfl(nrm_l, t + 2, 64);
            float w3 = __shfl(nrm_l, t + 3, 64);
            float w4 = __shfl(nrm_l, t + 4, 64);
            float w5 = __shfl(nrm_l, t + 5, 64);
            float w6 = __shfl(nrm_l, t + 6, 64);
            float w7 = __shfl(nrm_l, t + 7, 64);
            ax += v0.x * w0; ay += v0.y * w0; az += v0.z * w0; aw += v0.w * w0;
            ax += v1.x * w1; ay += v1.y * w1; az += v1.z * w1; aw += v1.w * w1;
            ax += v2.x * w2; ay += v2.y * w2; az += v2.z * w2; aw += v2.w * w2;
            ax += v3.x * w3; ay += v3.y * w3; az += v3.z * w3; aw += v3.w * w3;
            ax += v4.x * w4; ay += v4.y * w4; az += v4.z * w4; aw += v4.w * w4;
            ax += v5.x * w5; ay += v5.y * w5; az += v5.z * w5; aw += v5.w * w5;
            ax += v6.x * w6; ay += v6.y * w6; az += v6.z * w6; aw += v6.w * w6;
            ax += v7.x * w7; ay += v7.y * w7; az += v7.z * w7; aw += v7.w * w7;
        }
        for (; t < cnt_i; ++t) {
            int s = __shfl(idx_l, t, 64);
            float w = __shfl(nrm_l, t, 64);
            float4 v = *(const float4*)(xw + (size_t)s * 256 + c);
            ax += v.x * w; ay += v.y * w; az += v.z * w; aw += v.w * w;
        }
    }
    if (RELU) {
        ax = ax > 0.f ? ax : 0.5f * ax;
        ay = ay > 0.f ? ay : 0.5f * ay;
        az = az > 0.f ? az : 0.5f * az;
        aw = aw > 0.f ? aw : 0.5f * aw;
    }
    if (MODE == 0) {
        *(float4*)(out + (size_t)node * 256 + c) = make_float4(ax, ay, az, aw);
    } else {
        float e[4] = {ax, ay, az, aw};
        unsigned short h[4], l[4];
        split4(e, h, l);
        size_t o = (size_t)node * 256 + c;
        *(uint2*)(outH + o) = make_uint2(h[0] | (h[1] << 16), h[2] | (h[3] << 16));
        *(uint2*)(outL + o) = make_uint2(l[0] | (l[1] << 16), l[2] | (l[3] << 16));
    }
}

__global__ __launch_bounds__(256, 4) void k_agg2(const float* __restrict__ xw,
                                                 const float* __restrict__ dinv,
                                                 const int* __restrict__ csr_src,
                                                 const float* __restrict__ csr_norm,
                                                 const int* __restrict__ row_start,
                                                 const int* __restrict__ cnt,
                                                 const float* __restrict__ bias,
                                                 float* __restrict__ out, int n) {
    int node = blockIdx.x * 4 + (threadIdx.x >> 6);
    if (node >= n) return;
    int lane = threadIdx.x & 63;
    int c = lane * 2;
    float di = dinv[node];
    float2 self = *(const float2*)(xw + (size_t)node * 128 + c);
    float2 bv = *(const float2*)(bias + c);
    float sw = di * di;
    float ax = self.x * sw + bv.x;
    float ay = self.y * sw + bv.y;
    int st = row_start[node];
    int m = cnt[node];
    for (int t0 = 0; t0 < m; t0 += 64) {
        int rem = m - t0;
        int cnt_i = rem < 64 ? rem : 64;
        int idx_l = 0;
        float nrm_l = 0.f;
        if (lane < cnt_i) {
            idx_l = csr_src[st + t0 + lane];
            nrm_l = csr_norm[st + t0 + lane];
        }
        int t = 0;
        for (; t + 8 <= cnt_i; t += 8) {
            const float* p0 = xw + (size_t)__shfl(idx_l, t + 0, 64) * 128 + c;
            const float* p1 = xw + (size_t)__shfl(idx_l, t + 1, 64) * 128 + c;
            const float* p2 = xw + (size_t)__shfl(idx_l, t + 2, 64) * 128 + c;
            const float* p3 = xw + (size_t)__shfl(idx_l, t + 3, 64) * 128 + c;
            const float* p4 = xw + (size_t)__shfl(idx_l, t + 4, 64) * 128 + c;
            const float* p5 = xw + (size_t)__shfl(idx_l, t + 5, 64) * 128 + c;
            const float* p6 = xw + (size_t)__shfl(idx_l, t + 6, 64) * 128 + c;
            const float* p7 = xw + (size_t)__shfl(idx_l, t + 7, 64) * 128 + c;
            float2 v0 = *(const float2*)p0;
            float2 v1 = *(const float2*)p1;
            float2 v2 = *(const float2*)p2;
            float2 v3 = *(const float2*)p3;
            float2 v4 = *(const float2*)p4;
            float2 v5 = *(const float2*)p5;
            float2 v6 = *(const float2*)p6;
            float2 v7 = *(const float2*)p7;
            float w0 = __shfl(nrm_l, t + 0, 64);
            float w1 = __shfl(nrm_l, t + 1, 64);
            float w2 = __shfl(nrm_l, t + 2, 64);
            float w3 = __shfl(nrm_l, t + 3, 64);
            float w4 = __shfl(nrm_l, t + 4, 64);
            float w5 = __shfl(nrm_l, t + 5, 64);
            float w6 = __shfl(nrm_l, t + 6, 64);
            float w7 = __shfl(nrm_l, t + 7, 64);
            ax += v0.x * w0; ay += v0.y * w0;
            ax += v1.x * w1; ay += v1.y * w1;
            ax += v2.x * w2; ay += v2.y * w2;
            ax += v3.x * w3; ay += v3.y * w3;
            ax += v4.x * w4; ay += v4.y * w4;
            ax += v5.x * w5; ay += v5.y * w5;
            ax += v6.x * w6; ay += v6.y * w6;
            ax += v7.x * w7; ay += v7.y * w7;
        }
        for (; t < cnt_i; ++t) {
            int s = __shfl(idx_l, t, 64);
            float w = __shfl(nrm_l, t, 64);
            float2 v = *(const float2*)(xw + (size_t)s * 128 + c);
            ax += v.x * w; ay += v.y * w;
        }
    }
    *(float2*)(out + (size_t)node * 128 + c) = make_float2(ax, ay);
}

// ---------------- Quantize v4 (softmax fully in registers) ----------------
// h3 output emitted as pre-split bf16 hi/lo (feeds gemm3 directly).

__global__ __launch_bounds__(256, 4) void k_quant4(const float* __restrict__ h2,
                                                   const float* __restrict__ cent,
                                                   short* __restrict__ h3h,
                                                   short* __restrict__ h3l,
                                                   float* __restrict__ balance_g, int n) {
    __shared__ float As[32 * 132];     // As[k][node]
    __shared__ float Bs[32 * 132];     // Bs[k][swizzled cent col]
    __shared__ float bal4[4 * 128];    // per-wave balance slices
    __shared__ int km_ls[128 * 4];
    const int tid = threadIdx.x;
    const int n0 = blockIdx.x * 128;
    const int d = blockIdx.y;
    const int ty = tid >> 4, tx = tid & 15;
    const int wave = tid >> 6, lane = tid & 63;

    int gid, base, sz;
    if (tx == 0)       { gid = 0; base = 0;  sz = 1; }
    else if (tx <= 2)  { gid = 1; base = 1;  sz = 2; }
    else if (tx <= 6)  { gid = 2; base = 3;  sz = 4; }
    else if (tx <= 14) { gid = 3; base = 7;  sz = 8; }
    else               { gid = 0; base = 15; sz = 0; }   // pad lane
    const int l = tx - base;
    const int segbase = lane & 48;

    {
        int k = tid >> 3, r = tid & 7;
        int col = (r < 4) ? (60 + r) : (120 + r);
        Bs[k * 132 + col] = 0.f;
    }

    float acc[8][8] = {};
    for (int c0 = 0; c0 < 64; c0 += 32) {
#pragma unroll
        for (int it = 0; it < 4; ++it) {
            int q = it * 256 + tid;
            int row = q >> 3, k4 = q & 7;
            float4 v = make_float4(0.f, 0.f, 0.f, 0.f);
            if (n0 + row < n)
                v = *(const float4*)(h2 + (size_t)(n0 + row) * 256 + d * 64 + c0 + k4 * 4);
            As[(k4 * 4 + 0) * 132 + row] = v.x;
            As[(k4 * 4 + 1) * 132 + row] = v.y;
            As[(k4 * 4 + 2) * 132 + row] = v.z;
            As[(k4 * 4 + 3) * 132 + row] = v.w;
        }
#pragma unroll
        for (int it = 0; it < 4; ++it) {
            int q = it * 256 + tid;
            if (q < 960) {
                int c = q >> 3, k4 = q & 7;
                float4 v = *(const float4*)(cent + (size_t)c * 256 + d * 64 + c0 + k4 * 4);
                int col = ((c >> 3) << 2) + (((c >> 2) & 1) << 6) + (c & 3);
                Bs[(k4 * 4 + 0) * 132 + col] = v.x;
                Bs[(k4 * 4 + 1) * 132 + col] = v.y;
                Bs[(k4 * 4 + 2) * 132 + col] = v.z;
                Bs[(k4 * 4 + 3) * 132 + col] = v.w;
            }
        }
        __syncthreads();
#pragma unroll 4
        for (int k = 0; k < 32; ++k) {
            float4 a0 = *(const float4*)&As[k * 132 + ty * 8];
            float4 a1 = *(const float4*)&As[k * 132 + ty * 8 + 4];
            float4 b0 = *(const float4*)&Bs[k * 132 + tx * 4];
            float4 b1 = *(const float4*)&Bs[k * 132 + 64 + tx * 4];
            float av[8] = {a0.x, a0.y, a0.z, a0.w, a1.x, a1.y, a1.z, a1.w};
            float bv[8] = {b0.x, b0.y, b0.z, b0.w, b1.x, b1.y, b1.z, b1.w};
#pragma unroll
            for (int i = 0; i < 8; ++i)
#pragma unroll
                for (int j = 0; j < 8; ++j)
                    acc[i][j] += av[i] * bv[j];
        }
        __syncthreads();
    }

    float balp[8] = {};
#pragma unroll
    for (int i = 0; i < 8; ++i) {
        const int node = ty * 8 + i;
        const bool act = (n0 + node) < n;
        float m = acc[i][0];
        int am = tx * 8;
#pragma unroll
        for (int j = 1; j < 8; ++j)
            if (acc[i][j] > m) { m = acc[i][j]; am = tx * 8 + j; }
#pragma unroll
        for (int s = 1; s <= 4; s <<= 1) {
            int pl = l ^ s;
            int srcl = segbase + base + pl;
            float mo = __shfl(m, srcl, 64);
            int amo = __shfl(am, srcl, 64);
            if (pl < sz && (mo > m || (mo == m && amo < am))) { m = mo; am = amo; }
        }
        float Z = 0.f;
#pragma unroll
        for (int j = 0; j < 8; ++j) {
            float e2 = expf(acc[i][j] - m);
            acc[i][j] = e2;
            Z += e2;
        }
#pragma unroll
        for (int s = 1; s <= 4; s <<= 1) {
            int pl = l ^ s;
            int srcl = segbase + base + pl;
            float Zo = __shfl(Z, srcl, 64);
            if (pl < sz) Z += Zo;
        }
        float invZ = (act && sz > 0) ? (1.0f / Z) : 0.f;
#pragma unroll
        for (int j = 0; j < 8; ++j) balp[j] += acc[i][j] * invZ;
        if (l == 0 && sz > 0) km_ls[node * 4 + gid] = am;
    }

#pragma unroll
    for (int j = 0; j < 8; ++j) {
        float v = balp[j];
        v += __shfl_xor(v, 16, 64);
        v += __shfl_xor(v, 32, 64);
        balp[j] = v;
    }
    if (lane < 16) {
#pragma unroll
        for (int j = 0; j < 8; ++j)
            bal4[wave * 128 + tx * 8 + j] = balp[j];
    }
    __syncthreads();
    if (tid < 120) {
        float s = bal4[tid] + bal4[128 + tid] + bal4[256 + tid] + bal4[384 + tid];
        atomicAdd(&balance_g[tid * 4 + d], s);
    }

    // P4: h3 = h2 + max_j cent[km_j], emitted as bf16 hi/lo split
    {
        const int node = tid >> 1;
        const int half = tid & 1;
        if (n0 + node < n) {
            int k0 = km_ls[node * 4 + 0], k1 = km_ls[node * 4 + 1];
            int k2 = km_ls[node * 4 + 2], k3 = km_ls[node * 4 + 3];
            const float* hp = h2 + (size_t)(n0 + node) * 256 + d * 64 + half * 32;
            const float* c0 = cent + (size_t)k0 * 256 + d * 64 + half * 32;
            const float* c1 = cent + (size_t)k1 * 256 + d * 64 + half * 32;
            const float* c2 = cent + (size_t)k2 * 256 + d * 64 + half * 32;
            const float* c3 = cent + (size_t)k3 * 256 + d * 64 + half * 32;
            size_t obase = (size_t)(n0 + node) * 256 + d * 64 + half * 32;
#pragma unroll
            for (int q = 0; q < 8; ++q) {
                int g = q * 4;
                float4 hv = *(const float4*)(hp + g);
                float4 v0 = *(const float4*)(c0 + g);
                float4 v1 = *(const float4*)(c1 + g);
                float4 v2 = *(const float4*)(c2 + g);
                float4 v3 = *(const float4*)(c3 + g);
                float e[4];
                e[0] = hv.x + fmaxf(fmaxf(v0.x, v1.x), fmaxf(v2.x, v3.x));
                e[1] = hv.y + fmaxf(fmaxf(v0.y, v1.y), fmaxf(v2.y, v3.y));
                e[2] = hv.z + fmaxf(fmaxf(v0.z, v1.z), fmaxf(v2.z, v3.z));
                e[3] = hv.w + fmaxf(fmaxf(v0.w, v1.w), fmaxf(v2.w, v3.w));
                unsigned short h[4], l[4];
                split4(e, h, l);
                *(uint2*)(h3h + obase + g) = make_uint2(h[0] | (h[1] << 16), h[2] | (h[3] << 16));
                *(uint2*)(h3l + obase + g) = make_uint2(l[0] | (l[1] << 16), l[2] | (l[3] << 16));
            }
        }
    }
}

__global__ void k_reg(const float* __restrict__ balance_g, float* __restrict__ out_reg,
                      float inv_n) {
    __shared__ float red[512];
    int tid = threadIdx.x;
    float v = 0.f;
    if (tid < 480) {
        int k = tid >> 2;
        float target = (k < 8) ? 0.125f : (k < 24) ? 0.0625f : (k < 56) ? 0.03125f : 0.015625f;
        float b = balance_g[tid] * inv_n;
        float df = b - target;
        v = df * df;
    }
    red[tid] = v;
    __syncthreads();
    for (int s = 256; s > 0; s >>= 1) {
        if (tid < s) red[tid] += red[tid + s];
        __syncthreads();
    }
    if (tid == 0) *out_reg = sqrtf(red[0]);
}

// ---------------- host launch ----------------

extern "C" void kernel_launch(void* const* d_in, const int* in_sizes, int n_in,
                              void* d_out, int out_size, void* d_ws, size_t ws_size,
                              hipStream_t stream) {
    const float* x    = (const float*)d_in[0];
    const int*   ei   = (const int*)d_in[1];
    const float* W0   = (const float*)d_in[2];
    const float* b0   = (const float*)d_in[3];
    const float* W1   = (const float*)d_in[4];
    const float* b1   = (const float*)d_in[5];
    const float* W2   = (const float*)d_in[6];
    const float* b2   = (const float*)d_in[7];
    const float* cent = (const float*)d_in[8];
    const int n = in_sizes[0] / 256;
    const int e = in_sizes[1] / 2;
    const int* src = ei;
    const int* dst = ei + e;
    float* out = (float*)d_out;

    char* w = (char*)d_ws;
    float* bufA = (float*)w;      w += (size_t)n * 256 * 4;
    float* bufB = (float*)w;      w += (size_t)n * 256 * 4;
    float* dinv = (float*)w;      w += (size_t)n * 4;
    int* cnt = (int*)w;           w += (size_t)n * 4;
    int* row_start = (int*)w;     w += (size_t)n * 4;
    int* cursor = (int*)w;        w += (size_t)n * 4;
    int* csr_src = (int*)w;       w += (size_t)e * 4;
    float* csr_norm = (float*)w;  w += (size_t)e * 4;
    int* counter = (int*)w;       w += 256;
    float* balance = (float*)w;   w += 480 * 4;
    short* w0h = (short*)w;       w += 256 * 256 * 2;
    short* w0l = (short*)w;       w += 256 * 256 * 2;
    short* w1h = (short*)w;       w += 256 * 256 * 2;
    short* w1l = (short*)w;       w += 256 * 256 * 2;
    short* w2h = (short*)w;       w += 128 * 256 * 2;
    short* w2l = (short*)w;       w += 128 * 256 * 2;

    // buffer roles (bufA/bufB alternate fp32 <-> packed hi|lo):
    //   splitA: x -> bufA = [Xh | Xl]
    //   gemm1 : bufA -> bufB fp32 (xw)
    //   agg4#1: bufB -> bufA = [H1h | H1l]   (split emission)
    //   gemm2 : bufA -> bufB fp32 (xw2)
    //   agg4#2: bufB -> bufA fp32 (h2)
    //   quant4: bufA -> bufB = [H3h | H3l]   (+balance)
    //   gemm3 : bufB -> bufA fp32 (128-dim)
    //   agg2  : bufA -> out
    short* xh = (short*)bufA;
    short* xl = xh + (size_t)n * 256;
    short* h1h = (short*)bufA;
    short* h1l = h1h + (size_t)n * 256;
    short* h3h = (short*)bufB;
    short* h3l = h3h + (size_t)n * 256;

    const int tb = 256;
    k_init<<<(n + tb - 1) / tb, tb, 0, stream>>>(cnt, cursor, counter, balance, n);
    k_count<<<(e + tb - 1) / tb, tb, 0, stream>>>(dst, cnt, e);
    k_dinv<<<(n + tb - 1) / tb, tb, 0, stream>>>(cnt, dinv, n);
    k_alloc<<<(n + tb - 1) / tb, tb, 0, stream>>>(cnt, row_start, counter, n);
    k_fill<<<(e + tb - 1) / tb, tb, 0, stream>>>(src, dst, dinv, row_start, cursor,
                                                 csr_src, csr_norm, e);

    k_splitW<<<(256 * 256 + tb - 1) / tb, tb, 0, stream>>>(W0, w0h, w0l, 256);
    k_splitW<<<(256 * 256 + tb - 1) / tb, tb, 0, stream>>>(W1, w1h, w1l, 256);
    k_splitW<<<(128 * 256 + tb - 1) / tb, tb, 0, stream>>>(W2, w2h, w2l, 128);
    k_splitA<<<(n * 32 + tb - 1) / tb, tb, 0, stream>>>(x, xh, xl, n * 32);

    dim3 g1((n + 127) / 128, 2);
    k_gemm_bf16s<<<g1, 256, 0, stream>>>(xh, xl, w0h, w0l, bufB, n, 256);
    k_agg4<true, 1><<<(n + 3) / 4, 256, 0, stream>>>(bufB, dinv, csr_src, csr_norm,
                                                     row_start, cnt, b0, nullptr,
                                                     h1h, h1l, n);
    k_gemm_bf16s<<<g1, 256, 0, stream>>>(h1h, h1l, w1h, w1l, bufB, n, 256);
    k_agg4<true, 0><<<(n + 3) / 4, 256, 0, stream>>>(bufB, dinv, csr_src, csr_norm,
                                                     row_start, cnt, b1, bufA,
                                                     nullptr, nullptr, n);

    dim3 gq((n + 127) / 128, 4);
    k_quant4<<<gq, 256, 0, stream>>>(bufA, cent, h3h, h3l, balance, n);

    dim3 g3((n + 127) / 128, 1);
    k_gemm_bf16s<<<g3, 256, 0, stream>>>(h3h, h3l, w2h, w2l, bufA, n, 128);
    k_agg2<<<(n + 3) / 4, 256, 0, stream>>>(bufA, dinv, csr_src, csr_norm,
                                            row_start, cnt, b2, out, n);
    k_reg<<<1, 512, 0, stream>>>(balance, out + (size_t)n * 128, 1.0f / (float)n);
}

// Round 9
// 611.696 us; speedup vs baseline: 1.7026x; 1.0130x over previous
//
#include <hip/hip_runtime.h>
#include <math.h>

// ---------------------------------------------------------------------------
// GCN pipeline: conv1(relu) -> conv2(relu) -> quantize(+reg) -> add -> conv3
// GEMMs: split-bf16 MFMA (Ootomo 3-term), pre-split hi/lo tables, register
// prefetch (async-stage: issue-early/write-late) + LDS-transposed epilogue.
// fp32 visible to quantize's argmax (split residual ~1e-5 accepted since r7).
// ---------------------------------------------------------------------------

typedef short bf16x8 __attribute__((ext_vector_type(8)));
typedef float f32x4 __attribute__((ext_vector_type(4)));

__device__ __forceinline__ unsigned short bf16_rne(float a) {
    unsigned u = __builtin_bit_cast(unsigned, a);
    return (unsigned short)((u + 0x7FFFu + ((u >> 16) & 1u)) >> 16);
}
__device__ __forceinline__ float bf16_to_f(unsigned short h) {
    return __builtin_bit_cast(float, (unsigned)h << 16);
}
__device__ __forceinline__ void split4(const float* e, unsigned short* h, unsigned short* l) {
#pragma unroll
    for (int t = 0; t < 4; ++t) {
        h[t] = bf16_rne(e[t]);
        l[t] = bf16_rne(e[t] - bf16_to_f(h[t]));
    }
}

// ---------------- CSR build ----------------

__global__ void k_init(int* cnt, int* cursor, int* counter, float* balance, int n) {
    int i = blockIdx.x * blockDim.x + threadIdx.x;
    if (i < n) { cnt[i] = 0; cursor[i] = 0; }
    if (i < 480) balance[i] = 0.f;
    if (i == 0) *counter = 0;
}

__global__ void k_count(const int* __restrict__ dst, int* __restrict__ cnt, int e) {
    int i = blockIdx.x * blockDim.x + threadIdx.x;
    if (i < e) atomicAdd(&cnt[dst[i]], 1);
}

__global__ void k_dinv(const int* __restrict__ cnt, float* __restrict__ dinv, int n) {
    int i = blockIdx.x * blockDim.x + threadIdx.x;
    if (i < n) dinv[i] = rsqrtf((float)cnt[i] + 1.0f);   // +1 self loop
}

__global__ void k_alloc(const int* __restrict__ cnt, int* __restrict__ row_start,
                        int* __restrict__ counter, int n) {
    int i = blockIdx.x * blockDim.x + threadIdx.x;
    if (i < n) row_start[i] = atomicAdd(counter, cnt[i]);
}

__global__ void k_fill(const int* __restrict__ src, const int* __restrict__ dst,
                       const float* __restrict__ dinv, const int* __restrict__ row_start,
                       int* __restrict__ cursor, int* __restrict__ csr_src,
                       float* __restrict__ csr_norm, int e) {
    int i = blockIdx.x * blockDim.x + threadIdx.x;
    if (i >= e) return;
    int s = src[i], d = dst[i];
    int slot = atomicAdd(&cursor[d], 1);
    int idx = row_start[d] + slot;
    csr_src[idx] = s;
    csr_norm[idx] = dinv[s] * dinv[d];
}

// ---------------- split kernels ----------------

__global__ void k_splitW(const float* __restrict__ W, short* __restrict__ Th,
                         short* __restrict__ Tl, int N) {
    int i = blockIdx.x * blockDim.x + threadIdx.x;
    if (i >= N * 256) return;
    int nn = i >> 8, kk = i & 255;
    float v = W[kk * N + nn];
    unsigned short h = bf16_rne(v);
    unsigned short l = bf16_rne(v - bf16_to_f(h));
    Th[i] = (short)h;
    Tl[i] = (short)l;
}

__global__ void k_splitA(const float* __restrict__ X, short* __restrict__ Hi,
                         short* __restrict__ Lo, int total8) {
    int i = blockIdx.x * blockDim.x + threadIdx.x;
    if (i >= total8) return;
    float4 a = *(const float4*)(X + (size_t)i * 8);
    float4 b = *(const float4*)(X + (size_t)i * 8 + 4);
    float e0[4] = {a.x, a.y, a.z, a.w}, e1[4] = {b.x, b.y, b.z, b.w};
    unsigned short h0[4], l0[4], h1[4], l1[4];
    split4(e0, h0, l0);
    split4(e1, h1, l1);
    *(uint4*)(Hi + (size_t)i * 8) = make_uint4(h0[0] | (h0[1] << 16), h0[2] | (h0[3] << 16),
                                              h1[0] | (h1[1] << 16), h1[2] | (h1[3] << 16));
    *(uint4*)(Lo + (size_t)i * 8) = make_uint4(l0[0] | (l0[1] << 16), l0[2] | (l0[3] << 16),
                                              l1[0] | (l1[1] << 16), l1[2] | (l1[3] << 16));
}

// ---------------- bf16-split MFMA GEMM v2 ----------------
// Register prefetch: next chunk's 8 b128 globals issued BEFORE the MFMA
// section, written to LDS after the barrier (T14 issue-early/write-late).
// Epilogue: acc -> LDS [128][68] f32 (2 passes) -> coalesced float4 stores.

__global__ __launch_bounds__(256, 2) void k_gemm_bf16s(const short* __restrict__ Ah,
                                                       const short* __restrict__ Al,
                                                       const short* __restrict__ Bh,
                                                       const short* __restrict__ Bl,
                                                       float* __restrict__ C,
                                                       int M, int N) {
    __shared__ short smem[4 * 128 * 56];   // Ash|Asl|Bsh|Bsl; epilogue: f32[128][68]
    short* Ash = smem;
    short* Asl = smem + 7168;
    short* Bsh = smem + 14336;
    short* Bsl = smem + 21504;
    const int tid = threadIdx.x;
    const int bm = blockIdx.x * 128;
    const int bn = blockIdx.y * 128;
    const int wave = tid >> 6, lane = tid & 63;
    const int wr = wave >> 1, wc = wave & 1;
    const int lr = lane & 15, lk = lane >> 4;

    int srow[2], ssg[2];
    bool aval[2];
#pragma unroll
    for (int it = 0; it < 2; ++it) {
        int u = it * 256 + tid;
        srow[it] = u >> 2;
        ssg[it] = (u & 3) << 3;
        aval[it] = (bm + srow[it]) < M;
    }

    const bf16x8 z8 = {0, 0, 0, 0, 0, 0, 0, 0};
    bf16x8 pah[2], pal[2], pbh[2], pbl[2];

    auto prefetch = [&](int k0) {
#pragma unroll
        for (int it = 0; it < 2; ++it) {
            size_t arow = (size_t)(bm + srow[it]) * 256 + k0 + ssg[it];
            size_t brow = (size_t)(bn + srow[it]) * 256 + k0 + ssg[it];
            pah[it] = aval[it] ? *(const bf16x8*)(Ah + arow) : z8;
            pal[it] = aval[it] ? *(const bf16x8*)(Al + arow) : z8;
            pbh[it] = *(const bf16x8*)(Bh + brow);
            pbl[it] = *(const bf16x8*)(Bl + brow);
        }
    };

    f32x4 acc[4][4] = {};
    prefetch(0);

    for (int k0 = 0; k0 < 256; k0 += 32) {
#pragma unroll
        for (int it = 0; it < 2; ++it) {
            int off = srow[it] * 56 + ssg[it];
            *(bf16x8*)&Ash[off] = pah[it];
            *(bf16x8*)&Asl[off] = pal[it];
            *(bf16x8*)&Bsh[off] = pbh[it];
            *(bf16x8*)&Bsl[off] = pbl[it];
        }
        __syncthreads();

        bf16x8 ah[4], al[4], bh[4], bl[4];
#pragma unroll
        for (int i = 0; i < 4; ++i) {
            int off = (wr * 64 + i * 16 + lr) * 56 + lk * 8;
            ah[i] = *(bf16x8*)&Ash[off];
            al[i] = *(bf16x8*)&Asl[off];
        }
#pragma unroll
        for (int j = 0; j < 4; ++j) {
            int off = (wc * 64 + j * 16 + lr) * 56 + lk * 8;
            bh[j] = *(bf16x8*)&Bsh[off];
            bl[j] = *(bf16x8*)&Bsl[off];
        }

        if (k0 < 224) prefetch(k0 + 32);   // issue next chunk under MFMA

#pragma unroll
        for (int i = 0; i < 4; ++i)
#pragma unroll
            for (int j = 0; j < 4; ++j) {
                acc[i][j] = __builtin_amdgcn_mfma_f32_16x16x32_bf16(al[i], bh[j], acc[i][j], 0, 0, 0);
                acc[i][j] = __builtin_amdgcn_mfma_f32_16x16x32_bf16(ah[i], bl[j], acc[i][j], 0, 0, 0);
                acc[i][j] = __builtin_amdgcn_mfma_f32_16x16x32_bf16(ah[i], bh[j], acc[i][j], 0, 0, 0);
            }
        __syncthreads();
    }

    // coalesced epilogue (C/D layout col=lane&15, row=(lane>>4)*4+reg [m89])
    float* Cs = (float*)smem;              // [128][68] f32 = 34.8KB <= 57KB
#pragma unroll
    for (int p = 0; p < 2; ++p) {
        if (wc == p) {
#pragma unroll
            for (int i = 0; i < 4; ++i)
#pragma unroll
                for (int r = 0; r < 4; ++r) {
                    int row = wr * 64 + i * 16 + lk * 4 + r;
#pragma unroll
                    for (int j = 0; j < 4; ++j)
                        Cs[row * 68 + j * 16 + lr] = acc[i][j][r];
                }
        }
        __syncthreads();
#pragma unroll
        for (int t = 0; t < 8; ++t) {
            int idx = t * 256 + tid;
            int row = idx >> 4, c4 = idx & 15;
            if (bm + row < M)
                *(float4*)(C + (size_t)(bm + row) * N + bn + p * 64 + c4 * 4) =
                    *(const float4*)&Cs[row * 68 + c4 * 4];
        }
        __syncthreads();
    }
}

// ---------------- Aggregation (gather over CSR), one wave per node ----------------
// L3-BW-bound floor (~125us: 3.7 TB/s, FETCH = 8 XCD x 51 MB, invariant across
// 3 MLP structures, rounds 4-6). MODE=1 emits bf16 hi/lo split.

template <bool RELU, int MODE>
__global__ __launch_bounds__(256, 4) void k_agg4(const float* __restrict__ xw,
                                                 const float* __restrict__ dinv,
                                                 const int* __restrict__ csr_src,
                                                 const float* __restrict__ csr_norm,
                                                 const int* __restrict__ row_start,
                                                 const int* __restrict__ cnt,
                                                 const float* __restrict__ bias,
                                                 float* __restrict__ out,
                                                 short* __restrict__ outH,
                                                 short* __restrict__ outL, int n) {
    int node = blockIdx.x * 4 + (threadIdx.x >> 6);
    if (node >= n) return;
    int lane = threadIdx.x & 63;
    int c = lane * 4;
    float di = dinv[node];
    float4 self = *(const float4*)(xw + (size_t)node * 256 + c);
    float4 bv = *(const float4*)(bias + c);
    float sw = di * di;
    float ax = self.x * sw + bv.x;
    float ay = self.y * sw + bv.y;
    float az = self.z * sw + bv.z;
    float aw = self.w * sw + bv.w;
    int st = row_start[node];
    int m = cnt[node];
    for (int t0 = 0; t0 < m; t0 += 64) {
        int rem = m - t0;
        int cnt_i = rem < 64 ? rem : 64;
        int idx_l = 0;
        float nrm_l = 0.f;
        if (lane < cnt_i) {
            idx_l = csr_src[st + t0 + lane];
            nrm_l = csr_norm[st + t0 + lane];
        }
        int t = 0;
        for (; t + 8 <= cnt_i; t += 8) {
            const float* p0 = xw + (size_t)__shfl(idx_l, t + 0, 64) * 256 + c;
            const float* p1 = xw + (size_t)__shfl(idx_l, t + 1, 64) * 256 + c;
            const float* p2 = xw + (size_t)__shfl(idx_l, t + 2, 64) * 256 + c;
            const float* p3 = xw + (size_t)__shfl(idx_l, t + 3, 64) * 256 + c;
            const float* p4 = xw + (size_t)__shfl(idx_l, t + 4, 64) * 256 + c;
            const float* p5 = xw + (size_t)__shfl(idx_l, t + 5, 64) * 256 + c;
            const float* p6 = xw + (size_t)__shfl(idx_l, t + 6, 64) * 256 + c;
            const float* p7 = xw + (size_t)__shfl(idx_l, t + 7, 64) * 256 + c;
            float4 v0 = *(const float4*)p0;
            float4 v1 = *(const float4*)p1;
            float4 v2 = *(const float4*)p2;
            float4 v3 = *(const float4*)p3;
            float4 v4 = *(const float4*)p4;
            float4 v5 = *(const float4*)p5;
            float4 v6 = *(const float4*)p6;
            float4 v7 = *(const float4*)p7;
            float w0 = __shfl(nrm_l, t + 0, 64);
            float w1 = __shfl(nrm_l, t + 1, 64);
            float w2 = __shfl(nrm_l, t + 2, 64);
            float w3 = __shfl(nrm_l, t + 3, 64);
            float w4 = __shfl(nrm_l, t + 4, 64);
            float w5 = __shfl(nrm_l, t + 5, 64);
            float w6 = __shfl(nrm_l, t + 6, 64);
            float w7 = __shfl(nrm_l, t + 7, 64);
            ax += v0.x * w0; ay += v0.y * w0; az += v0.z * w0; aw += v0.w * w0;
            ax += v1.x * w1; ay += v1.y * w1; az += v1.z * w1; aw += v1.w * w1;
            ax += v2.x * w2; ay += v2.y * w2; az += v2.z * w2; aw += v2.w * w2;
            ax += v3.x * w3; ay += v3.y * w3; az += v3.z * w3; aw += v3.w * w3;
            ax += v4.x * w4; ay += v4.y * w4; az += v4.z * w4; aw += v4.w * w4;
            ax += v5.x * w5; ay += v5.y * w5; az += v5.z * w5; aw += v5.w * w5;
            ax += v6.x * w6; ay += v6.y * w6; az += v6.z * w6; aw += v6.w * w6;
            ax += v7.x * w7; ay += v7.y * w7; az += v7.z * w7; aw += v7.w * w7;
        }
        for (; t < cnt_i; ++t) {
            int s = __shfl(idx_l, t, 64);
            float w = __shfl(nrm_l, t, 64);
            float4 v = *(const float4*)(xw + (size_t)s * 256 + c);
            ax += v.x * w; ay += v.y * w; az += v.z * w; aw += v.w * w;
        }
    }
    if (RELU) {
        ax = ax > 0.f ? ax : 0.5f * ax;
        ay = ay > 0.f ? ay : 0.5f * ay;
        az = az > 0.f ? az : 0.5f * az;
        aw = aw > 0.f ? aw : 0.5f * aw;
    }
    if (MODE == 0) {
        *(float4*)(out + (size_t)node * 256 + c) = make_float4(ax, ay, az, aw);
    } else {
        float e[4] = {ax, ay, az, aw};
        unsigned short h[4], l[4];
        split4(e, h, l);
        size_t o = (size_t)node * 256 + c;
        *(uint2*)(outH + o) = make_uint2(h[0] | (h[1] << 16), h[2] | (h[3] << 16));
        *(uint2*)(outL + o) = make_uint2(l[0] | (l[1] << 16), l[2] | (l[3] << 16));
    }
}

__global__ __launch_bounds__(256, 4) void k_agg2(const float* __restrict__ xw,
                                                 const float* __restrict__ dinv,
                                                 const int* __restrict__ csr_src,
                                                 const float* __restrict__ csr_norm,
                                                 const int* __restrict__ row_start,
                                                 const int* __restrict__ cnt,
                                                 const float* __restrict__ bias,
                                                 float* __restrict__ out, int n) {
    int node = blockIdx.x * 4 + (threadIdx.x >> 6);
    if (node >= n) return;
    int lane = threadIdx.x & 63;
    int c = lane * 2;
    float di = dinv[node];
    float2 self = *(const float2*)(xw + (size_t)node * 128 + c);
    float2 bv = *(const float2*)(bias + c);
    float sw = di * di;
    float ax = self.x * sw + bv.x;
    float ay = self.y * sw + bv.y;
    int st = row_start[node];
    int m = cnt[node];
    for (int t0 = 0; t0 < m; t0 += 64) {
        int rem = m - t0;
        int cnt_i = rem < 64 ? rem : 64;
        int idx_l = 0;
        float nrm_l = 0.f;
        if (lane < cnt_i) {
            idx_l = csr_src[st + t0 + lane];
            nrm_l = csr_norm[st + t0 + lane];
        }
        int t = 0;
        for (; t + 8 <= cnt_i; t += 8) {
            const float* p0 = xw + (size_t)__shfl(idx_l, t + 0, 64) * 128 + c;
            const float* p1 = xw + (size_t)__shfl(idx_l, t + 1, 64) * 128 + c;
            const float* p2 = xw + (size_t)__shfl(idx_l, t + 2, 64) * 128 + c;
            const float* p3 = xw + (size_t)__shfl(idx_l, t + 3, 64) * 128 + c;
            const float* p4 = xw + (size_t)__shfl(idx_l, t + 4, 64) * 128 + c;
            const float* p5 = xw + (size_t)__shfl(idx_l, t + 5, 64) * 128 + c;
            const float* p6 = xw + (size_t)__shfl(idx_l, t + 6, 64) * 128 + c;
            const float* p7 = xw + (size_t)__shfl(idx_l, t + 7, 64) * 128 + c;
            float2 v0 = *(const float2*)p0;
            float2 v1 = *(const float2*)p1;
            float2 v2 = *(const float2*)p2;
            float2 v3 = *(const float2*)p3;
            float2 v4 = *(const float2*)p4;
            float2 v5 = *(const float2*)p5;
            float2 v6 = *(const float2*)p6;
            float2 v7 = *(const float2*)p7;
            float w0 = __shfl(nrm_l, t + 0, 64);
            float w1 = __shfl(nrm_l, t + 1, 64);
            float w2 = __shfl(nrm_l, t + 2, 64);
            float w3 = __shfl(nrm_l, t + 3, 64);
            float w4 = __shfl(nrm_l, t + 4, 64);
            float w5 = __shfl(nrm_l, t + 5, 64);
            float w6 = __shfl(nrm_l, t + 6, 64);
            float w7 = __shfl(nrm_l, t + 7, 64);
            ax += v0.x * w0; ay += v0.y * w0;
            ax += v1.x * w1; ay += v1.y * w1;
            ax += v2.x * w2; ay += v2.y * w2;
            ax += v3.x * w3; ay += v3.y * w3;
            ax += v4.x * w4; ay += v4.y * w4;
            ax += v5.x * w5; ay += v5.y * w5;
            ax += v6.x * w6; ay += v6.y * w6;
            ax += v7.x * w7; ay += v7.y * w7;
        }
        for (; t < cnt_i; ++t) {
            int s = __shfl(idx_l, t, 64);
            float w = __shfl(nrm_l, t, 64);
            float2 v = *(const float2*)(xw + (size_t)s * 128 + c);
            ax += v.x * w; ay += v.y * w;
        }
    }
    *(float2*)(out + (size_t)node * 128 + c) = make_float2(ax, ay);
}

// ---------------- Quantize v5 (reg softmax + chunk-2 h prefetch) ----------------

__global__ __launch_bounds__(256, 4) void k_quant4(const float* __restrict__ h2,
                                                   const float* __restrict__ cent,
                                                   short* __restrict__ h3h,
                                                   short* __restrict__ h3l,
                                                   float* __restrict__ balance_g, int n) {
    __shared__ float As[32 * 132];     // As[k][node]
    __shared__ float Bs[32 * 132];     // Bs[k][swizzled cent col]
    __shared__ float bal4[4 * 128];
    __shared__ int km_ls[128 * 4];
    const int tid = threadIdx.x;
    const int n0 = blockIdx.x * 128;
    const int d = blockIdx.y;
    const int ty = tid >> 4, tx = tid & 15;
    const int wave = tid >> 6, lane = tid & 63;

    int gid, base, sz;
    if (tx == 0)       { gid = 0; base = 0;  sz = 1; }
    else if (tx <= 2)  { gid = 1; base = 1;  sz = 2; }
    else if (tx <= 6)  { gid = 2; base = 3;  sz = 4; }
    else if (tx <= 14) { gid = 3; base = 7;  sz = 8; }
    else               { gid = 0; base = 15; sz = 0; }
    const int l = tx - base;
    const int segbase = lane & 48;

    {
        int k = tid >> 3, r = tid & 7;
        int col = (r < 4) ? (60 + r) : (120 + r);
        Bs[k * 132 + col] = 0.f;
    }

    const int srow = tid >> 3, sk4 = tid & 7;           // h2 staging coords
    const bool srv = (n0 + srow) < n;
    float acc[8][8] = {};

    // ---- stage chunk 1 (c0=0) ----
#pragma unroll
    for (int it = 0; it < 4; ++it) {
        int row = srow + it * 32;
        float4 v = make_float4(0.f, 0.f, 0.f, 0.f);
        if (n0 + row < n)
            v = *(const float4*)(h2 + (size_t)(n0 + row) * 256 + d * 64 + sk4 * 4);
        As[(sk4 * 4 + 0) * 132 + row] = v.x;
        As[(sk4 * 4 + 1) * 132 + row] = v.y;
        As[(sk4 * 4 + 2) * 132 + row] = v.z;
        As[(sk4 * 4 + 3) * 132 + row] = v.w;
    }
#pragma unroll
    for (int it = 0; it < 4; ++it) {
        int q = it * 256 + tid;
        if (q < 960) {
            int cc = q >> 3, k4 = q & 7;
            float4 v = *(const float4*)(cent + (size_t)cc * 256 + d * 64 + k4 * 4);
            int col = ((cc >> 3) << 2) + (((cc >> 2) & 1) << 6) + (cc & 3);
            Bs[(k4 * 4 + 0) * 132 + col] = v.x;
            Bs[(k4 * 4 + 1) * 132 + col] = v.y;
            Bs[(k4 * 4 + 2) * 132 + col] = v.z;
            Bs[(k4 * 4 + 3) * 132 + col] = v.w;
        }
    }
    // prefetch chunk-2 h2 into regs (issue-early; lands under chunk-1 FMA)
    float4 ph[4];
#pragma unroll
    for (int it = 0; it < 4; ++it) {
        int row = srow + it * 32;
        ph[it] = make_float4(0.f, 0.f, 0.f, 0.f);
        if (n0 + row < n)
            ph[it] = *(const float4*)(h2 + (size_t)(n0 + row) * 256 + d * 64 + 32 + sk4 * 4);
    }
    __syncthreads();

    // ---- FMA chunk 1 ----
#pragma unroll 4
    for (int k = 0; k < 32; ++k) {
        float4 a0 = *(const float4*)&As[k * 132 + ty * 8];
        float4 a1 = *(const float4*)&As[k * 132 + ty * 8 + 4];
        float4 b0 = *(const float4*)&Bs[k * 132 + tx * 4];
        float4 b1 = *(const float4*)&Bs[k * 132 + 64 + tx * 4];
        float av[8] = {a0.x, a0.y, a0.z, a0.w, a1.x, a1.y, a1.z, a1.w};
        float bv[8] = {b0.x, b0.y, b0.z, b0.w, b1.x, b1.y, b1.z, b1.w};
#pragma unroll
        for (int i = 0; i < 8; ++i)
#pragma unroll
            for (int j = 0; j < 8; ++j)
                acc[i][j] += av[i] * bv[j];
    }
    __syncthreads();

    // ---- stage chunk 2 (h from regs, cent fresh) ----
#pragma unroll
    for (int it = 0; it < 4; ++it) {
        int row = srow + it * 32;
        As[(sk4 * 4 + 0) * 132 + row] = ph[it].x;
        As[(sk4 * 4 + 1) * 132 + row] = ph[it].y;
        As[(sk4 * 4 + 2) * 132 + row] = ph[it].z;
        As[(sk4 * 4 + 3) * 132 + row] = ph[it].w;
    }
#pragma unroll
    for (int it = 0; it < 4; ++it) {
        int q = it * 256 + tid;
        if (q < 960) {
            int cc = q >> 3, k4 = q & 7;
            float4 v = *(const float4*)(cent + (size_t)cc * 256 + d * 64 + 32 + k4 * 4);
            int col = ((cc >> 3) << 2) + (((cc >> 2) & 1) << 6) + (cc & 3);
            Bs[(k4 * 4 + 0) * 132 + col] = v.x;
            Bs[(k4 * 4 + 1) * 132 + col] = v.y;
            Bs[(k4 * 4 + 2) * 132 + col] = v.z;
            Bs[(k4 * 4 + 3) * 132 + col] = v.w;
        }
    }
    __syncthreads();

    // ---- FMA chunk 2 ----
#pragma unroll 4
    for (int k = 0; k < 32; ++k) {
        float4 a0 = *(const float4*)&As[k * 132 + ty * 8];
        float4 a1 = *(const float4*)&As[k * 132 + ty * 8 + 4];
        float4 b0 = *(const float4*)&Bs[k * 132 + tx * 4];
        float4 b1 = *(const float4*)&Bs[k * 132 + 64 + tx * 4];
        float av[8] = {a0.x, a0.y, a0.z, a0.w, a1.x, a1.y, a1.z, a1.w};
        float bv[8] = {b0.x, b0.y, b0.z, b0.w, b1.x, b1.y, b1.z, b1.w};
#pragma unroll
        for (int i = 0; i < 8; ++i)
#pragma unroll
            for (int j = 0; j < 8; ++j)
                acc[i][j] += av[i] * bv[j];
    }

    // ---- per-group softmax/argmax/balance in registers ----
    float balp[8] = {};
#pragma unroll
    for (int i = 0; i < 8; ++i) {
        const int node = ty * 8 + i;
        const bool act = (n0 + node) < n;
        float m = acc[i][0];
        int am = tx * 8;
#pragma unroll
        for (int j = 1; j < 8; ++j)
            if (acc[i][j] > m) { m = acc[i][j]; am = tx * 8 + j; }
#pragma unroll
        for (int s = 1; s <= 4; s <<= 1) {
            int pl = l ^ s;
            int srcl = segbase + base + pl;
            float mo = __shfl(m, srcl, 64);
            int amo = __shfl(am, srcl, 64);
            if (pl < sz && (mo > m || (mo == m && amo < am))) { m = mo; am = amo; }
        }
        float Z = 0.f;
#pragma unroll
        for (int j = 0; j < 8; ++j) {
            float e2 = expf(acc[i][j] - m);
            acc[i][j] = e2;
            Z += e2;
        }
#pragma unroll
        for (int s = 1; s <= 4; s <<= 1) {
            int pl = l ^ s;
            int srcl = segbase + base + pl;
            float Zo = __shfl(Z, srcl, 64);
            if (pl < sz) Z += Zo;
        }
        float invZ = (act && sz > 0) ? (1.0f / Z) : 0.f;
#pragma unroll
        for (int j = 0; j < 8; ++j) balp[j] += acc[i][j] * invZ;
        if (l == 0 && sz > 0) km_ls[node * 4 + gid] = am;
    }

#pragma unroll
    for (int j = 0; j < 8; ++j) {
        float v = balp[j];
        v += __shfl_xor(v, 16, 64);
        v += __shfl_xor(v, 32, 64);
        balp[j] = v;
    }
    if (lane < 16) {
#pragma unroll
        for (int j = 0; j < 8; ++j)
            bal4[wave * 128 + tx * 8 + j] = balp[j];
    }
    __syncthreads();
    if (tid < 120) {
        float s = bal4[tid] + bal4[128 + tid] + bal4[256 + tid] + bal4[384 + tid];
        atomicAdd(&balance_g[tid * 4 + d], s);
    }

    // ---- P4: h3 = h2 + max_j cent[km_j], bf16 hi/lo emission ----
    {
        const int node = tid >> 1;
        const int half = tid & 1;
        if (n0 + node < n) {
            int k0 = km_ls[node * 4 + 0], k1 = km_ls[node * 4 + 1];
            int k2 = km_ls[node * 4 + 2], k3 = km_ls[node * 4 + 3];
            const float* hp = h2 + (size_t)(n0 + node) * 256 + d * 64 + half * 32;
            const float* c0 = cent + (size_t)k0 * 256 + d * 64 + half * 32;
            const float* c1 = cent + (size_t)k1 * 256 + d * 64 + half * 32;
            const float* c2 = cent + (size_t)k2 * 256 + d * 64 + half * 32;
            const float* c3 = cent + (size_t)k3 * 256 + d * 64 + half * 32;
            size_t obase = (size_t)(n0 + node) * 256 + d * 64 + half * 32;
#pragma unroll
            for (int q = 0; q < 8; ++q) {
                int g = q * 4;
                float4 hv = *(const float4*)(hp + g);
                float4 v0 = *(const float4*)(c0 + g);
                float4 v1 = *(const float4*)(c1 + g);
                float4 v2 = *(const float4*)(c2 + g);
                float4 v3 = *(const float4*)(c3 + g);
                float e[4];
                e[0] = hv.x + fmaxf(fmaxf(v0.x, v1.x), fmaxf(v2.x, v3.x));
                e[1] = hv.y + fmaxf(fmaxf(v0.y, v1.y), fmaxf(v2.y, v3.y));
                e[2] = hv.z + fmaxf(fmaxf(v0.z, v1.z), fmaxf(v2.z, v3.z));
                e[3] = hv.w + fmaxf(fmaxf(v0.w, v1.w), fmaxf(v2.w, v3.w));
                unsigned short h[4], l[4];
                split4(e, h, l);
                *(uint2*)(h3h + obase + g) = make_uint2(h[0] | (h[1] << 16), h[2] | (h[3] << 16));
                *(uint2*)(h3l + obase + g) = make_uint2(l[0] | (l[1] << 16), l[2] | (l[3] << 16));
            }
        }
    }
}

__global__ void k_reg(const float* __restrict__ balance_g, float* __restrict__ out_reg,
                      float inv_n) {
    __shared__ float red[512];
    int tid = threadIdx.x;
    float v = 0.f;
    if (tid < 480) {
        int k = tid >> 2;
        float target = (k < 8) ? 0.125f : (k < 24) ? 0.0625f : (k < 56) ? 0.03125f : 0.015625f;
        float b = balance_g[tid] * inv_n;
        float df = b - target;
        v = df * df;
    }
    red[tid] = v;
    __syncthreads();
    for (int s = 256; s > 0; s >>= 1) {
        if (tid < s) red[tid] += red[tid + s];
        __syncthreads();
    }
    if (tid == 0) *out_reg = sqrtf(red[0]);
}

// ---------------- host launch ----------------

extern "C" void kernel_launch(void* const* d_in, const int* in_sizes, int n_in,
                              void* d_out, int out_size, void* d_ws, size_t ws_size,
                              hipStream_t stream) {
    const float* x    = (const float*)d_in[0];
    const int*   ei   = (const int*)d_in[1];
    const float* W0   = (const float*)d_in[2];
    const float* b0   = (const float*)d_in[3];
    const float* W1   = (const float*)d_in[4];
    const float* b1   = (const float*)d_in[5];
    const float* W2   = (const float*)d_in[6];
    const float* b2   = (const float*)d_in[7];
    const float* cent = (const float*)d_in[8];
    const int n = in_sizes[0] / 256;
    const int e = in_sizes[1] / 2;
    const int* src = ei;
    const int* dst = ei + e;
    float* out = (float*)d_out;

    char* w = (char*)d_ws;
    float* bufA = (float*)w;      w += (size_t)n * 256 * 4;
    float* bufB = (float*)w;      w += (size_t)n * 256 * 4;
    float* dinv = (float*)w;      w += (size_t)n * 4;
    int* cnt = (int*)w;           w += (size_t)n * 4;
    int* row_start = (int*)w;     w += (size_t)n * 4;
    int* cursor = (int*)w;        w += (size_t)n * 4;
    int* csr_src = (int*)w;       w += (size_t)e * 4;
    float* csr_norm = (float*)w;  w += (size_t)e * 4;
    int* counter = (int*)w;       w += 256;
    float* balance = (float*)w;   w += 480 * 4;
    short* w0h = (short*)w;       w += 256 * 256 * 2;
    short* w0l = (short*)w;       w += 256 * 256 * 2;
    short* w1h = (short*)w;       w += 256 * 256 * 2;
    short* w1l = (short*)w;       w += 256 * 256 * 2;
    short* w2h = (short*)w;       w += 128 * 256 * 2;
    short* w2l = (short*)w;       w += 128 * 256 * 2;

    short* xh = (short*)bufA;
    short* xl = xh + (size_t)n * 256;
    short* h1h = (short*)bufA;
    short* h1l = h1h + (size_t)n * 256;
    short* h3h = (short*)bufB;
    short* h3l = h3h + (size_t)n * 256;

    const int tb = 256;
    k_init<<<(n + tb - 1) / tb, tb, 0, stream>>>(cnt, cursor, counter, balance, n);
    k_count<<<(e + tb - 1) / tb, tb, 0, stream>>>(dst, cnt, e);
    k_dinv<<<(n + tb - 1) / tb, tb, 0, stream>>>(cnt, dinv, n);
    k_alloc<<<(n + tb - 1) / tb, tb, 0, stream>>>(cnt, row_start, counter, n);
    k_fill<<<(e + tb - 1) / tb, tb, 0, stream>>>(src, dst, dinv, row_start, cursor,
                                                 csr_src, csr_norm, e);

    k_splitW<<<(256 * 256 + tb - 1) / tb, tb, 0, stream>>>(W0, w0h, w0l, 256);
    k_splitW<<<(256 * 256 + tb - 1) / tb, tb, 0, stream>>>(W1, w1h, w1l, 256);
    k_splitW<<<(128 * 256 + tb - 1) / tb, tb, 0, stream>>>(W2, w2h, w2l, 128);
    k_splitA<<<(n * 32 + tb - 1) / tb, tb, 0, stream>>>(x, xh, xl, n * 32);

    dim3 g1((n + 127) / 128, 2);
    k_gemm_bf16s<<<g1, 256, 0, stream>>>(xh, xl, w0h, w0l, bufB, n, 256);
    k_agg4<true, 1><<<(n + 3) / 4, 256, 0, stream>>>(bufB, dinv, csr_src, csr_norm,
                                                     row_start, cnt, b0, nullptr,
                                                     h1h, h1l, n);
    k_gemm_bf16s<<<g1, 256, 0, stream>>>(h1h, h1l, w1h, w1l, bufB, n, 256);
    k_agg4<true, 0><<<(n + 3) / 4, 256, 0, stream>>>(bufB, dinv, csr_src, csr_norm,
                                                     row_start, cnt, b1, bufA,
                                                     nullptr, nullptr, n);

    dim3 gq((n + 127) / 128, 4);
    k_quant4<<<gq, 256, 0, stream>>>(bufA, cent, h3h, h3l, balance, n);

    dim3 g3((n + 127) / 128, 1);
    k_gemm_bf16s<<<g3, 256, 0, stream>>>(h3h, h3l, w2h, w2l, bufA, n, 128);
    k_agg2<<<(n + 3) / 4, 256, 0, stream>>>(bufA, dinv, csr_src, csr_norm,
                                            row_start, cnt, b2, out, n);
    k_reg<<<1, 512, 0, stream>>>(balance, out + (size_t)n * 128, 1.0f / (float)n);
}